// Round 1
// baseline (817.406 us; speedup 1.0000x reference)
//
#include <hip/hip_runtime.h>
#include <hip/hip_bf16.h>

// Problem constants
#define Bn   4
#define CHn  96
#define Hh   48
#define Ww   48
#define Ll   2304      // H*W
#define Pp   9216      // B*L
#define DIn  192
#define Nn   16
#define Rr   6
#define CL   32        // scan chunk length

__device__ inline float siluf(float x){ return x / (1.0f + __expf(-x)); }
__device__ inline float sigmf(float x){ return 1.0f / (1.0f + __expf(-x)); }

// ---------------- transpose-all-weights kernel (one launch) ----------------
struct TArgs {
  const float* s[14];
  float* d[14];
  int rows[14];
  int cols[14];
};
__global__ void k_tr(TArgs a){
  int id = blockIdx.y;
  int n = a.rows[id] * a.cols[id];
  int t = blockIdx.x * blockDim.x + threadIdx.x;
  if (t < n){
    int r = t / a.cols[id];
    int c = t - r * a.cols[id];
    a.d[id][c * a.rows[id] + r] = a.s[id][t];
  }
}

// ---------------- conv1x1 + BN + ReLU + channel linear ----------------
__global__ void k_pre(const float* __restrict__ x, const float* __restrict__ w1T, const float* __restrict__ b1,
                      const float* __restrict__ bng, const float* __restrict__ bnb,
                      const float* __restrict__ linT, const float* __restrict__ lb,
                      float* __restrict__ hlin){
  int p = blockIdx.x; int b = p / Ll; int pp = p - b * Ll;
  int c = threadIdx.x;
  __shared__ float xv[CHn];
  __shared__ float hv[CHn];
  xv[c] = x[(size_t)(b * CHn + c) * Ll + pp];
  __syncthreads();
  float acc = 0.f;
  for (int i = 0; i < CHn; ++i) acc = fmaf(w1T[i * CHn + c], xv[i], acc);
  float s = bng[c] * rsqrtf(1.0f + 1e-5f);
  float h = fmaxf((acc + b1[c]) * s + bnb[c], 0.f);
  hv[c] = h;
  __syncthreads();
  float a2 = lb[c];
  for (int i = 0; i < CHn; ++i) a2 = fmaf(linT[i * CHn + c], hv[i], a2);
  hlin[(size_t)p * CHn + c] = a2;
}

// ---------------- two depthwise 3x3 convs + SiLU ----------------
__global__ void k_dw(const float* __restrict__ hlin,
                     const float* __restrict__ dw1w, const float* __restrict__ dw1b,
                     const float* __restrict__ dw2w, const float* __restrict__ dw2b,
                     float* __restrict__ x1pre, float* __restrict__ x2){
  int t = blockIdx.x * 256 + threadIdx.x;
  if (t >= Pp * CHn) return;
  int c = t % CHn; int p = t / CHn; int b = p / Ll; int pp = p - b * Ll;
  int r = pp / Ww; int cx = pp - r * Ww;
  float a1 = dw1b[c], a2 = dw2b[c];
  for (int dy = -1; dy <= 1; ++dy){
    int ny = r + dy; if ((unsigned)ny >= Hh) continue;
    for (int dx = -1; dx <= 1; ++dx){
      int nx = cx + dx; if ((unsigned)nx >= Ww) continue;
      float v = hlin[(size_t)((b * Ll) + ny * Ww + nx) * CHn + c];
      int wi = c * 9 + (dy + 1) * 3 + (dx + 1);
      a1 = fmaf(dw1w[wi], v, a1);
      a2 = fmaf(dw2w[wi], v, a2);
    }
  }
  x1pre[t] = siluf(a1);
  x2[t]   = siluf(a2);
}

// ---------------- attention gate: sigmoid(ag2(relu(ag1 x2))) * x2 ----------------
__global__ void k_gate(const float* __restrict__ x2,
                       const float* __restrict__ ag1T, const float* __restrict__ ag1b,
                       const float* __restrict__ ag2T, const float* __restrict__ ag2b,
                       float* __restrict__ x2g){
  int p = blockIdx.x; int c = threadIdx.x;
  __shared__ float xv[CHn];
  __shared__ float rv[48];
  xv[c] = x2[(size_t)p * CHn + c];
  __syncthreads();
  if (c < 48){
    float a = ag1b[c];
    for (int i = 0; i < CHn; ++i) a = fmaf(ag1T[i * 48 + c], xv[i], a);
    rv[c] = fmaxf(a, 0.f);
  }
  __syncthreads();
  float a2 = ag2b[c];
  for (int tt = 0; tt < 48; ++tt) a2 = fmaf(ag2T[tt * CHn + c], rv[tt], a2);
  x2g[(size_t)p * CHn + c] = xv[c] * sigmf(a2);
}

// ---------------- SS2D input projection: 96 -> 384 (xi | z) ----------------
__global__ void k_ssin(const float* __restrict__ x1pre, const float* __restrict__ inT,
                       float* __restrict__ xi, float* __restrict__ z){
  int p = blockIdx.x; int j = threadIdx.x; // j < 192
  __shared__ float xv[CHn];
  if (j < CHn) xv[j] = x1pre[(size_t)p * CHn + j];
  __syncthreads();
  float a0 = 0.f, a1 = 0.f;
  for (int i = 0; i < CHn; ++i){
    float v = xv[i];
    a0 = fmaf(inT[i * 384 + j],        v, a0);
    a1 = fmaf(inT[i * 384 + 192 + j],  v, a1);
  }
  xi[(size_t)p * DIn + j] = a0;
  z [(size_t)p * DIn + j] = a1;
}

// ---------------- SS2D depthwise 3x3 + SiLU ----------------
__global__ void k_ssdw(const float* __restrict__ xi, const float* __restrict__ scw,
                       const float* __restrict__ scb, float* __restrict__ xc){
  int t = blockIdx.x * 256 + threadIdx.x;
  if (t >= Pp * DIn) return;
  int d = t % DIn; int p = t / DIn; int b = p / Ll; int pp = p - b * Ll;
  int r = pp / Ww; int cx = pp - r * Ww;
  float a = scb[d];
  for (int dy = -1; dy <= 1; ++dy){
    int ny = r + dy; if ((unsigned)ny >= Hh) continue;
    for (int dx = -1; dx <= 1; ++dx){
      int nx = cx + dx; if ((unsigned)nx >= Ww) continue;
      float v = xi[(size_t)((b * Ll) + ny * Ww + nx) * DIn + d];
      a = fmaf(scw[d * 9 + (dy + 1) * 3 + (dx + 1)], v, a);
    }
  }
  xc[t] = siluf(a);
}

__device__ inline int pix_of(int k, int l){
  if (k == 0) return l;
  if (k == 1) return (l % 48) * 48 + l / 48;
  if (k == 2) return Ll - 1 - l;
  int lr = Ll - 1 - l; return (lr % 48) * 48 + lr / 48;
}

// ---------------- xdbl = xpw[k] @ xs : per (bk,l) -> 38 outputs ----------------
__global__ void k_xdbl(const float* __restrict__ xc, const float* __restrict__ xpwT,
                       float* __restrict__ xdbl){
  int t = blockIdx.x * 256 + threadIdx.x;
  if (t >= 36864 * 38) return;
  int j = t % 38; int row = t / 38;            // row = bk*L + l
  int l = row % Ll; int bk = row / Ll; int k = bk & 3; int b = bk >> 2;
  int pix = pix_of(k, l);
  const float* xrow = xc + (size_t)(b * Ll + pix) * DIn;
  float acc = 0.f;
  for (int dd = 0; dd < DIn; ++dd)
    acc = fmaf(xpwT[dd * 152 + k * 38 + j], xrow[dd], acc);
  xdbl[(size_t)row * 38 + j] = acc;
}

// ---------------- delta = softplus(dts @ dtw^T + dtb) ----------------
__global__ void k_delta(const float* __restrict__ xdbl, const float* __restrict__ dtwT,
                        const float* __restrict__ dtb, float* __restrict__ delta){
  int t = blockIdx.x * 256 + threadIdx.x;
  if (t >= 36864 * DIn) return;
  int d = t % DIn; int row = t / DIn;
  int k = (row / Ll) & 3;
  const float* xr = xdbl + (size_t)row * 38;
  float acc = dtb[k * DIn + d];
  for (int r = 0; r < Rr; ++r)
    acc = fmaf(dtwT[r * 768 + k * DIn + d], xr[r], acc);
  float sp = fmaxf(acc, 0.f) + log1pf(__expf(-fabsf(acc)));
  delta[(size_t)row * DIn + d] = sp;
}

// ---------------- selective scan: 192 blocks x 64 threads (1 wave/block) ----------------
// lane = ch*4 + ns: ch in [0,16) local channel, ns in [0,4) handles 4 of the 16 states
__global__ __launch_bounds__(64) void k_scan(const float* __restrict__ delta, const float* __restrict__ xdbl,
                                             const float* __restrict__ xc, const float* __restrict__ Alog,
                                             float* __restrict__ oy){
  int blk = blockIdx.x; int g = blk % 12; int bk = blk / 12; int k = bk & 3; int b = bk >> 2;
  int lane = threadIdx.x; int ch = lane >> 2; int ns = lane & 3;
  int d = g * 16 + ch; int nb = ns * 4;
  const int arow = (k * DIn + d) * 16 + nb;
  float A0 = -__expf(Alog[arow + 0]);
  float A1 = -__expf(Alog[arow + 1]);
  float A2 = -__expf(Alog[arow + 2]);
  float A3 = -__expf(Alog[arow + 3]);
  float h0 = 0.f, h1 = 0.f, h2 = 0.f, h3 = 0.f;

  __shared__ __align__(16) float s_dt[2][CL][16];
  __shared__ __align__(16) float s_u [2][CL][16];
  __shared__ __align__(16) float s_bc[2][CL][32];

  const float* dbase = delta + (size_t)bk * Ll * DIn + g * 16;
  const float* xbase = xdbl  + (size_t)bk * Ll * 38 + 6;     // Bs at +6, Cs at +22
  const float* cbase = xc    + (size_t)b  * Ll * DIn + g * 16;
  float*       obase = oy    + (size_t)bk * Ll * DIn + d;

  float r_dt[8], r_u[8], r_bc[16];

  auto load_chunk = [&](int l0){
    #pragma unroll
    for (int it = 0; it < 8; ++it){
      int idx = it * 64 + lane; int lp = idx >> 4; int cc = idx & 15;
      r_dt[it] = dbase[(l0 + lp) * DIn + cc];
      r_u [it] = cbase[pix_of(k, l0 + lp) * DIn + cc];
    }
    #pragma unroll
    for (int it = 0; it < 16; ++it){
      int idx = it * 64 + lane; int lp = idx >> 5; int cc = idx & 31;
      r_bc[it] = xbase[(l0 + lp) * 38 + cc];
    }
  };
  auto write_chunk = [&](int buf){
    #pragma unroll
    for (int it = 0; it < 8; ++it){
      int idx = it * 64 + lane;
      ((float*)s_dt[buf])[idx] = r_dt[it];
      ((float*)s_u [buf])[idx] = r_u [it];
    }
    #pragma unroll
    for (int it = 0; it < 16; ++it){
      int idx = it * 64 + lane;
      ((float*)s_bc[buf])[idx] = r_bc[it];
    }
  };

  load_chunk(0);
  write_chunk(0);
  __syncthreads();
  load_chunk(CL);   // prefetch chunk 1 into registers

  for (int c0 = 0; c0 < Ll; c0 += CL){
    int buf = (c0 / CL) & 1;
    #pragma unroll 4
    for (int lp = 0; lp < CL; ++lp){
      float dt = s_dt[buf][lp][ch];
      float u  = s_u [buf][lp][ch];
      float4 Bv = *(const float4*)&s_bc[buf][lp][nb];
      float4 Cv = *(const float4*)&s_bc[buf][lp][16 + nb];
      float du = dt * u;
      h0 = fmaf(h0, __expf(dt * A0), du * Bv.x);
      h1 = fmaf(h1, __expf(dt * A1), du * Bv.y);
      h2 = fmaf(h2, __expf(dt * A2), du * Bv.z);
      h3 = fmaf(h3, __expf(dt * A3), du * Bv.w);
      float yp = fmaf(h0, Cv.x, fmaf(h1, Cv.y, fmaf(h2, Cv.z, h3 * Cv.w)));
      yp += __shfl_xor(yp, 1);
      yp += __shfl_xor(yp, 2);
      if (ns == 0) obase[(size_t)(c0 + lp) * DIn] = yp;
    }
    __syncthreads();
    if (c0 + CL < Ll){
      write_chunk(buf ^ 1);          // regs from loads issued one chunk ago
      __syncthreads();
      if (c0 + 2 * CL < Ll) load_chunk(c0 + 2 * CL);
    }
  }
}

// ---------------- block reductions ----------------
__device__ inline float block_sum_192(float* red, int d, float v){
  red[d] = v; __syncthreads();
  if (d < 96) red[d] += red[d + 96]; __syncthreads();
  if (d < 48) red[d] += red[d + 48]; __syncthreads();
  if (d < 24) red[d] += red[d + 24]; __syncthreads();
  if (d < 12) red[d] += red[d + 12]; __syncthreads();
  if (d < 6)  red[d] += red[d + 6];  __syncthreads();
  float tot = red[0] + red[1] + red[2] + red[3] + red[4] + red[5];
  __syncthreads();
  return tot;
}
__device__ inline float block_sum_96(float* red, int d, float v){
  if (d < 96) red[d] = v; __syncthreads();
  if (d < 48) red[d] += red[d + 48]; __syncthreads();
  if (d < 24) red[d] += red[d + 24]; __syncthreads();
  if (d < 12) red[d] += red[d + 12]; __syncthreads();
  if (d < 6)  red[d] += red[d + 6];  __syncthreads();
  float tot = red[0] + red[1] + red[2] + red[3] + red[4] + red[5];
  __syncthreads();
  return tot;
}

// ---------------- combine 4 directions + LN(192) + z-gate + out-proj + add + LN(96) ----------------
__global__ void k_combine(const float* __restrict__ oy, const float* __restrict__ xc,
                          const float* __restrict__ z, const float* __restrict__ Dp,
                          const float* __restrict__ ong, const float* __restrict__ onb,
                          const float* __restrict__ owT, const float* __restrict__ x2g,
                          const float* __restrict__ lng, const float* __restrict__ lnb,
                          float* __restrict__ crmin){
  int p = blockIdx.x; int b = p / Ll; int pp = p - b * Ll;
  int r = pp / Ww; int cx = pp - r * Ww;
  int d = threadIdx.x;
  __shared__ float red[192];
  __shared__ float ygv[192];
  int l1 = cx * 48 + r;
  size_t base = (size_t)(b * 4) * Ll * DIn;
  float yv = oy[base + (size_t)(0 * Ll + pp)            * DIn + d]
           + oy[base + (size_t)(1 * Ll + l1)            * DIn + d]
           + oy[base + (size_t)(2 * Ll + (Ll - 1 - pp)) * DIn + d]
           + oy[base + (size_t)(3 * Ll + (Ll - 1 - l1)) * DIn + d];
  float u = xc[(size_t)(b * Ll + pp) * DIn + d];
  float Ds = Dp[d] + Dp[192 + d] + Dp[384 + d] + Dp[576 + d];
  yv = fmaf(u, Ds, yv);
  // LayerNorm over 192
  float mu = block_sum_192(red, d, yv) * (1.f / 192.f);
  float dv = yv - mu;
  float var = block_sum_192(red, d, dv * dv) * (1.f / 192.f);
  float yn = dv * rsqrtf(var + 1e-5f) * ong[d] + onb[d];
  float zv = z[(size_t)(b * Ll + pp) * DIn + d];
  ygv[d] = yn * (zv * sigmf(zv));
  __syncthreads();
  // out-proj 192 -> 96, add gated branch
  float sval = 0.f;
  if (d < 96){
    float acc = 0.f;
    for (int dd = 0; dd < 192; ++dd) acc = fmaf(owT[dd * 96 + d], ygv[dd], acc);
    sval = acc + x2g[(size_t)p * CHn + d];
  }
  // LayerNorm over 96 channels
  float mu2 = block_sum_96(red, d, sval) * (1.f / 96.f);
  float dv2 = sval - mu2;
  float var2 = block_sum_96(red, d, (d < 96) ? dv2 * dv2 : 0.f) * (1.f / 96.f);
  if (d < 96)
    crmin[(size_t)p * CHn + d] = dv2 * rsqrtf(var2 + 1e-5f) * lng[d] + lnb[d];
}

// ---------------- CRM squeeze convs: up(24) | low(24) ----------------
__global__ void k_ul(const float* __restrict__ crmin, const float* __restrict__ sq1T,
                     const float* __restrict__ sq2T, float* __restrict__ ul){
  int t = blockIdx.x * 256 + threadIdx.x;
  if (t >= Pp * 48) return;
  int o = t % 48; int p = t / 48;
  const float* xr = crmin + (size_t)p * CHn;
  float acc = 0.f;
  if (o < 24){
    for (int i = 0; i < 48; ++i) acc = fmaf(sq1T[i * 24 + o], xr[i], acc);
  } else {
    int oo = o - 24;
    for (int i = 0; i < 48; ++i) acc = fmaf(sq2T[i * 24 + oo], xr[48 + i], acc);
  }
  ul[t] = acc;
}

// ---------------- CRM main: Y = [gwc(up)+pwc1(up) | pwc2(low) | low] ----------------
__global__ void k_y(const float* __restrict__ ul, const float* __restrict__ gwcT,
                    const float* __restrict__ gwcb, const float* __restrict__ pwc1T,
                    const float* __restrict__ pwc2T, float* __restrict__ Ybig){
  int p = blockIdx.x; int b = p / Ll; int pp = p - b * Ll;
  int r = pp / Ww; int cx = pp - r * Ww;
  int oc = threadIdx.x;
  __shared__ float ulv[48];
  if (oc < 48) ulv[oc] = ul[(size_t)p * 48 + oc];
  __syncthreads();
  float acc;
  if (oc < 96){
    acc = gwcb[oc];
    int grp = oc / 48;
    for (int dy = -1; dy <= 1; ++dy){
      int ny = r + dy; if ((unsigned)ny >= Hh) continue;
      for (int dx = -1; dx <= 1; ++dx){
        int nx = cx + dx; if ((unsigned)nx >= Ww) continue;
        const float* un = ul + (size_t)((b * Ll) + ny * Ww + nx) * 48 + grp * 12;
        int k9 = (dy + 1) * 3 + (dx + 1);
        #pragma unroll
        for (int i = 0; i < 12; ++i) acc = fmaf(gwcT[(i * 9 + k9) * 96 + oc], un[i], acc);
      }
    }
    for (int i = 0; i < 24; ++i) acc = fmaf(pwc1T[i * 96 + oc], ulv[i], acc);
  } else if (oc < 168){
    int o2 = oc - 96; acc = 0.f;
    for (int i = 0; i < 24; ++i) acc = fmaf(pwc2T[i * 72 + o2], ulv[24 + i], acc);
  } else {
    acc = ulv[24 + oc - 168];
  }
  Ybig[(size_t)p * 192 + oc] = acc;
}

// ---------------- per-(b,channel) spatial mean ----------------
__global__ void k_csum(const float* __restrict__ Ybig, float* __restrict__ csum){
  int bo = blockIdx.x; int b = bo / 192; int oc = bo - b * 192;
  float acc = 0.f;
  for (int pp = threadIdx.x; pp < Ll; pp += 256)
    acc += Ybig[(size_t)(b * Ll + pp) * 192 + oc];
  __shared__ float red[256];
  red[threadIdx.x] = acc; __syncthreads();
  for (int s = 128; s > 0; s >>= 1){
    if (threadIdx.x < s) red[threadIdx.x] += red[threadIdx.x + s];
    __syncthreads();
  }
  if (threadIdx.x == 0) csum[bo] = red[0] * (1.f / 2304.f);
}

// ---------------- softmax over 192 channels of the means ----------------
__global__ void k_softmax(const float* __restrict__ csum, float* __restrict__ wsm){
  int b = blockIdx.x; int t = threadIdx.x;
  __shared__ float red[192];
  float m = csum[b * 192 + t];
  red[t] = m; __syncthreads();
  if (t < 96) red[t] = fmaxf(red[t], red[t + 96]); __syncthreads();
  if (t < 48) red[t] = fmaxf(red[t], red[t + 48]); __syncthreads();
  if (t < 24) red[t] = fmaxf(red[t], red[t + 24]); __syncthreads();
  if (t < 12) red[t] = fmaxf(red[t], red[t + 12]); __syncthreads();
  if (t < 6)  red[t] = fmaxf(red[t], red[t + 6]);  __syncthreads();
  float mx = fmaxf(fmaxf(fmaxf(red[0], red[1]), fmaxf(red[2], red[3])), fmaxf(red[4], red[5]));
  __syncthreads();
  float e = __expf(m - mx);
  float s = block_sum_192(red, t, e);
  wsm[b * 192 + t] = e / s;
}

// ---------------- weighted halves + final linear -> NCHW output ----------------
__global__ void k_final(const float* __restrict__ Ybig, const float* __restrict__ wsm,
                        const float* __restrict__ finT, const float* __restrict__ finb,
                        float* __restrict__ out){
  int p = blockIdx.x; int b = p / Ll; int pp = p - b * Ll;
  int c = threadIdx.x;
  __shared__ float ov[96];
  float o = wsm[b * 192 + c]      * Ybig[(size_t)p * 192 + c]
          + wsm[b * 192 + 96 + c] * Ybig[(size_t)p * 192 + 96 + c];
  ov[c] = o; __syncthreads();
  float acc = finb[c];
  for (int i = 0; i < 96; ++i) acc = fmaf(finT[i * 96 + c], ov[i], acc);
  out[(size_t)(b * 96 + c) * Ll + pp] = acc;
}

// ---------------- host launch ----------------
extern "C" void kernel_launch(void* const* d_in, const int* in_sizes, int n_in,
                              void* d_out, int out_size, void* d_ws, size_t ws_size,
                              hipStream_t stream) {
  const float* x     = (const float*)d_in[0];
  const float* w1    = (const float*)d_in[1];
  const float* b1    = (const float*)d_in[2];
  const float* bng   = (const float*)d_in[3];
  const float* bnb   = (const float*)d_in[4];
  const float* linw  = (const float*)d_in[5];
  const float* linb  = (const float*)d_in[6];
  const float* dw1w  = (const float*)d_in[7];
  const float* dw1b  = (const float*)d_in[8];
  const float* dw2w  = (const float*)d_in[9];
  const float* dw2b  = (const float*)d_in[10];
  const float* ag1w  = (const float*)d_in[11];
  const float* ag1b  = (const float*)d_in[12];
  const float* ag2w  = (const float*)d_in[13];
  const float* ag2b  = (const float*)d_in[14];
  const float* lng   = (const float*)d_in[15];
  const float* lnb   = (const float*)d_in[16];
  const float* sq1w  = (const float*)d_in[17];
  const float* sq2w  = (const float*)d_in[18];
  const float* gwcw  = (const float*)d_in[19];
  const float* gwcb  = (const float*)d_in[20];
  const float* pwc1w = (const float*)d_in[21];
  const float* pwc2w = (const float*)d_in[22];
  const float* finw  = (const float*)d_in[23];
  const float* finb  = (const float*)d_in[24];
  const float* inw   = (const float*)d_in[25];
  const float* scw   = (const float*)d_in[26];
  const float* scb   = (const float*)d_in[27];
  const float* xpw   = (const float*)d_in[28];
  const float* dtw   = (const float*)d_in[29];
  const float* dtb   = (const float*)d_in[30];
  const float* Alog  = (const float*)d_in[31];
  const float* Dp    = (const float*)d_in[32];
  const float* ong   = (const float*)d_in[33];
  const float* onb   = (const float*)d_in[34];
  const float* oww   = (const float*)d_in[35];

  float* ws = (float*)d_ws;
  // main buffers (floats)
  float* hlin  = ws + 0;         // 884736 ; reused as ul after k_dw
  float* x1pre = ws + 884736;    // 884736 ; reused as csum/wsm after k_ssin
  float* x2    = ws + 1769472;   // 884736 ; reused as crmin after k_gate
  float* x2g   = ws + 2654208;   // 884736
  float* xibuf = ws + 3538944;   // 1769472 ; reused as Ybig after k_ssdw
  float* zbuf  = ws + 5308416;   // 1769472
  float* xcbuf = ws + 7077888;   // 1769472
  float* delta = ws + 8847360;   // 7077888
  float* xdbl  = ws + 15925248;  // 1400832
  float* oy    = ws + 17326080;  // 7077888
  float* ulb   = hlin;           // 442368 (alias)
  float* crmin = x2;             // 884736 (alias)
  float* Ybig  = xibuf;          // 1769472 (alias)
  float* csum  = x1pre;          // 768 (alias)
  float* wsmb  = x1pre + 768;    // 768 (alias)
  // transposed weights region
  float* wT = ws + 24403968;     // 142656 floats total -> ws end ~93.7 MB
  float* w1T   = wT + 0;
  float* linT  = wT + 9216;
  float* ag1T  = wT + 18432;
  float* ag2T  = wT + 23040;
  float* inT   = wT + 27648;
  float* owT   = wT + 64512;
  float* pwc1T = wT + 82944;
  float* pwc2T = wT + 85248;
  float* finT  = wT + 86976;
  float* sq1T  = wT + 96192;
  float* sq2T  = wT + 97344;
  float* gwcT  = wT + 98496;
  float* dtwT  = wT + 108864;
  float* xpwT  = wT + 113472;

  TArgs ta;
  const float* srcs[14] = {w1, linw, ag1w, ag2w, inw, oww, pwc1w, pwc2w, finw, sq1w, sq2w, gwcw, dtw, xpw};
  float* dsts[14]       = {w1T, linT, ag1T, ag2T, inT, owT, pwc1T, pwc2T, finT, sq1T, sq2T, gwcT, dtwT, xpwT};
  int rows[14] = {96, 96, 48, 96, 384, 96, 96, 72, 96, 24, 24, 96, 768, 152};
  int cols[14] = {96, 96, 96, 48, 96, 192, 24, 24, 96, 48, 48, 108, 6, 192};
  for (int i = 0; i < 14; ++i){ ta.s[i] = srcs[i]; ta.d[i] = dsts[i]; ta.rows[i] = rows[i]; ta.cols[i] = cols[i]; }

  k_tr<<<dim3(144, 14), 256, 0, stream>>>(ta);
  k_pre<<<Pp, CHn, 0, stream>>>(x, w1T, b1, bng, bnb, linT, linb, hlin);
  k_dw<<<(Pp * CHn) / 256, 256, 0, stream>>>(hlin, dw1w, dw1b, dw2w, dw2b, x1pre, x2);
  k_gate<<<Pp, CHn, 0, stream>>>(x2, ag1T, ag1b, ag2T, ag2b, x2g);
  k_ssin<<<Pp, DIn, 0, stream>>>(x1pre, inT, xibuf, zbuf);
  k_ssdw<<<(Pp * DIn) / 256, 256, 0, stream>>>(xibuf, scw, scb, xcbuf);
  k_xdbl<<<(36864 * 38) / 256, 256, 0, stream>>>(xcbuf, xpwT, xdbl);
  k_delta<<<(36864 * DIn) / 256, 256, 0, stream>>>(xdbl, dtwT, dtb, delta);
  k_scan<<<192, 64, 0, stream>>>(delta, xdbl, xcbuf, Alog, oy);
  k_combine<<<Pp, DIn, 0, stream>>>(oy, xcbuf, zbuf, Dp, ong, onb, owT, x2g, lng, lnb, crmin);
  k_ul<<<(Pp * 48) / 256, 256, 0, stream>>>(crmin, sq1T, sq2T, ulb);
  k_y<<<Pp, 192, 0, stream>>>(ulb, gwcT, gwcb, pwc1T, pwc2T, Ybig);
  k_csum<<<768, 256, 0, stream>>>(Ybig, csum);
  k_softmax<<<4, 192, 0, stream>>>(csum, wsmb);
  k_final<<<Pp, CHn, 0, stream>>>(Ybig, wsmb, finT, finb, (float*)d_out);
}

// Round 2
// 488.383 us; speedup vs baseline: 1.6737x; 1.6737x over previous
//
#include <hip/hip_runtime.h>
#include <hip/hip_bf16.h>

// Problem constants
#define Bn   4
#define CHn  96
#define Hh   48
#define Ww   48
#define Ll   2304      // H*W
#define Pp   9216      // B*L
#define DIn  192
#define Nn   16
#define Rr   6
#define Sseg   16      // scan segments per sequence
#define SEGLEN 144     // 2304 / 16
#define SC      8      // register prefetch sub-chunk

__device__ inline float siluf(float x){ return x / (1.0f + __expf(-x)); }
__device__ inline float sigmf(float x){ return 1.0f / (1.0f + __expf(-x)); }

// ---------------- transpose-all-weights kernel (one launch) ----------------
struct TArgs {
  const float* s[14];
  float* d[14];
  int rows[14];
  int cols[14];
};
__global__ void k_tr(TArgs a){
  int id = blockIdx.y;
  int n = a.rows[id] * a.cols[id];
  int t = blockIdx.x * blockDim.x + threadIdx.x;
  if (t < n){
    int r = t / a.cols[id];
    int c = t - r * a.cols[id];
    a.d[id][c * a.rows[id] + r] = a.s[id][t];
  }
}

// ---------------- conv1x1 + BN + ReLU + channel linear ----------------
__global__ void k_pre(const float* __restrict__ x, const float* __restrict__ w1T, const float* __restrict__ b1,
                      const float* __restrict__ bng, const float* __restrict__ bnb,
                      const float* __restrict__ linT, const float* __restrict__ lb,
                      float* __restrict__ hlin){
  int p = blockIdx.x; int b = p / Ll; int pp = p - b * Ll;
  int c = threadIdx.x;
  __shared__ float xv[CHn];
  __shared__ float hv[CHn];
  xv[c] = x[(size_t)(b * CHn + c) * Ll + pp];
  __syncthreads();
  float acc = 0.f;
  for (int i = 0; i < CHn; ++i) acc = fmaf(w1T[i * CHn + c], xv[i], acc);
  float s = bng[c] * rsqrtf(1.0f + 1e-5f);
  float h = fmaxf((acc + b1[c]) * s + bnb[c], 0.f);
  hv[c] = h;
  __syncthreads();
  float a2 = lb[c];
  for (int i = 0; i < CHn; ++i) a2 = fmaf(linT[i * CHn + c], hv[i], a2);
  hlin[(size_t)p * CHn + c] = a2;
}

// ---------------- two depthwise 3x3 convs + SiLU ----------------
__global__ void k_dw(const float* __restrict__ hlin,
                     const float* __restrict__ dw1w, const float* __restrict__ dw1b,
                     const float* __restrict__ dw2w, const float* __restrict__ dw2b,
                     float* __restrict__ x1pre, float* __restrict__ x2){
  int t = blockIdx.x * 256 + threadIdx.x;
  if (t >= Pp * CHn) return;
  int c = t % CHn; int p = t / CHn; int b = p / Ll; int pp = p - b * Ll;
  int r = pp / Ww; int cx = pp - r * Ww;
  float a1 = dw1b[c], a2 = dw2b[c];
  for (int dy = -1; dy <= 1; ++dy){
    int ny = r + dy; if ((unsigned)ny >= Hh) continue;
    for (int dx = -1; dx <= 1; ++dx){
      int nx = cx + dx; if ((unsigned)nx >= Ww) continue;
      float v = hlin[(size_t)((b * Ll) + ny * Ww + nx) * CHn + c];
      int wi = c * 9 + (dy + 1) * 3 + (dx + 1);
      a1 = fmaf(dw1w[wi], v, a1);
      a2 = fmaf(dw2w[wi], v, a2);
    }
  }
  x1pre[t] = siluf(a1);
  x2[t]   = siluf(a2);
}

// ---------------- attention gate: sigmoid(ag2(relu(ag1 x2))) * x2 ----------------
__global__ void k_gate(const float* __restrict__ x2,
                       const float* __restrict__ ag1T, const float* __restrict__ ag1b,
                       const float* __restrict__ ag2T, const float* __restrict__ ag2b,
                       float* __restrict__ x2g){
  int p = blockIdx.x; int c = threadIdx.x;
  __shared__ float xv[CHn];
  __shared__ float rv[48];
  xv[c] = x2[(size_t)p * CHn + c];
  __syncthreads();
  if (c < 48){
    float a = ag1b[c];
    for (int i = 0; i < CHn; ++i) a = fmaf(ag1T[i * 48 + c], xv[i], a);
    rv[c] = fmaxf(a, 0.f);
  }
  __syncthreads();
  float a2 = ag2b[c];
  for (int tt = 0; tt < 48; ++tt) a2 = fmaf(ag2T[tt * CHn + c], rv[tt], a2);
  x2g[(size_t)p * CHn + c] = xv[c] * sigmf(a2);
}

// ---------------- SS2D input projection: 96 -> 384 (xi | z) ----------------
__global__ void k_ssin(const float* __restrict__ x1pre, const float* __restrict__ inT,
                       float* __restrict__ xi, float* __restrict__ z){
  int p = blockIdx.x; int j = threadIdx.x; // j < 192
  __shared__ float xv[CHn];
  if (j < CHn) xv[j] = x1pre[(size_t)p * CHn + j];
  __syncthreads();
  float a0 = 0.f, a1 = 0.f;
  for (int i = 0; i < CHn; ++i){
    float v = xv[i];
    a0 = fmaf(inT[i * 384 + j],        v, a0);
    a1 = fmaf(inT[i * 384 + 192 + j],  v, a1);
  }
  xi[(size_t)p * DIn + j] = a0;
  z [(size_t)p * DIn + j] = a1;
}

// ---------------- SS2D depthwise 3x3 + SiLU ----------------
__global__ void k_ssdw(const float* __restrict__ xi, const float* __restrict__ scw,
                       const float* __restrict__ scb, float* __restrict__ xc){
  int t = blockIdx.x * 256 + threadIdx.x;
  if (t >= Pp * DIn) return;
  int d = t % DIn; int p = t / DIn; int b = p / Ll; int pp = p - b * Ll;
  int r = pp / Ww; int cx = pp - r * Ww;
  float a = scb[d];
  for (int dy = -1; dy <= 1; ++dy){
    int ny = r + dy; if ((unsigned)ny >= Hh) continue;
    for (int dx = -1; dx <= 1; ++dx){
      int nx = cx + dx; if ((unsigned)nx >= Ww) continue;
      float v = xi[(size_t)((b * Ll) + ny * Ww + nx) * DIn + d];
      a = fmaf(scw[d * 9 + (dy + 1) * 3 + (dx + 1)], v, a);
    }
  }
  xc[t] = siluf(a);
}

__device__ inline int pix_of(int k, int l){
  if (k == 0) return l;
  if (k == 1) return (l % 48) * 48 + l / 48;
  if (k == 2) return Ll - 1 - l;
  int lr = Ll - 1 - l; return (lr % 48) * 48 + lr / 48;
}

// ---------------- xdbl: per (bk,l) -> dts[6] (rank) + bc[32] (B|C padded/aligned) ----------------
__global__ void k_xdbl(const float* __restrict__ xc, const float* __restrict__ xpwT,
                       float* __restrict__ dts, float* __restrict__ bc){
  int t = blockIdx.x * 256 + threadIdx.x;
  if (t >= 36864 * 38) return;
  int j = t % 38; int row = t / 38;            // row = bk*L + l
  int l = row % Ll; int bk = row / Ll; int k = bk & 3; int b = bk >> 2;
  int pix = pix_of(k, l);
  const float* xrow = xc + (size_t)(b * Ll + pix) * DIn;
  float acc = 0.f;
  for (int dd = 0; dd < DIn; ++dd)
    acc = fmaf(xpwT[dd * 152 + k * 38 + j], xrow[dd], acc);
  if (j < 6) dts[(size_t)row * 6 + j] = acc;
  else       bc [(size_t)row * 32 + (j - 6)] = acc;
}

// ---------------- delta = softplus(dts @ dtw^T + dtb) ----------------
__global__ void k_delta(const float* __restrict__ dts, const float* __restrict__ dtwT,
                        const float* __restrict__ dtb, float* __restrict__ delta){
  int t = blockIdx.x * 256 + threadIdx.x;
  if (t >= 36864 * DIn) return;
  int d = t % DIn; int row = t / DIn;
  int k = (row / Ll) & 3;
  const float* xr = dts + (size_t)row * 6;
  float acc = dtb[k * DIn + d];
  for (int r = 0; r < Rr; ++r)
    acc = fmaf(dtwT[r * 768 + k * DIn + d], xr[r], acc);
  float sp = fmaxf(acc, 0.f) + log1pf(__expf(-fabsf(acc)));
  delta[(size_t)row * DIn + d] = sp;
}

// ======================= segmented selective scan =======================
// unit = bk*12+g : 192 independent (sequence, 16-channel-group) units.
// lane = ch*4 + ns : ch local channel [0,16), ns handles 4 of 16 states.

// ---- pass A: local scan per segment (h0=0), emit h_end + sum(dt) ----
__global__ __launch_bounds__(64) void k_scanA(const float* __restrict__ delta, const float* __restrict__ bc,
                                              const float* __restrict__ xc, const float* __restrict__ Alog,
                                              float* __restrict__ hend, float* __restrict__ dtsum){
  int blk = blockIdx.x; int unit = blk / Sseg; int seg = blk - unit * Sseg;
  int g = unit % 12; int bk = unit / 12; int k = bk & 3; int b = bk >> 2;
  int lane = threadIdx.x; int ch = lane >> 2; int ns = lane & 3; int nb = ns * 4;
  int d = g * 16 + ch;
  const int arow = (k * DIn + d) * 16 + nb;
  float A0 = -__expf(Alog[arow + 0]);
  float A1 = -__expf(Alog[arow + 1]);
  float A2 = -__expf(Alog[arow + 2]);
  float A3 = -__expf(Alog[arow + 3]);
  float h0 = 0.f, h1 = 0.f, h2 = 0.f, h3 = 0.f, dacc = 0.f;

  const int l0 = seg * SEGLEN;
  const float* dptr = delta + (size_t)(bk * Ll) * DIn + g * 16 + ch;
  const float* bptr = bc    + (size_t)(bk * Ll) * 32 + nb;
  const float* cxb  = xc    + (size_t)(b  * Ll) * DIn + g * 16 + ch;

  float dtA[SC], uA[SC]; float4 BA[SC];
  float dtB[SC], uB[SC]; float4 BB[SC];

  auto load = [&](float (&dtv)[SC], float (&uv)[SC], float4 (&Bv)[SC], int ls){
    #pragma unroll
    for (int i = 0; i < SC; ++i){
      int l = ls + i;
      dtv[i] = dptr[(size_t)l * DIn];
      Bv[i]  = *(const float4*)(bptr + (size_t)l * 32);
      int pix;
      if (k == 0) pix = l;
      else if (k == 2) pix = Ll - 1 - l;
      else { int l2 = (k == 1) ? l : (Ll - 1 - l); pix = (l2 % 48) * 48 + l2 / 48; }
      uv[i] = cxb[(size_t)pix * DIn];
    }
  };

  load(dtA, uA, BA, l0);
  int lcur = l0;
  #pragma unroll 1
  for (int cc = 0; cc < SEGLEN / (2 * SC); ++cc){
    load(dtB, uB, BB, lcur + SC);
    #pragma unroll
    for (int i = 0; i < SC; ++i){
      float dt = dtA[i]; dacc += dt;
      float du = dt * uA[i];
      h0 = fmaf(h0, __expf(dt * A0), du * BA[i].x);
      h1 = fmaf(h1, __expf(dt * A1), du * BA[i].y);
      h2 = fmaf(h2, __expf(dt * A2), du * BA[i].z);
      h3 = fmaf(h3, __expf(dt * A3), du * BA[i].w);
    }
    if (cc < SEGLEN / (2 * SC) - 1) load(dtA, uA, BA, lcur + 2 * SC);
    #pragma unroll
    for (int i = 0; i < SC; ++i){
      float dt = dtB[i]; dacc += dt;
      float du = dt * uB[i];
      h0 = fmaf(h0, __expf(dt * A0), du * BB[i].x);
      h1 = fmaf(h1, __expf(dt * A1), du * BB[i].y);
      h2 = fmaf(h2, __expf(dt * A2), du * BB[i].z);
      h3 = fmaf(h3, __expf(dt * A3), du * BB[i].w);
    }
    lcur += 2 * SC;
  }
  size_t sb = (size_t)unit * Sseg + seg;
  *(float4*)&hend[sb * 256 + lane * 4] = make_float4(h0, h1, h2, h3);
  if (ns == 0) dtsum[sb * 16 + ch] = dacc;
}

// ---- combine: sequential fold over segments -> h_init per segment ----
__global__ __launch_bounds__(64) void k_comb(const float* __restrict__ Alog, const float* __restrict__ hend,
                                             const float* __restrict__ dtsum, float* __restrict__ hinit){
  int unit = blockIdx.x; int g = unit % 12; int bk = unit / 12; int k = bk & 3;
  int lane = threadIdx.x; int ch = lane >> 2; int ns = lane & 3; int nb = ns * 4;
  int d = g * 16 + ch;
  const int arow = (k * DIn + d) * 16 + nb;
  float A0 = -__expf(Alog[arow + 0]);
  float A1 = -__expf(Alog[arow + 1]);
  float A2 = -__expf(Alog[arow + 2]);
  float A3 = -__expf(Alog[arow + 3]);
  float h0 = 0.f, h1 = 0.f, h2 = 0.f, h3 = 0.f;
  for (int s = 0; s < Sseg; ++s){
    size_t sb = (size_t)unit * Sseg + s;
    *(float4*)&hinit[sb * 256 + lane * 4] = make_float4(h0, h1, h2, h3);
    float ds = dtsum[sb * 16 + ch];
    float4 he = *(const float4*)&hend[sb * 256 + lane * 4];
    h0 = fmaf(h0, __expf(A0 * ds), he.x);
    h1 = fmaf(h1, __expf(A1 * ds), he.y);
    h2 = fmaf(h2, __expf(A2 * ds), he.z);
    h3 = fmaf(h3, __expf(A3 * ds), he.w);
  }
}

// ---- pass B: rescan from h_init, emit y ----
__global__ __launch_bounds__(64) void k_scanB(const float* __restrict__ delta, const float* __restrict__ bc,
                                              const float* __restrict__ xc, const float* __restrict__ Alog,
                                              const float* __restrict__ hinit, float* __restrict__ oy){
  int blk = blockIdx.x; int unit = blk / Sseg; int seg = blk - unit * Sseg;
  int g = unit % 12; int bk = unit / 12; int k = bk & 3; int b = bk >> 2;
  int lane = threadIdx.x; int ch = lane >> 2; int ns = lane & 3; int nb = ns * 4;
  int d = g * 16 + ch;
  const int arow = (k * DIn + d) * 16 + nb;
  float A0 = -__expf(Alog[arow + 0]);
  float A1 = -__expf(Alog[arow + 1]);
  float A2 = -__expf(Alog[arow + 2]);
  float A3 = -__expf(Alog[arow + 3]);
  size_t sb = (size_t)unit * Sseg + seg;
  float4 hi = *(const float4*)&hinit[sb * 256 + lane * 4];
  float h0 = hi.x, h1 = hi.y, h2 = hi.z, h3 = hi.w;

  const int l0 = seg * SEGLEN;
  const float* dptr = delta + (size_t)(bk * Ll) * DIn + g * 16 + ch;
  const float* bptr = bc    + (size_t)(bk * Ll) * 32 + nb;
  const float* cxb  = xc    + (size_t)(b  * Ll) * DIn + g * 16 + ch;
  float*       obase = oy   + (size_t)(bk * Ll) * DIn + d;

  float dtA[SC], uA[SC]; float4 BA[SC], CA[SC];
  float dtB[SC], uB[SC]; float4 BB[SC], CB[SC];

  auto load = [&](float (&dtv)[SC], float (&uv)[SC], float4 (&Bv)[SC], float4 (&Cv)[SC], int ls){
    #pragma unroll
    for (int i = 0; i < SC; ++i){
      int l = ls + i;
      dtv[i] = dptr[(size_t)l * DIn];
      Bv[i]  = *(const float4*)(bptr + (size_t)l * 32);
      Cv[i]  = *(const float4*)(bptr + (size_t)l * 32 + 16);
      int pix;
      if (k == 0) pix = l;
      else if (k == 2) pix = Ll - 1 - l;
      else { int l2 = (k == 1) ? l : (Ll - 1 - l); pix = (l2 % 48) * 48 + l2 / 48; }
      uv[i] = cxb[(size_t)pix * DIn];
    }
  };

  load(dtA, uA, BA, CA, l0);
  int lcur = l0;
  #pragma unroll 1
  for (int cc = 0; cc < SEGLEN / (2 * SC); ++cc){
    load(dtB, uB, BB, CB, lcur + SC);
    #pragma unroll
    for (int i = 0; i < SC; ++i){
      float dt = dtA[i];
      float du = dt * uA[i];
      h0 = fmaf(h0, __expf(dt * A0), du * BA[i].x);
      h1 = fmaf(h1, __expf(dt * A1), du * BA[i].y);
      h2 = fmaf(h2, __expf(dt * A2), du * BA[i].z);
      h3 = fmaf(h3, __expf(dt * A3), du * BA[i].w);
      float yp = fmaf(h0, CA[i].x, fmaf(h1, CA[i].y, fmaf(h2, CA[i].z, h3 * CA[i].w)));
      yp += __shfl_xor(yp, 1);
      yp += __shfl_xor(yp, 2);
      if (ns == 0) obase[(size_t)(lcur + i) * DIn] = yp;
    }
    if (cc < SEGLEN / (2 * SC) - 1) load(dtA, uA, BA, CA, lcur + 2 * SC);
    #pragma unroll
    for (int i = 0; i < SC; ++i){
      float dt = dtB[i];
      float du = dt * uB[i];
      h0 = fmaf(h0, __expf(dt * A0), du * BB[i].x);
      h1 = fmaf(h1, __expf(dt * A1), du * BB[i].y);
      h2 = fmaf(h2, __expf(dt * A2), du * BB[i].z);
      h3 = fmaf(h3, __expf(dt * A3), du * BB[i].w);
      float yp = fmaf(h0, CB[i].x, fmaf(h1, CB[i].y, fmaf(h2, CB[i].z, h3 * CB[i].w)));
      yp += __shfl_xor(yp, 1);
      yp += __shfl_xor(yp, 2);
      if (ns == 0) obase[(size_t)(lcur + SC + i) * DIn] = yp;
    }
    lcur += 2 * SC;
  }
}

// ---------------- block reductions ----------------
__device__ inline float block_sum_192(float* red, int d, float v){
  red[d] = v; __syncthreads();
  if (d < 96) red[d] += red[d + 96]; __syncthreads();
  if (d < 48) red[d] += red[d + 48]; __syncthreads();
  if (d < 24) red[d] += red[d + 24]; __syncthreads();
  if (d < 12) red[d] += red[d + 12]; __syncthreads();
  if (d < 6)  red[d] += red[d + 6];  __syncthreads();
  float tot = red[0] + red[1] + red[2] + red[3] + red[4] + red[5];
  __syncthreads();
  return tot;
}
__device__ inline float block_sum_96(float* red, int d, float v){
  if (d < 96) red[d] = v; __syncthreads();
  if (d < 48) red[d] += red[d + 48]; __syncthreads();
  if (d < 24) red[d] += red[d + 24]; __syncthreads();
  if (d < 12) red[d] += red[d + 12]; __syncthreads();
  if (d < 6)  red[d] += red[d + 6];  __syncthreads();
  float tot = red[0] + red[1] + red[2] + red[3] + red[4] + red[5];
  __syncthreads();
  return tot;
}

// ---------------- combine 4 directions + LN(192) + z-gate + out-proj + add + LN(96) ----------------
__global__ void k_combine(const float* __restrict__ oy, const float* __restrict__ xc,
                          const float* __restrict__ z, const float* __restrict__ Dp,
                          const float* __restrict__ ong, const float* __restrict__ onb,
                          const float* __restrict__ owT, const float* __restrict__ x2g,
                          const float* __restrict__ lng, const float* __restrict__ lnb,
                          float* __restrict__ crmin){
  int p = blockIdx.x; int b = p / Ll; int pp = p - b * Ll;
  int r = pp / Ww; int cx = pp - r * Ww;
  int d = threadIdx.x;
  __shared__ float red[192];
  __shared__ float ygv[192];
  int l1 = cx * 48 + r;
  size_t base = (size_t)(b * 4) * Ll * DIn;
  float yv = oy[base + (size_t)(0 * Ll + pp)            * DIn + d]
           + oy[base + (size_t)(1 * Ll + l1)            * DIn + d]
           + oy[base + (size_t)(2 * Ll + (Ll - 1 - pp)) * DIn + d]
           + oy[base + (size_t)(3 * Ll + (Ll - 1 - l1)) * DIn + d];
  float u = xc[(size_t)(b * Ll + pp) * DIn + d];
  float Ds = Dp[d] + Dp[192 + d] + Dp[384 + d] + Dp[576 + d];
  yv = fmaf(u, Ds, yv);
  float mu = block_sum_192(red, d, yv) * (1.f / 192.f);
  float dv = yv - mu;
  float var = block_sum_192(red, d, dv * dv) * (1.f / 192.f);
  float yn = dv * rsqrtf(var + 1e-5f) * ong[d] + onb[d];
  float zv = z[(size_t)(b * Ll + pp) * DIn + d];
  ygv[d] = yn * (zv * sigmf(zv));
  __syncthreads();
  float sval = 0.f;
  if (d < 96){
    float acc = 0.f;
    for (int dd = 0; dd < 192; ++dd) acc = fmaf(owT[dd * 96 + d], ygv[dd], acc);
    sval = acc + x2g[(size_t)p * CHn + d];
  }
  float mu2 = block_sum_96(red, d, sval) * (1.f / 96.f);
  float dv2 = sval - mu2;
  float var2 = block_sum_96(red, d, (d < 96) ? dv2 * dv2 : 0.f) * (1.f / 96.f);
  if (d < 96)
    crmin[(size_t)p * CHn + d] = dv2 * rsqrtf(var2 + 1e-5f) * lng[d] + lnb[d];
}

// ---------------- CRM squeeze convs: up(24) | low(24) ----------------
__global__ void k_ul(const float* __restrict__ crmin, const float* __restrict__ sq1T,
                     const float* __restrict__ sq2T, float* __restrict__ ul){
  int t = blockIdx.x * 256 + threadIdx.x;
  if (t >= Pp * 48) return;
  int o = t % 48; int p = t / 48;
  const float* xr = crmin + (size_t)p * CHn;
  float acc = 0.f;
  if (o < 24){
    for (int i = 0; i < 48; ++i) acc = fmaf(sq1T[i * 24 + o], xr[i], acc);
  } else {
    int oo = o - 24;
    for (int i = 0; i < 48; ++i) acc = fmaf(sq2T[i * 24 + oo], xr[48 + i], acc);
  }
  ul[t] = acc;
}

// ---------------- CRM main: Y = [gwc(up)+pwc1(up) | pwc2(low) | low] ----------------
__global__ void k_y(const float* __restrict__ ul, const float* __restrict__ gwcT,
                    const float* __restrict__ gwcb, const float* __restrict__ pwc1T,
                    const float* __restrict__ pwc2T, float* __restrict__ Ybig){
  int p = blockIdx.x; int b = p / Ll; int pp = p - b * Ll;
  int r = pp / Ww; int cx = pp - r * Ww;
  int oc = threadIdx.x;
  __shared__ float ulv[48];
  if (oc < 48) ulv[oc] = ul[(size_t)p * 48 + oc];
  __syncthreads();
  float acc;
  if (oc < 96){
    acc = gwcb[oc];
    int grp = oc / 48;
    for (int dy = -1; dy <= 1; ++dy){
      int ny = r + dy; if ((unsigned)ny >= Hh) continue;
      for (int dx = -1; dx <= 1; ++dx){
        int nx = cx + dx; if ((unsigned)nx >= Ww) continue;
        const float* un = ul + (size_t)((b * Ll) + ny * Ww + nx) * 48 + grp * 12;
        int k9 = (dy + 1) * 3 + (dx + 1);
        #pragma unroll
        for (int i = 0; i < 12; ++i) acc = fmaf(gwcT[(i * 9 + k9) * 96 + oc], un[i], acc);
      }
    }
    for (int i = 0; i < 24; ++i) acc = fmaf(pwc1T[i * 96 + oc], ulv[i], acc);
  } else if (oc < 168){
    int o2 = oc - 96; acc = 0.f;
    for (int i = 0; i < 24; ++i) acc = fmaf(pwc2T[i * 72 + o2], ulv[24 + i], acc);
  } else {
    acc = ulv[24 + oc - 168];
  }
  Ybig[(size_t)p * 192 + oc] = acc;
}

// ---------------- per-(b,channel) spatial mean ----------------
__global__ void k_csum(const float* __restrict__ Ybig, float* __restrict__ csum){
  int bo = blockIdx.x; int b = bo / 192; int oc = bo - b * 192;
  float acc = 0.f;
  for (int pp = threadIdx.x; pp < Ll; pp += 256)
    acc += Ybig[(size_t)(b * Ll + pp) * 192 + oc];
  __shared__ float red[256];
  red[threadIdx.x] = acc; __syncthreads();
  for (int s = 128; s > 0; s >>= 1){
    if (threadIdx.x < s) red[threadIdx.x] += red[threadIdx.x + s];
    __syncthreads();
  }
  if (threadIdx.x == 0) csum[bo] = red[0] * (1.f / 2304.f);
}

// ---------------- softmax over 192 channels of the means ----------------
__global__ void k_softmax(const float* __restrict__ csum, float* __restrict__ wsm){
  int b = blockIdx.x; int t = threadIdx.x;
  __shared__ float red[192];
  float m = csum[b * 192 + t];
  red[t] = m; __syncthreads();
  if (t < 96) red[t] = fmaxf(red[t], red[t + 96]); __syncthreads();
  if (t < 48) red[t] = fmaxf(red[t], red[t + 48]); __syncthreads();
  if (t < 24) red[t] = fmaxf(red[t], red[t + 24]); __syncthreads();
  if (t < 12) red[t] = fmaxf(red[t], red[t + 12]); __syncthreads();
  if (t < 6)  red[t] = fmaxf(red[t], red[t + 6]);  __syncthreads();
  float mx = fmaxf(fmaxf(fmaxf(red[0], red[1]), fmaxf(red[2], red[3])), fmaxf(red[4], red[5]));
  __syncthreads();
  float e = __expf(m - mx);
  float s = block_sum_192(red, t, e);
  wsm[b * 192 + t] = e / s;
}

// ---------------- weighted halves + final linear -> NCHW output ----------------
__global__ void k_final(const float* __restrict__ Ybig, const float* __restrict__ wsm,
                        const float* __restrict__ finT, const float* __restrict__ finb,
                        float* __restrict__ out){
  int p = blockIdx.x; int b = p / Ll; int pp = p - b * Ll;
  int c = threadIdx.x;
  __shared__ float ov[96];
  float o = wsm[b * 192 + c]      * Ybig[(size_t)p * 192 + c]
          + wsm[b * 192 + 96 + c] * Ybig[(size_t)p * 192 + 96 + c];
  ov[c] = o; __syncthreads();
  float acc = finb[c];
  for (int i = 0; i < 96; ++i) acc = fmaf(finT[i * 96 + c], ov[i], acc);
  out[(size_t)(b * 96 + c) * Ll + pp] = acc;
}

// ---------------- host launch ----------------
extern "C" void kernel_launch(void* const* d_in, const int* in_sizes, int n_in,
                              void* d_out, int out_size, void* d_ws, size_t ws_size,
                              hipStream_t stream) {
  const float* x     = (const float*)d_in[0];
  const float* w1    = (const float*)d_in[1];
  const float* b1    = (const float*)d_in[2];
  const float* bng   = (const float*)d_in[3];
  const float* bnb   = (const float*)d_in[4];
  const float* linw  = (const float*)d_in[5];
  const float* linb  = (const float*)d_in[6];
  const float* dw1w  = (const float*)d_in[7];
  const float* dw1b  = (const float*)d_in[8];
  const float* dw2w  = (const float*)d_in[9];
  const float* dw2b  = (const float*)d_in[10];
  const float* ag1w  = (const float*)d_in[11];
  const float* ag1b  = (const float*)d_in[12];
  const float* ag2w  = (const float*)d_in[13];
  const float* ag2b  = (const float*)d_in[14];
  const float* lng   = (const float*)d_in[15];
  const float* lnb   = (const float*)d_in[16];
  const float* sq1w  = (const float*)d_in[17];
  const float* sq2w  = (const float*)d_in[18];
  const float* gwcw  = (const float*)d_in[19];
  const float* gwcb  = (const float*)d_in[20];
  const float* pwc1w = (const float*)d_in[21];
  const float* pwc2w = (const float*)d_in[22];
  const float* finw  = (const float*)d_in[23];
  const float* finb  = (const float*)d_in[24];
  const float* inw   = (const float*)d_in[25];
  const float* scw   = (const float*)d_in[26];
  const float* scb   = (const float*)d_in[27];
  const float* xpw   = (const float*)d_in[28];
  const float* dtw   = (const float*)d_in[29];
  const float* dtb   = (const float*)d_in[30];
  const float* Alog  = (const float*)d_in[31];
  const float* Dp    = (const float*)d_in[32];
  const float* ong   = (const float*)d_in[33];
  const float* onb   = (const float*)d_in[34];
  const float* oww   = (const float*)d_in[35];

  float* ws = (float*)d_ws;
  // main buffers (floats) -- layout identical footprint to round-1 (98.2 MB)
  float* hlin  = ws + 0;         // 884736  [k_pre->k_dw]; ul alias (442368) at k_ul; dtsum alias below
  float* dtsum = ws + 442368;    // 49152   [scanA->comb]  (inside hlin region, dead by then)
  float* x1pre = ws + 884736;    // 884736  [k_dw->k_ssin]; hend alias; csum/wsm alias later
  float* x2    = ws + 1769472;   // 884736  [k_dw->k_gate]; crmin alias at k_combine
  float* x2g   = ws + 2654208;   // 884736  [k_gate->k_combine]
  float* xibuf = ws + 3538944;   // 1769472 [k_ssin->k_ssdw]; hinit alias; Ybig alias at k_y
  float* zbuf  = ws + 5308416;   // 1769472 [k_ssin->k_combine]
  float* xcbuf = ws + 7077888;   // 1769472 [k_ssdw-> many]
  float* delta = ws + 8847360;   // 7077888 [k_delta->scan]
  float* dts   = ws + 15925248;  // 221184  [k_xdbl->k_delta]
  float* bcbuf = ws + 16146432;  // 1179648 [k_xdbl->scan]
  float* oy    = ws + 17326080;  // 7077888 [scanB->k_combine]
  float* hend  = x1pre;          // 786432 alias [scanA->comb]
  float* hinit = xibuf;          // 786432 alias [comb->scanB]
  float* ulb   = hlin;           // 442368 alias
  float* crmin = x2;             // alias
  float* Ybig  = xibuf;          // alias
  float* csum  = x1pre;          // alias (after hend dead)
  float* wsmb  = x1pre + 768;    // alias
  // transposed weights region
  float* wT = ws + 24403968;     // 142656 floats
  float* w1T   = wT + 0;
  float* linT  = wT + 9216;
  float* ag1T  = wT + 18432;
  float* ag2T  = wT + 23040;
  float* inT   = wT + 27648;
  float* owT   = wT + 64512;
  float* pwc1T = wT + 82944;
  float* pwc2T = wT + 85248;
  float* finT  = wT + 86976;
  float* sq1T  = wT + 96192;
  float* sq2T  = wT + 97344;
  float* gwcT  = wT + 98496;
  float* dtwT  = wT + 108864;
  float* xpwT  = wT + 113472;

  TArgs ta;
  const float* srcs[14] = {w1, linw, ag1w, ag2w, inw, oww, pwc1w, pwc2w, finw, sq1w, sq2w, gwcw, dtw, xpw};
  float* dsts[14]       = {w1T, linT, ag1T, ag2T, inT, owT, pwc1T, pwc2T, finT, sq1T, sq2T, gwcT, dtwT, xpwT};
  int rows[14] = {96, 96, 48, 96, 384, 96, 96, 72, 96, 24, 24, 96, 768, 152};
  int cols[14] = {96, 96, 96, 48, 96, 192, 24, 24, 96, 48, 48, 108, 6, 192};
  for (int i = 0; i < 14; ++i){ ta.s[i] = srcs[i]; ta.d[i] = dsts[i]; ta.rows[i] = rows[i]; ta.cols[i] = cols[i]; }

  k_tr<<<dim3(144, 14), 256, 0, stream>>>(ta);
  k_pre<<<Pp, CHn, 0, stream>>>(x, w1T, b1, bng, bnb, linT, linb, hlin);
  k_dw<<<(Pp * CHn) / 256, 256, 0, stream>>>(hlin, dw1w, dw1b, dw2w, dw2b, x1pre, x2);
  k_gate<<<Pp, CHn, 0, stream>>>(x2, ag1T, ag1b, ag2T, ag2b, x2g);
  k_ssin<<<Pp, DIn, 0, stream>>>(x1pre, inT, xibuf, zbuf);
  k_ssdw<<<(Pp * DIn) / 256, 256, 0, stream>>>(xibuf, scw, scb, xcbuf);
  k_xdbl<<<(36864 * 38) / 256, 256, 0, stream>>>(xcbuf, xpwT, dts, bcbuf);
  k_delta<<<(36864 * DIn) / 256, 256, 0, stream>>>(dts, dtwT, dtb, delta);
  k_scanA<<<192 * Sseg, 64, 0, stream>>>(delta, bcbuf, xcbuf, Alog, hend, dtsum);
  k_comb<<<192, 64, 0, stream>>>(Alog, hend, dtsum, hinit);
  k_scanB<<<192 * Sseg, 64, 0, stream>>>(delta, bcbuf, xcbuf, Alog, hinit, oy);
  k_combine<<<Pp, DIn, 0, stream>>>(oy, xcbuf, zbuf, Dp, ong, onb, owT, x2g, lng, lnb, crmin);
  k_ul<<<(Pp * 48) / 256, 256, 0, stream>>>(crmin, sq1T, sq2T, ulb);
  k_y<<<Pp, 192, 0, stream>>>(ulb, gwcT, gwcb, pwc1T, pwc2T, Ybig);
  k_csum<<<768, 256, 0, stream>>>(Ybig, csum);
  k_softmax<<<4, 192, 0, stream>>>(csum, wsmb);
  k_final<<<Pp, CHn, 0, stream>>>(Ybig, wsmb, finT, finb, (float*)d_out);
}

// Round 3
// 460.079 us; speedup vs baseline: 1.7767x; 1.0615x over previous
//
#include <hip/hip_runtime.h>
#include <hip/hip_bf16.h>

// Problem constants
#define Bn   4
#define CHn  96
#define Hh   48
#define Ww   48
#define Ll   2304      // H*W
#define Pp   9216      // B*L
#define DIn  192
#define Nn   16
#define Rr   6
#define Sseg   16      // scan segments per sequence
#define SEGLEN 144     // 2304 / 16
#define SC      8      // register prefetch sub-chunk

__device__ inline float siluf(float x){ return x / (1.0f + __expf(-x)); }
__device__ inline float sigmf(float x){ return 1.0f / (1.0f + __expf(-x)); }

// row index l for direction k such that pix_of(k,l) == p
__device__ inline int l_of(int k, int p){
  if (k == 0) return p;
  if (k == 1) return (p % 48) * 48 + p / 48;
  if (k == 2) return Ll - 1 - p;
  return Ll - 1 - ((p % 48) * 48 + p / 48);
}

// ---------------- transpose-all-weights kernel (one launch) ----------------
struct TArgs {
  const float* s[14];
  float* d[14];
  int rows[14];
  int cols[14];
};
__global__ void k_tr(TArgs a){
  int id = blockIdx.y;
  int n = a.rows[id] * a.cols[id];
  int t = blockIdx.x * blockDim.x + threadIdx.x;
  if (t < n){
    int r = t / a.cols[id];
    int c = t - r * a.cols[id];
    a.d[id][c * a.rows[id] + r] = a.s[id][t];
  }
}

// ---------------- conv1x1 + BN + ReLU + channel linear ----------------
__global__ void k_pre(const float* __restrict__ x, const float* __restrict__ w1T, const float* __restrict__ b1,
                      const float* __restrict__ bng, const float* __restrict__ bnb,
                      const float* __restrict__ linT, const float* __restrict__ lb,
                      float* __restrict__ hlin){
  int p = blockIdx.x; int b = p / Ll; int pp = p - b * Ll;
  int c = threadIdx.x;
  __shared__ float xv[CHn];
  __shared__ float hv[CHn];
  xv[c] = x[(size_t)(b * CHn + c) * Ll + pp];
  __syncthreads();
  float acc = 0.f;
  for (int i = 0; i < CHn; ++i) acc = fmaf(w1T[i * CHn + c], xv[i], acc);
  float s = bng[c] * rsqrtf(1.0f + 1e-5f);
  float h = fmaxf((acc + b1[c]) * s + bnb[c], 0.f);
  hv[c] = h;
  __syncthreads();
  float a2 = lb[c];
  for (int i = 0; i < CHn; ++i) a2 = fmaf(linT[i * CHn + c], hv[i], a2);
  hlin[(size_t)p * CHn + c] = a2;
}

// ---------------- two depthwise 3x3 convs + SiLU ----------------
__global__ void k_dw(const float* __restrict__ hlin,
                     const float* __restrict__ dw1w, const float* __restrict__ dw1b,
                     const float* __restrict__ dw2w, const float* __restrict__ dw2b,
                     float* __restrict__ x1pre, float* __restrict__ x2){
  int t = blockIdx.x * 256 + threadIdx.x;
  if (t >= Pp * CHn) return;
  int c = t % CHn; int p = t / CHn; int b = p / Ll; int pp = p - b * Ll;
  int r = pp / Ww; int cx = pp - r * Ww;
  float a1 = dw1b[c], a2 = dw2b[c];
  for (int dy = -1; dy <= 1; ++dy){
    int ny = r + dy; if ((unsigned)ny >= Hh) continue;
    for (int dx = -1; dx <= 1; ++dx){
      int nx = cx + dx; if ((unsigned)nx >= Ww) continue;
      float v = hlin[(size_t)((b * Ll) + ny * Ww + nx) * CHn + c];
      int wi = c * 9 + (dy + 1) * 3 + (dx + 1);
      a1 = fmaf(dw1w[wi], v, a1);
      a2 = fmaf(dw2w[wi], v, a2);
    }
  }
  x1pre[t] = siluf(a1);
  x2[t]   = siluf(a2);
}

// ---------------- attention gate: sigmoid(ag2(relu(ag1 x2))) * x2 ----------------
__global__ void k_gate(const float* __restrict__ x2,
                       const float* __restrict__ ag1T, const float* __restrict__ ag1b,
                       const float* __restrict__ ag2T, const float* __restrict__ ag2b,
                       float* __restrict__ x2g){
  int p = blockIdx.x; int c = threadIdx.x;
  __shared__ float xv[CHn];
  __shared__ float rv[48];
  xv[c] = x2[(size_t)p * CHn + c];
  __syncthreads();
  if (c < 48){
    float a = ag1b[c];
    for (int i = 0; i < CHn; ++i) a = fmaf(ag1T[i * 48 + c], xv[i], a);
    rv[c] = fmaxf(a, 0.f);
  }
  __syncthreads();
  float a2 = ag2b[c];
  for (int tt = 0; tt < 48; ++tt) a2 = fmaf(ag2T[tt * CHn + c], rv[tt], a2);
  x2g[(size_t)p * CHn + c] = xv[c] * sigmf(a2);
}

// ---------------- SS2D input projection (GEMM-tiled): 9216 x 384 = X(9216x96) @ inT ----------------
__global__ __launch_bounds__(256) void k_ssin(const float* __restrict__ x1pre, const float* __restrict__ inT,
                                              float* __restrict__ xi, float* __restrict__ z){
  __shared__ float Xs[32][34];
  __shared__ float Wsh[32][128];
  int tid = threadIdx.x;
  int mt = blockIdx.x % 288; int nt = blockIdx.x / 288;
  int p0 = mt * 32, n0 = nt * 128;
  int tx = tid & 15, ty = tid >> 4;
  float acc[2][8];
  #pragma unroll
  for (int i = 0; i < 2; ++i)
    #pragma unroll
    for (int j = 0; j < 8; ++j) acc[i][j] = 0.f;
  for (int kc = 0; kc < 96; kc += 32){
    #pragma unroll
    for (int it = 0; it < 4; ++it){
      int e = it * 256 + tid; int dd = e & 31; int m = e >> 5;
      Xs[dd][m] = x1pre[(size_t)(p0 + m) * CHn + kc + dd];
    }
    #pragma unroll
    for (int it = 0; it < 16; ++it){
      int e = it * 256 + tid; int n = e & 127; int dd = e >> 7;
      Wsh[dd][n] = inT[(size_t)(kc + dd) * 384 + n0 + n];
    }
    __syncthreads();
    #pragma unroll
    for (int dd = 0; dd < 32; ++dd){
      float2 xv = *(const float2*)&Xs[dd][ty * 2];
      #pragma unroll
      for (int j = 0; j < 8; ++j){
        float w = Wsh[dd][tx + 16 * j];
        acc[0][j] = fmaf(xv.x, w, acc[0][j]);
        acc[1][j] = fmaf(xv.y, w, acc[1][j]);
      }
    }
    __syncthreads();
  }
  #pragma unroll
  for (int i = 0; i < 2; ++i){
    int p = p0 + ty * 2 + i;
    #pragma unroll
    for (int j = 0; j < 8; ++j){
      int n = n0 + tx + 16 * j;
      float v = acc[i][j];
      if (n < 192) xi[(size_t)p * DIn + n] = v;
      else         z [(size_t)p * DIn + (n - 192)] = v;
    }
  }
}

// ---------------- SS2D depthwise 3x3 + SiLU ----------------
__global__ void k_ssdw(const float* __restrict__ xi, const float* __restrict__ scw,
                       const float* __restrict__ scb, float* __restrict__ xc){
  int t = blockIdx.x * 256 + threadIdx.x;
  if (t >= Pp * DIn) return;
  int d = t % DIn; int p = t / DIn; int b = p / Ll; int pp = p - b * Ll;
  int r = pp / Ww; int cx = pp - r * Ww;
  float a = scb[d];
  for (int dy = -1; dy <= 1; ++dy){
    int ny = r + dy; if ((unsigned)ny >= Hh) continue;
    for (int dx = -1; dx <= 1; ++dx){
      int nx = cx + dx; if ((unsigned)nx >= Ww) continue;
      float v = xi[(size_t)((b * Ll) + ny * Ww + nx) * DIn + d];
      a = fmaf(scw[d * 9 + (dy + 1) * 3 + (dx + 1)], v, a);
    }
  }
  xc[t] = siluf(a);
}

// ---------------- fused xproj GEMM + delta: per pixel, all 4 directions ----------------
// C[9216 x 152] = xc[9216 x 192] @ xpwT ; scatter B/C to bc, keep dt-rank in LDS,
// then compute delta = softplus(dts @ dtw^T + dtb) in-block.
__global__ __launch_bounds__(256) void k_xdelta(const float* __restrict__ xc,
    const float* __restrict__ xpwT, const float* __restrict__ dtwT,
    const float* __restrict__ dtb, float* __restrict__ bc, float* __restrict__ delta){
  __shared__ float Xs[32][34];
  __shared__ float Wsh[32][160];
  __shared__ float dss[32][24];   // [pixel m][k*6 + rank]
  int tid = threadIdx.x;
  int b = blockIdx.x / 72; int p0 = (blockIdx.x - b * 72) * 32;
  int tx = tid & 15, ty = tid >> 4;
  float acc[2][10];
  #pragma unroll
  for (int i = 0; i < 2; ++i)
    #pragma unroll
    for (int j = 0; j < 10; ++j) acc[i][j] = 0.f;
  const float* xbase = xc + (size_t)(b * Ll + p0) * DIn;
  for (int kc = 0; kc < 192; kc += 32){
    #pragma unroll
    for (int it = 0; it < 4; ++it){
      int e = it * 256 + tid; int dd = e & 31; int m = e >> 5;
      Xs[dd][m] = xbase[(size_t)m * DIn + kc + dd];
    }
    #pragma unroll
    for (int it = 0; it < 20; ++it){
      int e = it * 256 + tid; int n = e % 160; int dd = e / 160;
      Wsh[dd][n] = (n < 152) ? xpwT[(size_t)(kc + dd) * 152 + n] : 0.f;
    }
    __syncthreads();
    #pragma unroll
    for (int dd = 0; dd < 32; ++dd){
      float2 xv = *(const float2*)&Xs[dd][ty * 2];
      #pragma unroll
      for (int j = 0; j < 10; ++j){
        float w = Wsh[dd][tx + 16 * j];
        acc[0][j] = fmaf(xv.x, w, acc[0][j]);
        acc[1][j] = fmaf(xv.y, w, acc[1][j]);
      }
    }
    __syncthreads();
  }
  // scatter B/C, stash dt-rank values
  #pragma unroll
  for (int i = 0; i < 2; ++i){
    int m = ty * 2 + i; int p = p0 + m;
    #pragma unroll
    for (int j = 0; j < 10; ++j){
      int n = tx + 16 * j;
      if (n >= 152) continue;
      int k = n / 38, jj = n - k * 38;
      if (jj < 6){
        dss[m][k * 6 + jj] = acc[i][j];
      } else {
        int l = l_of(k, p);
        bc[((size_t)((b * 4 + k) * Ll + l)) * 32 + (jj - 6)] = acc[i][j];
      }
    }
  }
  __syncthreads();
  // delta phase: 32 pixels x 4 dirs x 192 channels
  for (int it = 0; it < 96; ++it){
    int o = it * 256 + tid;
    int mk = o / 192; int d = o - mk * 192;
    int k = mk & 3; int m = mk >> 2;
    const float* ds = &dss[m][k * 6];
    float a = dtb[k * 192 + d];
    #pragma unroll
    for (int r = 0; r < 6; ++r) a = fmaf(dtwT[r * 768 + k * 192 + d], ds[r], a);
    float sp = fmaxf(a, 0.f) + log1pf(__expf(-fabsf(a)));
    int p = p0 + m; int l = l_of(k, p);
    delta[((size_t)((b * 4 + k) * Ll + l)) * DIn + d] = sp;
  }
}

// ======================= segmented selective scan =======================
// unit = bk*12+g : 192 independent (sequence, 16-channel-group) units.
// lane = ch*4 + ns : ch local channel [0,16), ns handles 4 of 16 states.

// ---- pass A: local scan per segment (h0=0), emit h_end + sum(dt) ----
__global__ __launch_bounds__(64) void k_scanA(const float* __restrict__ delta, const float* __restrict__ bc,
                                              const float* __restrict__ xc, const float* __restrict__ Alog,
                                              float* __restrict__ hend, float* __restrict__ dtsum){
  int blk = blockIdx.x; int unit = blk / Sseg; int seg = blk - unit * Sseg;
  int g = unit % 12; int bk = unit / 12; int k = bk & 3; int b = bk >> 2;
  int lane = threadIdx.x; int ch = lane >> 2; int ns = lane & 3; int nb = ns * 4;
  int d = g * 16 + ch;
  const int arow = (k * DIn + d) * 16 + nb;
  float A0 = -__expf(Alog[arow + 0]);
  float A1 = -__expf(Alog[arow + 1]);
  float A2 = -__expf(Alog[arow + 2]);
  float A3 = -__expf(Alog[arow + 3]);
  float h0 = 0.f, h1 = 0.f, h2 = 0.f, h3 = 0.f, dacc = 0.f;

  const int l0 = seg * SEGLEN;
  const float* dptr = delta + (size_t)(bk * Ll) * DIn + g * 16 + ch;
  const float* bptr = bc    + (size_t)(bk * Ll) * 32 + nb;
  const float* cxb  = xc    + (size_t)(b  * Ll) * DIn + g * 16 + ch;

  float dtA[SC], uA[SC]; float4 BA[SC];
  float dtB[SC], uB[SC]; float4 BB[SC];

  auto load = [&](float (&dtv)[SC], float (&uv)[SC], float4 (&Bv)[SC], int ls){
    #pragma unroll
    for (int i = 0; i < SC; ++i){
      int l = ls + i;
      dtv[i] = dptr[(size_t)l * DIn];
      Bv[i]  = *(const float4*)(bptr + (size_t)l * 32);
      int pix;
      if (k == 0) pix = l;
      else if (k == 2) pix = Ll - 1 - l;
      else { int l2 = (k == 1) ? l : (Ll - 1 - l); pix = (l2 % 48) * 48 + l2 / 48; }
      uv[i] = cxb[(size_t)pix * DIn];
    }
  };

  load(dtA, uA, BA, l0);
  int lcur = l0;
  #pragma unroll 1
  for (int cc = 0; cc < SEGLEN / (2 * SC); ++cc){
    load(dtB, uB, BB, lcur + SC);
    #pragma unroll
    for (int i = 0; i < SC; ++i){
      float dt = dtA[i]; dacc += dt;
      float du = dt * uA[i];
      h0 = fmaf(h0, __expf(dt * A0), du * BA[i].x);
      h1 = fmaf(h1, __expf(dt * A1), du * BA[i].y);
      h2 = fmaf(h2, __expf(dt * A2), du * BA[i].z);
      h3 = fmaf(h3, __expf(dt * A3), du * BA[i].w);
    }
    if (cc < SEGLEN / (2 * SC) - 1) load(dtA, uA, BA, lcur + 2 * SC);
    #pragma unroll
    for (int i = 0; i < SC; ++i){
      float dt = dtB[i]; dacc += dt;
      float du = dt * uB[i];
      h0 = fmaf(h0, __expf(dt * A0), du * BB[i].x);
      h1 = fmaf(h1, __expf(dt * A1), du * BB[i].y);
      h2 = fmaf(h2, __expf(dt * A2), du * BB[i].z);
      h3 = fmaf(h3, __expf(dt * A3), du * BB[i].w);
    }
    lcur += 2 * SC;
  }
  size_t sb = (size_t)unit * Sseg + seg;
  *(float4*)&hend[sb * 256 + lane * 4] = make_float4(h0, h1, h2, h3);
  if (ns == 0) dtsum[sb * 16 + ch] = dacc;
}

// ---- combine: sequential fold over segments -> h_init per segment ----
__global__ __launch_bounds__(64) void k_comb(const float* __restrict__ Alog, const float* __restrict__ hend,
                                             const float* __restrict__ dtsum, float* __restrict__ hinit){
  int unit = blockIdx.x; int g = unit % 12; int bk = unit / 12; int k = bk & 3;
  int lane = threadIdx.x; int ch = lane >> 2; int ns = lane & 3; int nb = ns * 4;
  int d = g * 16 + ch;
  const int arow = (k * DIn + d) * 16 + nb;
  float A0 = -__expf(Alog[arow + 0]);
  float A1 = -__expf(Alog[arow + 1]);
  float A2 = -__expf(Alog[arow + 2]);
  float A3 = -__expf(Alog[arow + 3]);
  float h0 = 0.f, h1 = 0.f, h2 = 0.f, h3 = 0.f;
  for (int s = 0; s < Sseg; ++s){
    size_t sb = (size_t)unit * Sseg + s;
    *(float4*)&hinit[sb * 256 + lane * 4] = make_float4(h0, h1, h2, h3);
    float ds = dtsum[sb * 16 + ch];
    float4 he = *(const float4*)&hend[sb * 256 + lane * 4];
    h0 = fmaf(h0, __expf(A0 * ds), he.x);
    h1 = fmaf(h1, __expf(A1 * ds), he.y);
    h2 = fmaf(h2, __expf(A2 * ds), he.z);
    h3 = fmaf(h3, __expf(A3 * ds), he.w);
  }
}

// ---- pass B: rescan from h_init, emit y ----
__global__ __launch_bounds__(64) void k_scanB(const float* __restrict__ delta, const float* __restrict__ bc,
                                              const float* __restrict__ xc, const float* __restrict__ Alog,
                                              const float* __restrict__ hinit, float* __restrict__ oy){
  int blk = blockIdx.x; int unit = blk / Sseg; int seg = blk - unit * Sseg;
  int g = unit % 12; int bk = unit / 12; int k = bk & 3; int b = bk >> 2;
  int lane = threadIdx.x; int ch = lane >> 2; int ns = lane & 3; int nb = ns * 4;
  int d = g * 16 + ch;
  const int arow = (k * DIn + d) * 16 + nb;
  float A0 = -__expf(Alog[arow + 0]);
  float A1 = -__expf(Alog[arow + 1]);
  float A2 = -__expf(Alog[arow + 2]);
  float A3 = -__expf(Alog[arow + 3]);
  size_t sb = (size_t)unit * Sseg + seg;
  float4 hi = *(const float4*)&hinit[sb * 256 + lane * 4];
  float h0 = hi.x, h1 = hi.y, h2 = hi.z, h3 = hi.w;

  const int l0 = seg * SEGLEN;
  const float* dptr = delta + (size_t)(bk * Ll) * DIn + g * 16 + ch;
  const float* bptr = bc    + (size_t)(bk * Ll) * 32 + nb;
  const float* cxb  = xc    + (size_t)(b  * Ll) * DIn + g * 16 + ch;
  float*       obase = oy   + (size_t)(bk * Ll) * DIn + d;

  float dtA[SC], uA[SC]; float4 BA[SC], CA[SC];
  float dtB[SC], uB[SC]; float4 BB[SC], CB[SC];

  auto load = [&](float (&dtv)[SC], float (&uv)[SC], float4 (&Bv)[SC], float4 (&Cv)[SC], int ls){
    #pragma unroll
    for (int i = 0; i < SC; ++i){
      int l = ls + i;
      dtv[i] = dptr[(size_t)l * DIn];
      Bv[i]  = *(const float4*)(bptr + (size_t)l * 32);
      Cv[i]  = *(const float4*)(bptr + (size_t)l * 32 + 16);
      int pix;
      if (k == 0) pix = l;
      else if (k == 2) pix = Ll - 1 - l;
      else { int l2 = (k == 1) ? l : (Ll - 1 - l); pix = (l2 % 48) * 48 + l2 / 48; }
      uv[i] = cxb[(size_t)pix * DIn];
    }
  };

  load(dtA, uA, BA, CA, l0);
  int lcur = l0;
  #pragma unroll 1
  for (int cc = 0; cc < SEGLEN / (2 * SC); ++cc){
    load(dtB, uB, BB, CB, lcur + SC);
    #pragma unroll
    for (int i = 0; i < SC; ++i){
      float dt = dtA[i];
      float du = dt * uA[i];
      h0 = fmaf(h0, __expf(dt * A0), du * BA[i].x);
      h1 = fmaf(h1, __expf(dt * A1), du * BA[i].y);
      h2 = fmaf(h2, __expf(dt * A2), du * BA[i].z);
      h3 = fmaf(h3, __expf(dt * A3), du * BA[i].w);
      float yp = fmaf(h0, CA[i].x, fmaf(h1, CA[i].y, fmaf(h2, CA[i].z, h3 * CA[i].w)));
      yp += __shfl_xor(yp, 1);
      yp += __shfl_xor(yp, 2);
      if (ns == 0) obase[(size_t)(lcur + i) * DIn] = yp;
    }
    if (cc < SEGLEN / (2 * SC) - 1) load(dtA, uA, BA, CA, lcur + 2 * SC);
    #pragma unroll
    for (int i = 0; i < SC; ++i){
      float dt = dtB[i];
      float du = dt * uB[i];
      h0 = fmaf(h0, __expf(dt * A0), du * BB[i].x);
      h1 = fmaf(h1, __expf(dt * A1), du * BB[i].y);
      h2 = fmaf(h2, __expf(dt * A2), du * BB[i].z);
      h3 = fmaf(h3, __expf(dt * A3), du * BB[i].w);
      float yp = fmaf(h0, CB[i].x, fmaf(h1, CB[i].y, fmaf(h2, CB[i].z, h3 * CB[i].w)));
      yp += __shfl_xor(yp, 1);
      yp += __shfl_xor(yp, 2);
      if (ns == 0) obase[(size_t)(lcur + SC + i) * DIn] = yp;
    }
    lcur += 2 * SC;
  }
}

// ---------------- block reductions ----------------
__device__ inline float block_sum_192(float* red, int d, float v){
  red[d] = v; __syncthreads();
  if (d < 96) red[d] += red[d + 96]; __syncthreads();
  if (d < 48) red[d] += red[d + 48]; __syncthreads();
  if (d < 24) red[d] += red[d + 24]; __syncthreads();
  if (d < 12) red[d] += red[d + 12]; __syncthreads();
  if (d < 6)  red[d] += red[d + 6];  __syncthreads();
  float tot = red[0] + red[1] + red[2] + red[3] + red[4] + red[5];
  __syncthreads();
  return tot;
}
__device__ inline float block_sum_96(float* red, int d, float v){
  if (d < 96) red[d] = v; __syncthreads();
  if (d < 48) red[d] += red[d + 48]; __syncthreads();
  if (d < 24) red[d] += red[d + 24]; __syncthreads();
  if (d < 12) red[d] += red[d + 12]; __syncthreads();
  if (d < 6)  red[d] += red[d + 6];  __syncthreads();
  float tot = red[0] + red[1] + red[2] + red[3] + red[4] + red[5];
  __syncthreads();
  return tot;
}

// ---- combine 4 dirs + LN(192) + z-gate + out-proj + add + LN(96) + squeeze convs (ul) ----
__global__ void k_combine(const float* __restrict__ oy, const float* __restrict__ xc,
                          const float* __restrict__ z, const float* __restrict__ Dp,
                          const float* __restrict__ ong, const float* __restrict__ onb,
                          const float* __restrict__ owT, const float* __restrict__ x2g,
                          const float* __restrict__ lng, const float* __restrict__ lnb,
                          const float* __restrict__ sq1T, const float* __restrict__ sq2T,
                          float* __restrict__ ul){
  int p = blockIdx.x; int b = p / Ll; int pp = p - b * Ll;
  int r = pp / Ww; int cx = pp - r * Ww;
  int d = threadIdx.x;
  __shared__ float red[192];
  __shared__ float ygv[192];
  __shared__ float crs[96];
  int l1 = cx * 48 + r;
  size_t base = (size_t)(b * 4) * Ll * DIn;
  float yv = oy[base + (size_t)(0 * Ll + pp)            * DIn + d]
           + oy[base + (size_t)(1 * Ll + l1)            * DIn + d]
           + oy[base + (size_t)(2 * Ll + (Ll - 1 - pp)) * DIn + d]
           + oy[base + (size_t)(3 * Ll + (Ll - 1 - l1)) * DIn + d];
  float u = xc[(size_t)(b * Ll + pp) * DIn + d];
  float Ds = Dp[d] + Dp[192 + d] + Dp[384 + d] + Dp[576 + d];
  yv = fmaf(u, Ds, yv);
  float mu = block_sum_192(red, d, yv) * (1.f / 192.f);
  float dv = yv - mu;
  float var = block_sum_192(red, d, dv * dv) * (1.f / 192.f);
  float yn = dv * rsqrtf(var + 1e-5f) * ong[d] + onb[d];
  float zv = z[(size_t)(b * Ll + pp) * DIn + d];
  ygv[d] = yn * (zv * sigmf(zv));
  __syncthreads();
  float sval = 0.f;
  if (d < 96){
    float acc = 0.f;
    for (int dd = 0; dd < 192; ++dd) acc = fmaf(owT[dd * 96 + d], ygv[dd], acc);
    sval = acc + x2g[(size_t)p * CHn + d];
  }
  float mu2 = block_sum_96(red, d, sval) * (1.f / 96.f);
  float dv2 = sval - mu2;
  float var2 = block_sum_96(red, d, (d < 96) ? dv2 * dv2 : 0.f) * (1.f / 96.f);
  if (d < 96) crs[d] = dv2 * rsqrtf(var2 + 1e-5f) * lng[d] + lnb[d];
  __syncthreads();
  if (d < 48){
    float a = 0.f;
    if (d < 24){
      for (int i = 0; i < 48; ++i) a = fmaf(sq1T[i * 24 + d], crs[i], a);
    } else {
      int o = d - 24;
      for (int i = 0; i < 48; ++i) a = fmaf(sq2T[i * 24 + o], crs[48 + i], a);
    }
    ul[(size_t)p * 48 + d] = a;
  }
}

// ---------------- CRM main: Y = [gwc(up)+pwc1(up) | pwc2(low) | low] ----------------
__global__ void k_y(const float* __restrict__ ul, const float* __restrict__ gwcT,
                    const float* __restrict__ gwcb, const float* __restrict__ pwc1T,
                    const float* __restrict__ pwc2T, float* __restrict__ Ybig){
  int p = blockIdx.x; int b = p / Ll; int pp = p - b * Ll;
  int r = pp / Ww; int cx = pp - r * Ww;
  int oc = threadIdx.x;
  __shared__ float ulv[48];
  if (oc < 48) ulv[oc] = ul[(size_t)p * 48 + oc];
  __syncthreads();
  float acc;
  if (oc < 96){
    acc = gwcb[oc];
    int grp = oc / 48;
    for (int dy = -1; dy <= 1; ++dy){
      int ny = r + dy; if ((unsigned)ny >= Hh) continue;
      for (int dx = -1; dx <= 1; ++dx){
        int nx = cx + dx; if ((unsigned)nx >= Ww) continue;
        const float* un = ul + (size_t)((b * Ll) + ny * Ww + nx) * 48 + grp * 12;
        int k9 = (dy + 1) * 3 + (dx + 1);
        #pragma unroll
        for (int i = 0; i < 12; ++i) acc = fmaf(gwcT[(i * 9 + k9) * 96 + oc], un[i], acc);
      }
    }
    for (int i = 0; i < 24; ++i) acc = fmaf(pwc1T[i * 96 + oc], ulv[i], acc);
  } else if (oc < 168){
    int o2 = oc - 96; acc = 0.f;
    for (int i = 0; i < 24; ++i) acc = fmaf(pwc2T[i * 72 + o2], ulv[24 + i], acc);
  } else {
    acc = ulv[24 + oc - 168];
  }
  Ybig[(size_t)p * 192 + oc] = acc;
}

// ---------------- coalesced partial spatial sums: 144 blocks x 64-pixel chunks ----------------
__global__ void k_csum(const float* __restrict__ Ybig, float* __restrict__ csum_p){
  int b = blockIdx.x / 36; int ch = blockIdx.x - b * 36;
  int t = threadIdx.x;
  if (t >= 192) return;
  float acc = 0.f;
  const float* base = Ybig + (size_t)(b * Ll + ch * 64) * 192 + t;
  #pragma unroll 4
  for (int i = 0; i < 64; ++i) acc += base[(size_t)i * 192];
  csum_p[(size_t)blockIdx.x * 192 + t] = acc;
}

// ---------------- softmax over 192 channel means ----------------
__global__ void k_softmax(const float* __restrict__ csum_p, float* __restrict__ wsm){
  int b = blockIdx.x; int t = threadIdx.x;
  __shared__ float red[192];
  float m = 0.f;
  for (int cc = 0; cc < 36; ++cc) m += csum_p[(size_t)(b * 36 + cc) * 192 + t];
  m *= (1.f / 2304.f);
  red[t] = m; __syncthreads();
  if (t < 96) red[t] = fmaxf(red[t], red[t + 96]); __syncthreads();
  if (t < 48) red[t] = fmaxf(red[t], red[t + 48]); __syncthreads();
  if (t < 24) red[t] = fmaxf(red[t], red[t + 24]); __syncthreads();
  if (t < 12) red[t] = fmaxf(red[t], red[t + 12]); __syncthreads();
  if (t < 6)  red[t] = fmaxf(red[t], red[t + 6]);  __syncthreads();
  float mx = fmaxf(fmaxf(fmaxf(red[0], red[1]), fmaxf(red[2], red[3])), fmaxf(red[4], red[5]));
  __syncthreads();
  float e = __expf(m - mx);
  float s = block_sum_192(red, t, e);
  wsm[b * 192 + t] = e / s;
}

// ---------------- weighted halves + final linear -> NCHW output ----------------
__global__ void k_final(const float* __restrict__ Ybig, const float* __restrict__ wsm,
                        const float* __restrict__ finT, const float* __restrict__ finb,
                        float* __restrict__ out){
  int p = blockIdx.x; int b = p / Ll; int pp = p - b * Ll;
  int c = threadIdx.x;
  __shared__ float ov[96];
  float o = wsm[b * 192 + c]      * Ybig[(size_t)p * 192 + c]
          + wsm[b * 192 + 96 + c] * Ybig[(size_t)p * 192 + 96 + c];
  ov[c] = o; __syncthreads();
  float acc = finb[c];
  for (int i = 0; i < 96; ++i) acc = fmaf(finT[i * 96 + c], ov[i], acc);
  out[(size_t)(b * 96 + c) * Ll + pp] = acc;
}

// ---------------- host launch ----------------
extern "C" void kernel_launch(void* const* d_in, const int* in_sizes, int n_in,
                              void* d_out, int out_size, void* d_ws, size_t ws_size,
                              hipStream_t stream) {
  const float* x     = (const float*)d_in[0];
  const float* w1    = (const float*)d_in[1];
  const float* b1    = (const float*)d_in[2];
  const float* bng   = (const float*)d_in[3];
  const float* bnb   = (const float*)d_in[4];
  const float* linw  = (const float*)d_in[5];
  const float* linb  = (const float*)d_in[6];
  const float* dw1w  = (const float*)d_in[7];
  const float* dw1b  = (const float*)d_in[8];
  const float* dw2w  = (const float*)d_in[9];
  const float* dw2b  = (const float*)d_in[10];
  const float* ag1w  = (const float*)d_in[11];
  const float* ag1b  = (const float*)d_in[12];
  const float* ag2w  = (const float*)d_in[13];
  const float* ag2b  = (const float*)d_in[14];
  const float* lng   = (const float*)d_in[15];
  const float* lnb   = (const float*)d_in[16];
  const float* sq1w  = (const float*)d_in[17];
  const float* sq2w  = (const float*)d_in[18];
  const float* gwcw  = (const float*)d_in[19];
  const float* gwcb  = (const float*)d_in[20];
  const float* pwc1w = (const float*)d_in[21];
  const float* pwc2w = (const float*)d_in[22];
  const float* finw  = (const float*)d_in[23];
  const float* finb  = (const float*)d_in[24];
  const float* inw   = (const float*)d_in[25];
  const float* scw   = (const float*)d_in[26];
  const float* scb   = (const float*)d_in[27];
  const float* xpw   = (const float*)d_in[28];
  const float* dtw   = (const float*)d_in[29];
  const float* dtb   = (const float*)d_in[30];
  const float* Alog  = (const float*)d_in[31];
  const float* Dp    = (const float*)d_in[32];
  const float* ong   = (const float*)d_in[33];
  const float* onb   = (const float*)d_in[34];
  const float* oww   = (const float*)d_in[35];

  float* ws = (float*)d_ws;
  float* hlin  = ws + 0;         // 884736  [k_pre->k_dw]; ul alias (442368) later
  float* dtsum = ws + 442368;    // 49152   [scanA->comb]
  float* x1pre = ws + 884736;    // 884736  [k_dw->k_ssin]; hend alias; csum_p/wsm alias later
  float* x2    = ws + 1769472;   // 884736  [k_dw->k_gate]
  float* x2g   = ws + 2654208;   // 884736  [k_gate->k_combine]
  float* xibuf = ws + 3538944;   // 1769472 [k_ssin->k_ssdw]; hinit alias; Ybig alias at k_y
  float* zbuf  = ws + 5308416;   // 1769472 [k_ssin->k_combine]
  float* xcbuf = ws + 7077888;   // 1769472 [k_ssdw-> many]
  float* delta = ws + 8847360;   // 7077888 [k_xdelta->scan]
  float* bcbuf = ws + 16146432;  // 1179648 [k_xdelta->scan]
  float* oy    = ws + 17326080;  // 7077888 [scanB->k_combine]
  float* hend  = x1pre;          // 786432 alias [scanA->comb]
  float* hinit = xibuf;          // 786432 alias [comb->scanB]
  float* ulb   = hlin;           // 442368 alias [k_combine->k_y]
  float* Ybig  = xibuf;          // alias
  float* csum_p = x1pre;         // 27648 alias (after hend dead)
  float* wsmb  = x1pre + 27648;  // 768 alias
  // transposed weights region
  float* wT = ws + 24403968;     // 142656 floats
  float* w1T   = wT + 0;
  float* linT  = wT + 9216;
  float* ag1T  = wT + 18432;
  float* ag2T  = wT + 23040;
  float* inT   = wT + 27648;
  float* owT   = wT + 64512;
  float* pwc1T = wT + 82944;
  float* pwc2T = wT + 85248;
  float* finT  = wT + 86976;
  float* sq1T  = wT + 96192;
  float* sq2T  = wT + 97344;
  float* gwcT  = wT + 98496;
  float* dtwT  = wT + 108864;
  float* xpwT  = wT + 113472;

  TArgs ta;
  const float* srcs[14] = {w1, linw, ag1w, ag2w, inw, oww, pwc1w, pwc2w, finw, sq1w, sq2w, gwcw, dtw, xpw};
  float* dsts[14]       = {w1T, linT, ag1T, ag2T, inT, owT, pwc1T, pwc2T, finT, sq1T, sq2T, gwcT, dtwT, xpwT};
  int rows[14] = {96, 96, 48, 96, 384, 96, 96, 72, 96, 24, 24, 96, 768, 152};
  int cols[14] = {96, 96, 96, 48, 96, 192, 24, 24, 96, 48, 48, 108, 6, 192};
  for (int i = 0; i < 14; ++i){ ta.s[i] = srcs[i]; ta.d[i] = dsts[i]; ta.rows[i] = rows[i]; ta.cols[i] = cols[i]; }

  k_tr<<<dim3(144, 14), 256, 0, stream>>>(ta);
  k_pre<<<Pp, CHn, 0, stream>>>(x, w1T, b1, bng, bnb, linT, linb, hlin);
  k_dw<<<(Pp * CHn) / 256, 256, 0, stream>>>(hlin, dw1w, dw1b, dw2w, dw2b, x1pre, x2);
  k_gate<<<Pp, CHn, 0, stream>>>(x2, ag1T, ag1b, ag2T, ag2b, x2g);
  k_ssin<<<288 * 3, 256, 0, stream>>>(x1pre, inT, xibuf, zbuf);
  k_ssdw<<<(Pp * DIn) / 256, 256, 0, stream>>>(xibuf, scw, scb, xcbuf);
  k_xdelta<<<288, 256, 0, stream>>>(xcbuf, xpwT, dtwT, dtb, bcbuf, delta);
  k_scanA<<<192 * Sseg, 64, 0, stream>>>(delta, bcbuf, xcbuf, Alog, hend, dtsum);
  k_comb<<<192, 64, 0, stream>>>(Alog, hend, dtsum, hinit);
  k_scanB<<<192 * Sseg, 64, 0, stream>>>(delta, bcbuf, xcbuf, Alog, hinit, oy);
  k_combine<<<Pp, DIn, 0, stream>>>(oy, xcbuf, zbuf, Dp, ong, onb, owT, x2g, lng, lnb, sq1T, sq2T, ulb);
  k_y<<<Pp, 192, 0, stream>>>(ulb, gwcT, gwcb, pwc1T, pwc2T, Ybig);
  k_csum<<<144, 256, 0, stream>>>(Ybig, csum_p);
  k_softmax<<<4, 192, 0, stream>>>(csum_p, wsmb);
  k_final<<<Pp, CHn, 0, stream>>>(Ybig, wsmb, finT, finb, (float*)d_out);
}

// Round 4
// 432.016 us; speedup vs baseline: 1.8921x; 1.0650x over previous
//
#include <hip/hip_runtime.h>
#include <hip/hip_bf16.h>

// Problem constants
#define Bn   4
#define CHn  96
#define Hh   48
#define Ww   48
#define Ll   2304      // H*W
#define Pp   9216      // B*L
#define DIn  192
#define Nn   16
#define Rr   6
#define Sseg   16      // scan segments per sequence
#define SEGLEN 144     // 2304 / 16
#define SC      8      // register prefetch sub-chunk

__device__ inline float siluf(float x){ return x / (1.0f + __expf(-x)); }
__device__ inline float sigmf(float x){ return 1.0f / (1.0f + __expf(-x)); }

// row index l for direction k such that pix_of(k,l) == p
__device__ inline int l_of(int k, int p){
  if (k == 0) return p;
  if (k == 1) return (p % 48) * 48 + p / 48;
  if (k == 2) return Ll - 1 - p;
  return Ll - 1 - ((p % 48) * 48 + p / 48);
}

// ---------------- transpose-all-weights kernel (one launch) ----------------
struct TArgs {
  const float* s[14];
  float* d[14];
  int rows[14];
  int cols[14];
};
__global__ void k_tr(TArgs a){
  int id = blockIdx.y;
  int n = a.rows[id] * a.cols[id];
  int t = blockIdx.x * blockDim.x + threadIdx.x;
  if (t < n){
    int r = t / a.cols[id];
    int c = t - r * a.cols[id];
    a.d[id][c * a.rows[id] + r] = a.s[id][t];
  }
}

// ---------------- NCHW -> NHWC transpose of input x ----------------
__global__ void k_trx(const float* __restrict__ src, float* __restrict__ dst){
  __shared__ float tile[32][33];
  int pt = blockIdx.x, ct = blockIdx.y, b = blockIdx.z;
  int tx = threadIdx.x & 31, ty = threadIdx.x >> 5;
  #pragma unroll
  for (int i = 0; i < 4; ++i){
    int r = ty + i * 8;     // c-local
    tile[r][tx] = src[((size_t)(b * CHn + ct * 32 + r)) * Ll + pt * 32 + tx];
  }
  __syncthreads();
  #pragma unroll
  for (int i = 0; i < 4; ++i){
    int r = ty + i * 8;     // pp-local
    dst[((size_t)(b * Ll + pt * 32 + r)) * CHn + ct * 32 + tx] = tile[tx][r];
  }
}

// ---------------- [p][c] -> NCHW transpose of output ----------------
__global__ void k_tro(const float* __restrict__ src, float* __restrict__ dst){
  __shared__ float tile[32][33];
  int pt = blockIdx.x, ct = blockIdx.y, b = blockIdx.z;
  int tx = threadIdx.x & 31, ty = threadIdx.x >> 5;
  #pragma unroll
  for (int i = 0; i < 4; ++i){
    int r = ty + i * 8;     // pp-local
    tile[r][tx] = src[((size_t)(b * Ll + pt * 32 + r)) * CHn + ct * 32 + tx];
  }
  __syncthreads();
  #pragma unroll
  for (int i = 0; i < 4; ++i){
    int r = ty + i * 8;     // c-local
    dst[((size_t)(b * CHn + ct * 32 + r)) * Ll + pt * 32 + tx] = tile[tx][r];
  }
}

// ---------------- conv1x1 + BN + ReLU + channel linear (reads NHWC xT) ----------------
__global__ void k_pre(const float* __restrict__ xT, const float* __restrict__ w1T, const float* __restrict__ b1,
                      const float* __restrict__ bng, const float* __restrict__ bnb,
                      const float* __restrict__ linT, const float* __restrict__ lb,
                      float* __restrict__ hlin){
  int p = blockIdx.x;
  int c = threadIdx.x;
  __shared__ float xv[CHn];
  __shared__ float hv[CHn];
  xv[c] = xT[(size_t)p * CHn + c];
  __syncthreads();
  float acc = 0.f;
  for (int i = 0; i < CHn; ++i) acc = fmaf(w1T[i * CHn + c], xv[i], acc);
  float s = bng[c] * rsqrtf(1.0f + 1e-5f);
  float h = fmaxf((acc + b1[c]) * s + bnb[c], 0.f);
  hv[c] = h;
  __syncthreads();
  float a2 = lb[c];
  for (int i = 0; i < CHn; ++i) a2 = fmaf(linT[i * CHn + c], hv[i], a2);
  hlin[(size_t)p * CHn + c] = a2;
}

// ---------------- two depthwise 3x3 convs + SiLU ----------------
__global__ void k_dw(const float* __restrict__ hlin,
                     const float* __restrict__ dw1w, const float* __restrict__ dw1b,
                     const float* __restrict__ dw2w, const float* __restrict__ dw2b,
                     float* __restrict__ x1pre, float* __restrict__ x2){
  int t = blockIdx.x * 256 + threadIdx.x;
  if (t >= Pp * CHn) return;
  int c = t % CHn; int p = t / CHn; int b = p / Ll; int pp = p - b * Ll;
  int r = pp / Ww; int cx = pp - r * Ww;
  float a1 = dw1b[c], a2 = dw2b[c];
  for (int dy = -1; dy <= 1; ++dy){
    int ny = r + dy; if ((unsigned)ny >= Hh) continue;
    for (int dx = -1; dx <= 1; ++dx){
      int nx = cx + dx; if ((unsigned)nx >= Ww) continue;
      float v = hlin[(size_t)((b * Ll) + ny * Ww + nx) * CHn + c];
      int wi = c * 9 + (dy + 1) * 3 + (dx + 1);
      a1 = fmaf(dw1w[wi], v, a1);
      a2 = fmaf(dw2w[wi], v, a2);
    }
  }
  x1pre[t] = siluf(a1);
  x2[t]   = siluf(a2);
}

// ---------------- attention gate: sigmoid(ag2(relu(ag1 x2))) * x2 ----------------
__global__ void k_gate(const float* __restrict__ x2,
                       const float* __restrict__ ag1T, const float* __restrict__ ag1b,
                       const float* __restrict__ ag2T, const float* __restrict__ ag2b,
                       float* __restrict__ x2g){
  int p = blockIdx.x; int c = threadIdx.x;
  __shared__ float xv[CHn];
  __shared__ float rv[48];
  xv[c] = x2[(size_t)p * CHn + c];
  __syncthreads();
  if (c < 48){
    float a = ag1b[c];
    for (int i = 0; i < CHn; ++i) a = fmaf(ag1T[i * 48 + c], xv[i], a);
    rv[c] = fmaxf(a, 0.f);
  }
  __syncthreads();
  float a2 = ag2b[c];
  for (int tt = 0; tt < 48; ++tt) a2 = fmaf(ag2T[tt * CHn + c], rv[tt], a2);
  x2g[(size_t)p * CHn + c] = xv[c] * sigmf(a2);
}

// ---------------- SS2D input projection (GEMM-tiled): 9216 x 384 = X(9216x96) @ inT ----------------
__global__ __launch_bounds__(256) void k_ssin(const float* __restrict__ x1pre, const float* __restrict__ inT,
                                              float* __restrict__ xi, float* __restrict__ z){
  __shared__ float Xs[32][34];
  __shared__ float Wsh[32][128];
  int tid = threadIdx.x;
  int mt = blockIdx.x % 288; int nt = blockIdx.x / 288;
  int p0 = mt * 32, n0 = nt * 128;
  int tx = tid & 15, ty = tid >> 4;
  float acc[2][8];
  #pragma unroll
  for (int i = 0; i < 2; ++i)
    #pragma unroll
    for (int j = 0; j < 8; ++j) acc[i][j] = 0.f;
  for (int kc = 0; kc < 96; kc += 32){
    #pragma unroll
    for (int it = 0; it < 4; ++it){
      int e = it * 256 + tid; int dd = e & 31; int m = e >> 5;
      Xs[dd][m] = x1pre[(size_t)(p0 + m) * CHn + kc + dd];
    }
    #pragma unroll
    for (int it = 0; it < 16; ++it){
      int e = it * 256 + tid; int n = e & 127; int dd = e >> 7;
      Wsh[dd][n] = inT[(size_t)(kc + dd) * 384 + n0 + n];
    }
    __syncthreads();
    #pragma unroll
    for (int dd = 0; dd < 32; ++dd){
      float2 xv = *(const float2*)&Xs[dd][ty * 2];
      #pragma unroll
      for (int j = 0; j < 8; ++j){
        float w = Wsh[dd][tx + 16 * j];
        acc[0][j] = fmaf(xv.x, w, acc[0][j]);
        acc[1][j] = fmaf(xv.y, w, acc[1][j]);
      }
    }
    __syncthreads();
  }
  #pragma unroll
  for (int i = 0; i < 2; ++i){
    int p = p0 + ty * 2 + i;
    #pragma unroll
    for (int j = 0; j < 8; ++j){
      int n = n0 + tx + 16 * j;
      float v = acc[i][j];
      if (n < 192) xi[(size_t)p * DIn + n] = v;
      else         z [(size_t)p * DIn + (n - 192)] = v;
    }
  }
}

// ---------------- SS2D depthwise 3x3 + SiLU ----------------
__global__ void k_ssdw(const float* __restrict__ xi, const float* __restrict__ scw,
                       const float* __restrict__ scb, float* __restrict__ xc){
  int t = blockIdx.x * 256 + threadIdx.x;
  if (t >= Pp * DIn) return;
  int d = t % DIn; int p = t / DIn; int b = p / Ll; int pp = p - b * Ll;
  int r = pp / Ww; int cx = pp - r * Ww;
  float a = scb[d];
  for (int dy = -1; dy <= 1; ++dy){
    int ny = r + dy; if ((unsigned)ny >= Hh) continue;
    for (int dx = -1; dx <= 1; ++dx){
      int nx = cx + dx; if ((unsigned)nx >= Ww) continue;
      float v = xi[(size_t)((b * Ll) + ny * Ww + nx) * DIn + d];
      a = fmaf(scw[d * 9 + (dy + 1) * 3 + (dx + 1)], v, a);
    }
  }
  xc[t] = siluf(a);
}

// ---------------- xproj GEMM: C[9216 x 152] = xc @ xpwT; scatter B/C + dt-rank ----------------
// M-tile 16 -> 576 blocks for occupancy; 256 threads: tx=16 outputs-group, ty=16 pixels.
__global__ __launch_bounds__(256) void k_xproj(const float* __restrict__ xc,
    const float* __restrict__ xpwT, float* __restrict__ bc, float* __restrict__ dtsG){
  __shared__ float Xs[32][17];
  __shared__ float Wsh[32][160];
  int tid = threadIdx.x;
  int p0g = blockIdx.x * 16;
  int b = p0g / Ll; int p0 = p0g - b * Ll;
  int tx = tid & 15, ty = tid >> 4;
  float acc[10];
  #pragma unroll
  for (int j = 0; j < 10; ++j) acc[j] = 0.f;
  const float* xbase = xc + (size_t)p0g * DIn;
  for (int kc = 0; kc < 192; kc += 32){
    #pragma unroll
    for (int it = 0; it < 2; ++it){
      int e = it * 256 + tid; int dd = e & 31; int m = e >> 5;
      Xs[dd][m] = xbase[(size_t)m * DIn + kc + dd];
    }
    #pragma unroll
    for (int it = 0; it < 20; ++it){
      int e = it * 256 + tid; int dd = e / 160; int n = e - dd * 160;
      Wsh[dd][n] = (n < 152) ? xpwT[(size_t)(kc + dd) * 152 + n] : 0.f;
    }
    __syncthreads();
    #pragma unroll
    for (int dd = 0; dd < 32; ++dd){
      float xv = Xs[dd][ty];
      #pragma unroll
      for (int j = 0; j < 10; ++j)
        acc[j] = fmaf(xv, Wsh[dd][tx + 16 * j], acc[j]);
    }
    __syncthreads();
  }
  int p = p0 + ty;
  #pragma unroll
  for (int j = 0; j < 10; ++j){
    int n = tx + 16 * j;
    if (n >= 152) continue;
    int k = n / 38, jj = n - k * 38;
    int l = l_of(k, p);
    if (jj < 6) dtsG[((size_t)((b * 4 + k) * Ll + l)) * 6 + jj] = acc[j];
    else        bc [((size_t)((b * 4 + k) * Ll + l)) * 32 + (jj - 6)] = acc[j];
  }
}

// ---------------- delta = softplus(dts @ dtw^T + dtb), full occupancy ----------------
__global__ void k_delta(const float* __restrict__ dtsG, const float* __restrict__ dtwT,
                        const float* __restrict__ dtb, float* __restrict__ delta){
  int t = blockIdx.x * 256 + threadIdx.x;
  if (t >= 36864 * DIn) return;
  int d = t % DIn; int row = t / DIn;
  int k = (row / Ll) & 3;
  const float* ds = dtsG + (size_t)row * 6;
  float a = dtb[k * DIn + d];
  #pragma unroll
  for (int r = 0; r < 6; ++r)
    a = fmaf(dtwT[r * 768 + k * DIn + d], ds[r], a);
  float sp = fmaxf(a, 0.f) + __logf(1.0f + __expf(-fabsf(a)));
  delta[(size_t)row * DIn + d] = sp;
}

// ======================= segmented selective scan =======================
// unit = bk*12+g : 192 independent (sequence, 16-channel-group) units.
// lane = ch*4 + ns : ch local channel [0,16), ns handles 4 of 16 states.

// ---- pass A: local scan per segment (h0=0), emit h_end + sum(dt) ----
__global__ __launch_bounds__(64) void k_scanA(const float* __restrict__ delta, const float* __restrict__ bc,
                                              const float* __restrict__ xc, const float* __restrict__ Alog,
                                              float* __restrict__ hend, float* __restrict__ dtsum){
  int blk = blockIdx.x; int unit = blk / Sseg; int seg = blk - unit * Sseg;
  int g = unit % 12; int bk = unit / 12; int k = bk & 3; int b = bk >> 2;
  int lane = threadIdx.x; int ch = lane >> 2; int ns = lane & 3; int nb = ns * 4;
  int d = g * 16 + ch;
  const int arow = (k * DIn + d) * 16 + nb;
  float A0 = -__expf(Alog[arow + 0]);
  float A1 = -__expf(Alog[arow + 1]);
  float A2 = -__expf(Alog[arow + 2]);
  float A3 = -__expf(Alog[arow + 3]);
  float h0 = 0.f, h1 = 0.f, h2 = 0.f, h3 = 0.f, dacc = 0.f;

  const int l0 = seg * SEGLEN;
  const float* dptr = delta + (size_t)(bk * Ll) * DIn + g * 16 + ch;
  const float* bptr = bc    + (size_t)(bk * Ll) * 32 + nb;
  const float* cxb  = xc    + (size_t)(b  * Ll) * DIn + g * 16 + ch;

  float dtA[SC], uA[SC]; float4 BA[SC];
  float dtB[SC], uB[SC]; float4 BB[SC];

  auto load = [&](float (&dtv)[SC], float (&uv)[SC], float4 (&Bv)[SC], int ls){
    #pragma unroll
    for (int i = 0; i < SC; ++i){
      int l = ls + i;
      dtv[i] = dptr[(size_t)l * DIn];
      Bv[i]  = *(const float4*)(bptr + (size_t)l * 32);
      int pix;
      if (k == 0) pix = l;
      else if (k == 2) pix = Ll - 1 - l;
      else { int l2 = (k == 1) ? l : (Ll - 1 - l); pix = (l2 % 48) * 48 + l2 / 48; }
      uv[i] = cxb[(size_t)pix * DIn];
    }
  };

  load(dtA, uA, BA, l0);
  int lcur = l0;
  #pragma unroll 1
  for (int cc = 0; cc < SEGLEN / (2 * SC); ++cc){
    load(dtB, uB, BB, lcur + SC);
    #pragma unroll
    for (int i = 0; i < SC; ++i){
      float dt = dtA[i]; dacc += dt;
      float du = dt * uA[i];
      h0 = fmaf(h0, __expf(dt * A0), du * BA[i].x);
      h1 = fmaf(h1, __expf(dt * A1), du * BA[i].y);
      h2 = fmaf(h2, __expf(dt * A2), du * BA[i].z);
      h3 = fmaf(h3, __expf(dt * A3), du * BA[i].w);
    }
    if (cc < SEGLEN / (2 * SC) - 1) load(dtA, uA, BA, lcur + 2 * SC);
    #pragma unroll
    for (int i = 0; i < SC; ++i){
      float dt = dtB[i]; dacc += dt;
      float du = dt * uB[i];
      h0 = fmaf(h0, __expf(dt * A0), du * BB[i].x);
      h1 = fmaf(h1, __expf(dt * A1), du * BB[i].y);
      h2 = fmaf(h2, __expf(dt * A2), du * BB[i].z);
      h3 = fmaf(h3, __expf(dt * A3), du * BB[i].w);
    }
    lcur += 2 * SC;
  }
  size_t sb = (size_t)unit * Sseg + seg;
  *(float4*)&hend[sb * 256 + lane * 4] = make_float4(h0, h1, h2, h3);
  if (ns == 0) dtsum[sb * 16 + ch] = dacc;
}

// ---- combine: sequential fold over segments -> h_init per segment ----
__global__ __launch_bounds__(64) void k_comb(const float* __restrict__ Alog, const float* __restrict__ hend,
                                             const float* __restrict__ dtsum, float* __restrict__ hinit){
  int unit = blockIdx.x; int g = unit % 12; int bk = unit / 12; int k = bk & 3;
  int lane = threadIdx.x; int ch = lane >> 2; int ns = lane & 3; int nb = ns * 4;
  int d = g * 16 + ch;
  const int arow = (k * DIn + d) * 16 + nb;
  float A0 = -__expf(Alog[arow + 0]);
  float A1 = -__expf(Alog[arow + 1]);
  float A2 = -__expf(Alog[arow + 2]);
  float A3 = -__expf(Alog[arow + 3]);
  float h0 = 0.f, h1 = 0.f, h2 = 0.f, h3 = 0.f;
  for (int s = 0; s < Sseg; ++s){
    size_t sb = (size_t)unit * Sseg + s;
    *(float4*)&hinit[sb * 256 + lane * 4] = make_float4(h0, h1, h2, h3);
    float ds = dtsum[sb * 16 + ch];
    float4 he = *(const float4*)&hend[sb * 256 + lane * 4];
    h0 = fmaf(h0, __expf(A0 * ds), he.x);
    h1 = fmaf(h1, __expf(A1 * ds), he.y);
    h2 = fmaf(h2, __expf(A2 * ds), he.z);
    h3 = fmaf(h3, __expf(A3 * ds), he.w);
  }
}

// ---- pass B: rescan from h_init, emit y ----
__global__ __launch_bounds__(64) void k_scanB(const float* __restrict__ delta, const float* __restrict__ bc,
                                              const float* __restrict__ xc, const float* __restrict__ Alog,
                                              const float* __restrict__ hinit, float* __restrict__ oy){
  int blk = blockIdx.x; int unit = blk / Sseg; int seg = blk - unit * Sseg;
  int g = unit % 12; int bk = unit / 12; int k = bk & 3; int b = bk >> 2;
  int lane = threadIdx.x; int ch = lane >> 2; int ns = lane & 3; int nb = ns * 4;
  int d = g * 16 + ch;
  const int arow = (k * DIn + d) * 16 + nb;
  float A0 = -__expf(Alog[arow + 0]);
  float A1 = -__expf(Alog[arow + 1]);
  float A2 = -__expf(Alog[arow + 2]);
  float A3 = -__expf(Alog[arow + 3]);
  size_t sb = (size_t)unit * Sseg + seg;
  float4 hi = *(const float4*)&hinit[sb * 256 + lane * 4];
  float h0 = hi.x, h1 = hi.y, h2 = hi.z, h3 = hi.w;

  const int l0 = seg * SEGLEN;
  const float* dptr = delta + (size_t)(bk * Ll) * DIn + g * 16 + ch;
  const float* bptr = bc    + (size_t)(bk * Ll) * 32 + nb;
  const float* cxb  = xc    + (size_t)(b  * Ll) * DIn + g * 16 + ch;
  float*       obase = oy   + (size_t)(bk * Ll) * DIn + d;

  float dtA[SC], uA[SC]; float4 BA[SC], CA[SC];
  float dtB[SC], uB[SC]; float4 BB[SC], CB[SC];

  auto load = [&](float (&dtv)[SC], float (&uv)[SC], float4 (&Bv)[SC], float4 (&Cv)[SC], int ls){
    #pragma unroll
    for (int i = 0; i < SC; ++i){
      int l = ls + i;
      dtv[i] = dptr[(size_t)l * DIn];
      Bv[i]  = *(const float4*)(bptr + (size_t)l * 32);
      Cv[i]  = *(const float4*)(bptr + (size_t)l * 32 + 16);
      int pix;
      if (k == 0) pix = l;
      else if (k == 2) pix = Ll - 1 - l;
      else { int l2 = (k == 1) ? l : (Ll - 1 - l); pix = (l2 % 48) * 48 + l2 / 48; }
      uv[i] = cxb[(size_t)pix * DIn];
    }
  };

  load(dtA, uA, BA, CA, l0);
  int lcur = l0;
  #pragma unroll 1
  for (int cc = 0; cc < SEGLEN / (2 * SC); ++cc){
    load(dtB, uB, BB, CB, lcur + SC);
    #pragma unroll
    for (int i = 0; i < SC; ++i){
      float dt = dtA[i];
      float du = dt * uA[i];
      h0 = fmaf(h0, __expf(dt * A0), du * BA[i].x);
      h1 = fmaf(h1, __expf(dt * A1), du * BA[i].y);
      h2 = fmaf(h2, __expf(dt * A2), du * BA[i].z);
      h3 = fmaf(h3, __expf(dt * A3), du * BA[i].w);
      float yp = fmaf(h0, CA[i].x, fmaf(h1, CA[i].y, fmaf(h2, CA[i].z, h3 * CA[i].w)));
      yp += __shfl_xor(yp, 1);
      yp += __shfl_xor(yp, 2);
      if (ns == 0) obase[(size_t)(lcur + i) * DIn] = yp;
    }
    if (cc < SEGLEN / (2 * SC) - 1) load(dtA, uA, BA, CA, lcur + 2 * SC);
    #pragma unroll
    for (int i = 0; i < SC; ++i){
      float dt = dtB[i];
      float du = dt * uB[i];
      h0 = fmaf(h0, __expf(dt * A0), du * BB[i].x);
      h1 = fmaf(h1, __expf(dt * A1), du * BB[i].y);
      h2 = fmaf(h2, __expf(dt * A2), du * BB[i].z);
      h3 = fmaf(h3, __expf(dt * A3), du * BB[i].w);
      float yp = fmaf(h0, CB[i].x, fmaf(h1, CB[i].y, fmaf(h2, CB[i].z, h3 * CB[i].w)));
      yp += __shfl_xor(yp, 1);
      yp += __shfl_xor(yp, 2);
      if (ns == 0) obase[(size_t)(lcur + SC + i) * DIn] = yp;
    }
    lcur += 2 * SC;
  }
}

// ---------------- block reductions ----------------
__device__ inline float block_sum_192(float* red, int d, float v){
  red[d] = v; __syncthreads();
  if (d < 96) red[d] += red[d + 96]; __syncthreads();
  if (d < 48) red[d] += red[d + 48]; __syncthreads();
  if (d < 24) red[d] += red[d + 24]; __syncthreads();
  if (d < 12) red[d] += red[d + 12]; __syncthreads();
  if (d < 6)  red[d] += red[d + 6];  __syncthreads();
  float tot = red[0] + red[1] + red[2] + red[3] + red[4] + red[5];
  __syncthreads();
  return tot;
}
__device__ inline float block_sum_96(float* red, int d, float v){
  if (d < 96) red[d] = v; __syncthreads();
  if (d < 48) red[d] += red[d + 48]; __syncthreads();
  if (d < 24) red[d] += red[d + 24]; __syncthreads();
  if (d < 12) red[d] += red[d + 12]; __syncthreads();
  if (d < 6)  red[d] += red[d + 6];  __syncthreads();
  float tot = red[0] + red[1] + red[2] + red[3] + red[4] + red[5];
  __syncthreads();
  return tot;
}

// ---- combine 4 dirs + LN(192) + z-gate + out-proj + add + LN(96) + squeeze convs (ul) ----
__global__ void k_combine(const float* __restrict__ oy, const float* __restrict__ xc,
                          const float* __restrict__ z, const float* __restrict__ Dp,
                          const float* __restrict__ ong, const float* __restrict__ onb,
                          const float* __restrict__ owT, const float* __restrict__ x2g,
                          const float* __restrict__ lng, const float* __restrict__ lnb,
                          const float* __restrict__ sq1T, const float* __restrict__ sq2T,
                          float* __restrict__ ul){
  int p = blockIdx.x; int b = p / Ll; int pp = p - b * Ll;
  int r = pp / Ww; int cx = pp - r * Ww;
  int d = threadIdx.x;
  __shared__ float red[192];
  __shared__ float ygv[192];
  __shared__ float crs[96];
  int l1 = cx * 48 + r;
  size_t base = (size_t)(b * 4) * Ll * DIn;
  float yv = oy[base + (size_t)(0 * Ll + pp)            * DIn + d]
           + oy[base + (size_t)(1 * Ll + l1)            * DIn + d]
           + oy[base + (size_t)(2 * Ll + (Ll - 1 - pp)) * DIn + d]
           + oy[base + (size_t)(3 * Ll + (Ll - 1 - l1)) * DIn + d];
  float u = xc[(size_t)(b * Ll + pp) * DIn + d];
  float Ds = Dp[d] + Dp[192 + d] + Dp[384 + d] + Dp[576 + d];
  yv = fmaf(u, Ds, yv);
  float mu = block_sum_192(red, d, yv) * (1.f / 192.f);
  float dv = yv - mu;
  float var = block_sum_192(red, d, dv * dv) * (1.f / 192.f);
  float yn = dv * rsqrtf(var + 1e-5f) * ong[d] + onb[d];
  float zv = z[(size_t)(b * Ll + pp) * DIn + d];
  ygv[d] = yn * (zv * sigmf(zv));
  __syncthreads();
  float sval = 0.f;
  if (d < 96){
    float acc = 0.f;
    for (int dd = 0; dd < 192; ++dd) acc = fmaf(owT[dd * 96 + d], ygv[dd], acc);
    sval = acc + x2g[(size_t)p * CHn + d];
  }
  float mu2 = block_sum_96(red, d, sval) * (1.f / 96.f);
  float dv2 = sval - mu2;
  float var2 = block_sum_96(red, d, (d < 96) ? dv2 * dv2 : 0.f) * (1.f / 96.f);
  if (d < 96) crs[d] = dv2 * rsqrtf(var2 + 1e-5f) * lng[d] + lnb[d];
  __syncthreads();
  if (d < 48){
    float a = 0.f;
    if (d < 24){
      for (int i = 0; i < 48; ++i) a = fmaf(sq1T[i * 24 + d], crs[i], a);
    } else {
      int o = d - 24;
      for (int i = 0; i < 48; ++i) a = fmaf(sq2T[i * 24 + o], crs[48 + i], a);
    }
    ul[(size_t)p * 48 + d] = a;
  }
}

// ---------------- CRM main: Y = [gwc(up)+pwc1(up) | pwc2(low) | low] ----------------
__global__ void k_y(const float* __restrict__ ul, const float* __restrict__ gwcT,
                    const float* __restrict__ gwcb, const float* __restrict__ pwc1T,
                    const float* __restrict__ pwc2T, float* __restrict__ Ybig){
  int p = blockIdx.x; int b = p / Ll; int pp = p - b * Ll;
  int r = pp / Ww; int cx = pp - r * Ww;
  int oc = threadIdx.x;
  __shared__ float ulv[48];
  if (oc < 48) ulv[oc] = ul[(size_t)p * 48 + oc];
  __syncthreads();
  float acc;
  if (oc < 96){
    acc = gwcb[oc];
    int grp = oc / 48;
    for (int dy = -1; dy <= 1; ++dy){
      int ny = r + dy; if ((unsigned)ny >= Hh) continue;
      for (int dx = -1; dx <= 1; ++dx){
        int nx = cx + dx; if ((unsigned)nx >= Ww) continue;
        const float* un = ul + (size_t)((b * Ll) + ny * Ww + nx) * 48 + grp * 12;
        int k9 = (dy + 1) * 3 + (dx + 1);
        #pragma unroll
        for (int i = 0; i < 12; ++i) acc = fmaf(gwcT[(i * 9 + k9) * 96 + oc], un[i], acc);
      }
    }
    for (int i = 0; i < 24; ++i) acc = fmaf(pwc1T[i * 96 + oc], ulv[i], acc);
  } else if (oc < 168){
    int o2 = oc - 96; acc = 0.f;
    for (int i = 0; i < 24; ++i) acc = fmaf(pwc2T[i * 72 + o2], ulv[24 + i], acc);
  } else {
    acc = ulv[24 + oc - 168];
  }
  Ybig[(size_t)p * 192 + oc] = acc;
}

// ---------------- coalesced partial spatial sums: 144 blocks x 64-pixel chunks ----------------
__global__ void k_csum(const float* __restrict__ Ybig, float* __restrict__ csum_p){
  int b = blockIdx.x / 36; int ch = blockIdx.x - b * 36;
  int t = threadIdx.x;
  if (t >= 192) return;
  float acc = 0.f;
  const float* base = Ybig + (size_t)(b * Ll + ch * 64) * 192 + t;
  #pragma unroll 4
  for (int i = 0; i < 64; ++i) acc += base[(size_t)i * 192];
  csum_p[(size_t)blockIdx.x * 192 + t] = acc;
}

// ---------------- softmax over 192 channel means ----------------
__global__ void k_softmax(const float* __restrict__ csum_p, float* __restrict__ wsm){
  int b = blockIdx.x; int t = threadIdx.x;
  __shared__ float red[192];
  float m = 0.f;
  for (int cc = 0; cc < 36; ++cc) m += csum_p[(size_t)(b * 36 + cc) * 192 + t];
  m *= (1.f / 2304.f);
  red[t] = m; __syncthreads();
  if (t < 96) red[t] = fmaxf(red[t], red[t + 96]); __syncthreads();
  if (t < 48) red[t] = fmaxf(red[t], red[t + 48]); __syncthreads();
  if (t < 24) red[t] = fmaxf(red[t], red[t + 24]); __syncthreads();
  if (t < 12) red[t] = fmaxf(red[t], red[t + 12]); __syncthreads();
  if (t < 6)  red[t] = fmaxf(red[t], red[t + 6]);  __syncthreads();
  float mx = fmaxf(fmaxf(fmaxf(red[0], red[1]), fmaxf(red[2], red[3])), fmaxf(red[4], red[5]));
  __syncthreads();
  float e = __expf(m - mx);
  float s = block_sum_192(red, t, e);
  wsm[b * 192 + t] = e / s;
}

// ---------------- weighted halves + final linear -> [p][c] (coalesced) ----------------
__global__ void k_final(const float* __restrict__ Ybig, const float* __restrict__ wsm,
                        const float* __restrict__ finT, const float* __restrict__ finb,
                        float* __restrict__ outT){
  int p = blockIdx.x; int b = p / Ll;
  int c = threadIdx.x;
  __shared__ float ov[96];
  float o = wsm[b * 192 + c]      * Ybig[(size_t)p * 192 + c]
          + wsm[b * 192 + 96 + c] * Ybig[(size_t)p * 192 + 96 + c];
  ov[c] = o; __syncthreads();
  float acc = finb[c];
  for (int i = 0; i < 96; ++i) acc = fmaf(finT[i * 96 + c], ov[i], acc);
  outT[(size_t)p * CHn + c] = acc;
}

// ---------------- host launch ----------------
extern "C" void kernel_launch(void* const* d_in, const int* in_sizes, int n_in,
                              void* d_out, int out_size, void* d_ws, size_t ws_size,
                              hipStream_t stream) {
  const float* x     = (const float*)d_in[0];
  const float* w1    = (const float*)d_in[1];
  const float* b1    = (const float*)d_in[2];
  const float* bng   = (const float*)d_in[3];
  const float* bnb   = (const float*)d_in[4];
  const float* linw  = (const float*)d_in[5];
  const float* linb  = (const float*)d_in[6];
  const float* dw1w  = (const float*)d_in[7];
  const float* dw1b  = (const float*)d_in[8];
  const float* dw2w  = (const float*)d_in[9];
  const float* dw2b  = (const float*)d_in[10];
  const float* ag1w  = (const float*)d_in[11];
  const float* ag1b  = (const float*)d_in[12];
  const float* ag2w  = (const float*)d_in[13];
  const float* ag2b  = (const float*)d_in[14];
  const float* lng   = (const float*)d_in[15];
  const float* lnb   = (const float*)d_in[16];
  const float* sq1w  = (const float*)d_in[17];
  const float* sq2w  = (const float*)d_in[18];
  const float* gwcw  = (const float*)d_in[19];
  const float* gwcb  = (const float*)d_in[20];
  const float* pwc1w = (const float*)d_in[21];
  const float* pwc2w = (const float*)d_in[22];
  const float* finw  = (const float*)d_in[23];
  const float* finb  = (const float*)d_in[24];
  const float* inw   = (const float*)d_in[25];
  const float* scw   = (const float*)d_in[26];
  const float* scb   = (const float*)d_in[27];
  const float* xpw   = (const float*)d_in[28];
  const float* dtw   = (const float*)d_in[29];
  const float* dtb   = (const float*)d_in[30];
  const float* Alog  = (const float*)d_in[31];
  const float* Dp    = (const float*)d_in[32];
  const float* ong   = (const float*)d_in[33];
  const float* onb   = (const float*)d_in[34];
  const float* oww   = (const float*)d_in[35];

  float* ws = (float*)d_ws;
  float* hlin  = ws + 0;         // 884736  [k_pre->k_dw]; ul alias later
  float* dtsum = ws + 442368;    // 49152   [scanA->comb]
  float* x1pre = ws + 884736;    // 884736  [k_dw->k_ssin]; hend alias; csum_p/wsm alias later
  float* x2    = ws + 1769472;   // 884736  [k_dw->k_gate]
  float* x2g   = ws + 2654208;   // 884736  [k_gate->k_combine]
  float* xibuf = ws + 3538944;   // 1769472 [k_ssin->k_ssdw]; hinit alias; Ybig alias at k_y
  float* zbuf  = ws + 5308416;   // 1769472 [k_ssin->k_combine]
  float* xcbuf = ws + 7077888;   // 1769472 [k_ssdw-> many]
  float* delta = ws + 8847360;   // 7077888 [k_delta->scan]; outT alias after scanB
  float* dtsG  = ws + 15925248;  // 221184  [k_xproj->k_delta]
  float* bcbuf = ws + 16146432;  // 1179648 [k_xproj->scan]
  float* oy    = ws + 17326080;  // 7077888 [scanB->k_combine]; xT alias early
  float* hend  = x1pre;          // 786432 alias [scanA->comb]
  float* hinit = xibuf;          // 786432 alias [comb->scanB]
  float* ulb   = hlin;           // 442368 alias [k_combine->k_y]
  float* Ybig  = xibuf;          // alias
  float* csum_p = x1pre;         // 27648 alias (after hend dead)
  float* wsmb  = x1pre + 27648;  // alias
  float* xT    = oy;             // 884736 alias [k_trx->k_pre, dead before scanB]
  float* outT  = delta;          // 884736 alias [k_final->k_tro, delta dead after scanB]
  // transposed weights region
  float* wT = ws + 24403968;     // 142656 floats
  float* w1T   = wT + 0;
  float* linT  = wT + 9216;
  float* ag1T  = wT + 18432;
  float* ag2T  = wT + 23040;
  float* inT   = wT + 27648;
  float* owT   = wT + 64512;
  float* pwc1T = wT + 82944;
  float* pwc2T = wT + 85248;
  float* finT  = wT + 86976;
  float* sq1T  = wT + 96192;
  float* sq2T  = wT + 97344;
  float* gwcT  = wT + 98496;
  float* dtwT  = wT + 108864;
  float* xpwT  = wT + 113472;

  TArgs ta;
  const float* srcs[14] = {w1, linw, ag1w, ag2w, inw, oww, pwc1w, pwc2w, finw, sq1w, sq2w, gwcw, dtw, xpw};
  float* dsts[14]       = {w1T, linT, ag1T, ag2T, inT, owT, pwc1T, pwc2T, finT, sq1T, sq2T, gwcT, dtwT, xpwT};
  int rows[14] = {96, 96, 48, 96, 384, 96, 96, 72, 96, 24, 24, 96, 768, 152};
  int cols[14] = {96, 96, 96, 48, 96, 192, 24, 24, 96, 48, 48, 108, 6, 192};
  for (int i = 0; i < 14; ++i){ ta.s[i] = srcs[i]; ta.d[i] = dsts[i]; ta.rows[i] = rows[i]; ta.cols[i] = cols[i]; }

  k_tr<<<dim3(144, 14), 256, 0, stream>>>(ta);
  k_trx<<<dim3(72, 3, 4), 256, 0, stream>>>(x, xT);
  k_pre<<<Pp, CHn, 0, stream>>>(xT, w1T, b1, bng, bnb, linT, linb, hlin);
  k_dw<<<(Pp * CHn) / 256, 256, 0, stream>>>(hlin, dw1w, dw1b, dw2w, dw2b, x1pre, x2);
  k_gate<<<Pp, CHn, 0, stream>>>(x2, ag1T, ag1b, ag2T, ag2b, x2g);
  k_ssin<<<288 * 3, 256, 0, stream>>>(x1pre, inT, xibuf, zbuf);
  k_ssdw<<<(Pp * DIn) / 256, 256, 0, stream>>>(xibuf, scw, scb, xcbuf);
  k_xproj<<<576, 256, 0, stream>>>(xcbuf, xpwT, bcbuf, dtsG);
  k_delta<<<(36864 * DIn) / 256, 256, 0, stream>>>(dtsG, dtwT, dtb, delta);
  k_scanA<<<192 * Sseg, 64, 0, stream>>>(delta, bcbuf, xcbuf, Alog, hend, dtsum);
  k_comb<<<192, 64, 0, stream>>>(Alog, hend, dtsum, hinit);
  k_scanB<<<192 * Sseg, 64, 0, stream>>>(delta, bcbuf, xcbuf, Alog, hinit, oy);
  k_combine<<<Pp, DIn, 0, stream>>>(oy, xcbuf, zbuf, Dp, ong, onb, owT, x2g, lng, lnb, sq1T, sq2T, ulb);
  k_y<<<Pp, 192, 0, stream>>>(ulb, gwcT, gwcb, pwc1T, pwc2T, Ybig);
  k_csum<<<144, 256, 0, stream>>>(Ybig, csum_p);
  k_softmax<<<4, 192, 0, stream>>>(csum_p, wsmb);
  k_final<<<Pp, CHn, 0, stream>>>(Ybig, wsmb, finT, finb, outT);
  k_tro<<<dim3(72, 3, 4), 256, 0, stream>>>(outT, (float*)d_out);
}

// Round 5
// 380.782 us; speedup vs baseline: 2.1467x; 1.1346x over previous
//
#include <hip/hip_runtime.h>
#include <hip/hip_bf16.h>

// Problem constants
#define Bn   4
#define CHn  96
#define Hh   48
#define Ww   48
#define Ll   2304      // H*W
#define Pp   9216      // B*L
#define DIn  192
#define Nn   16
#define Rr   6
#define Sseg   32      // scan segments per sequence
#define SEGL   72      // 2304 / 32
#define NCH     9      // 72 / 8 chunks
#define HSPLIT 884736  // hinit split boundary (floats)

__device__ inline float siluf(float x){ return x / (1.0f + __expf(-x)); }
__device__ inline float sigmf(float x){ return 1.0f / (1.0f + __expf(-x)); }

__device__ inline int pix_of(int k, int l){
  if (k == 0) return l;
  if (k == 1) return (l % 48) * 48 + l / 48;
  if (k == 2) return Ll - 1 - l;
  int lr = Ll - 1 - l; return (lr % 48) * 48 + lr / 48;
}
// row index l for direction k such that pix_of(k,l) == p
__device__ inline int l_of(int k, int p){
  if (k == 0) return p;
  if (k == 1) return (p % 48) * 48 + p / 48;
  if (k == 2) return Ll - 1 - p;
  return Ll - 1 - ((p % 48) * 48 + p / 48);
}

// split-region hinit accessor (boundary is a multiple of 256 -> float4 never straddles)
__device__ inline float4* hptr(float* lo, float* hi, size_t idx){
  return (float4*)(idx < HSPLIT ? lo + idx : hi + (idx - HSPLIT));
}

// ---------------- transpose-all-weights kernel (one launch) ----------------
struct TArgs {
  const float* s[14];
  float* d[14];
  int rows[14];
  int cols[14];
};
__global__ void k_tr(TArgs a){
  int id = blockIdx.y;
  int n = a.rows[id] * a.cols[id];
  int t = blockIdx.x * blockDim.x + threadIdx.x;
  if (t < n){
    int r = t / a.cols[id];
    int c = t - r * a.cols[id];
    a.d[id][c * a.rows[id] + r] = a.s[id][t];
  }
}

// ---------------- NCHW -> NHWC transpose of input x ----------------
__global__ void k_trx(const float* __restrict__ src, float* __restrict__ dst){
  __shared__ float tile[32][33];
  int pt = blockIdx.x, ct = blockIdx.y, b = blockIdx.z;
  int tx = threadIdx.x & 31, ty = threadIdx.x >> 5;
  #pragma unroll
  for (int i = 0; i < 4; ++i){
    int r = ty + i * 8;
    tile[r][tx] = src[((size_t)(b * CHn + ct * 32 + r)) * Ll + pt * 32 + tx];
  }
  __syncthreads();
  #pragma unroll
  for (int i = 0; i < 4; ++i){
    int r = ty + i * 8;
    dst[((size_t)(b * Ll + pt * 32 + r)) * CHn + ct * 32 + tx] = tile[tx][r];
  }
}

// ---------------- [p][c] -> NCHW transpose of output ----------------
__global__ void k_tro(const float* __restrict__ src, float* __restrict__ dst){
  __shared__ float tile[32][33];
  int pt = blockIdx.x, ct = blockIdx.y, b = blockIdx.z;
  int tx = threadIdx.x & 31, ty = threadIdx.x >> 5;
  #pragma unroll
  for (int i = 0; i < 4; ++i){
    int r = ty + i * 8;
    tile[r][tx] = src[((size_t)(b * Ll + pt * 32 + r)) * CHn + ct * 32 + tx];
  }
  __syncthreads();
  #pragma unroll
  for (int i = 0; i < 4; ++i){
    int r = ty + i * 8;
    dst[((size_t)(b * CHn + ct * 32 + r)) * Ll + pt * 32 + tx] = tile[tx][r];
  }
}

// ---------------- conv1x1 + BN + ReLU + channel linear ----------------
__global__ void k_pre(const float* __restrict__ xT, const float* __restrict__ w1T, const float* __restrict__ b1,
                      const float* __restrict__ bng, const float* __restrict__ bnb,
                      const float* __restrict__ linT, const float* __restrict__ lb,
                      float* __restrict__ hlin){
  int p = blockIdx.x;
  int c = threadIdx.x;
  __shared__ float xv[CHn];
  __shared__ float hv[CHn];
  xv[c] = xT[(size_t)p * CHn + c];
  __syncthreads();
  float acc = 0.f;
  for (int i = 0; i < CHn; ++i) acc = fmaf(w1T[i * CHn + c], xv[i], acc);
  float s = bng[c] * rsqrtf(1.0f + 1e-5f);
  float h = fmaxf((acc + b1[c]) * s + bnb[c], 0.f);
  hv[c] = h;
  __syncthreads();
  float a2 = lb[c];
  for (int i = 0; i < CHn; ++i) a2 = fmaf(linT[i * CHn + c], hv[i], a2);
  hlin[(size_t)p * CHn + c] = a2;
}

// ---------------- two depthwise 3x3 convs + SiLU ----------------
__global__ void k_dw(const float* __restrict__ hlin,
                     const float* __restrict__ dw1w, const float* __restrict__ dw1b,
                     const float* __restrict__ dw2w, const float* __restrict__ dw2b,
                     float* __restrict__ x1pre, float* __restrict__ x2){
  int t = blockIdx.x * 256 + threadIdx.x;
  if (t >= Pp * CHn) return;
  int c = t % CHn; int p = t / CHn; int b = p / Ll; int pp = p - b * Ll;
  int r = pp / Ww; int cx = pp - r * Ww;
  float a1 = dw1b[c], a2 = dw2b[c];
  for (int dy = -1; dy <= 1; ++dy){
    int ny = r + dy; if ((unsigned)ny >= Hh) continue;
    for (int dx = -1; dx <= 1; ++dx){
      int nx = cx + dx; if ((unsigned)nx >= Ww) continue;
      float v = hlin[(size_t)((b * Ll) + ny * Ww + nx) * CHn + c];
      int wi = c * 9 + (dy + 1) * 3 + (dx + 1);
      a1 = fmaf(dw1w[wi], v, a1);
      a2 = fmaf(dw2w[wi], v, a2);
    }
  }
  x1pre[t] = siluf(a1);
  x2[t]   = siluf(a2);
}

// ---------------- attention gate ----------------
__global__ void k_gate(const float* __restrict__ x2,
                       const float* __restrict__ ag1T, const float* __restrict__ ag1b,
                       const float* __restrict__ ag2T, const float* __restrict__ ag2b,
                       float* __restrict__ x2g){
  int p = blockIdx.x; int c = threadIdx.x;
  __shared__ float xv[CHn];
  __shared__ float rv[48];
  xv[c] = x2[(size_t)p * CHn + c];
  __syncthreads();
  if (c < 48){
    float a = ag1b[c];
    for (int i = 0; i < CHn; ++i) a = fmaf(ag1T[i * 48 + c], xv[i], a);
    rv[c] = fmaxf(a, 0.f);
  }
  __syncthreads();
  float a2 = ag2b[c];
  for (int tt = 0; tt < 48; ++tt) a2 = fmaf(ag2T[tt * CHn + c], rv[tt], a2);
  x2g[(size_t)p * CHn + c] = xv[c] * sigmf(a2);
}

// ---------------- SS2D input projection (GEMM-tiled) ----------------
__global__ __launch_bounds__(256) void k_ssin(const float* __restrict__ x1pre, const float* __restrict__ inT,
                                              float* __restrict__ xi, float* __restrict__ z){
  __shared__ float Xs[32][34];
  __shared__ float Wsh[32][128];
  int tid = threadIdx.x;
  int mt = blockIdx.x % 288; int nt = blockIdx.x / 288;
  int p0 = mt * 32, n0 = nt * 128;
  int tx = tid & 15, ty = tid >> 4;
  float acc[2][8];
  #pragma unroll
  for (int i = 0; i < 2; ++i)
    #pragma unroll
    for (int j = 0; j < 8; ++j) acc[i][j] = 0.f;
  for (int kc = 0; kc < 96; kc += 32){
    #pragma unroll
    for (int it = 0; it < 4; ++it){
      int e = it * 256 + tid; int dd = e & 31; int m = e >> 5;
      Xs[dd][m] = x1pre[(size_t)(p0 + m) * CHn + kc + dd];
    }
    #pragma unroll
    for (int it = 0; it < 16; ++it){
      int e = it * 256 + tid; int n = e & 127; int dd = e >> 7;
      Wsh[dd][n] = inT[(size_t)(kc + dd) * 384 + n0 + n];
    }
    __syncthreads();
    #pragma unroll
    for (int dd = 0; dd < 32; ++dd){
      float2 xv = *(const float2*)&Xs[dd][ty * 2];
      #pragma unroll
      for (int j = 0; j < 8; ++j){
        float w = Wsh[dd][tx + 16 * j];
        acc[0][j] = fmaf(xv.x, w, acc[0][j]);
        acc[1][j] = fmaf(xv.y, w, acc[1][j]);
      }
    }
    __syncthreads();
  }
  #pragma unroll
  for (int i = 0; i < 2; ++i){
    int p = p0 + ty * 2 + i;
    #pragma unroll
    for (int j = 0; j < 8; ++j){
      int n = n0 + tx + 16 * j;
      float v = acc[i][j];
      if (n < 192) xi[(size_t)p * DIn + n] = v;
      else         z [(size_t)p * DIn + (n - 192)] = v;
    }
  }
}

// ---------------- SS2D depthwise 3x3 + SiLU ----------------
__global__ void k_ssdw(const float* __restrict__ xi, const float* __restrict__ scw,
                       const float* __restrict__ scb, float* __restrict__ xc){
  int t = blockIdx.x * 256 + threadIdx.x;
  if (t >= Pp * DIn) return;
  int d = t % DIn; int p = t / DIn; int b = p / Ll; int pp = p - b * Ll;
  int r = pp / Ww; int cx = pp - r * Ww;
  float a = scb[d];
  for (int dy = -1; dy <= 1; ++dy){
    int ny = r + dy; if ((unsigned)ny >= Hh) continue;
    for (int dx = -1; dx <= 1; ++dx){
      int nx = cx + dx; if ((unsigned)nx >= Ww) continue;
      float v = xi[(size_t)((b * Ll) + ny * Ww + nx) * DIn + d];
      a = fmaf(scw[d * 9 + (dy + 1) * 3 + (dx + 1)], v, a);
    }
  }
  xc[t] = siluf(a);
}

// ---------------- xproj GEMM: scatter B/C + dt-rank ----------------
__global__ __launch_bounds__(256) void k_xproj(const float* __restrict__ xc,
    const float* __restrict__ xpwT, float* __restrict__ bc, float* __restrict__ dtsG){
  __shared__ float Xs[32][17];
  __shared__ float Wsh[32][160];
  int tid = threadIdx.x;
  int p0g = blockIdx.x * 16;
  int b = p0g / Ll; int p0 = p0g - b * Ll;
  int tx = tid & 15, ty = tid >> 4;
  float acc[10];
  #pragma unroll
  for (int j = 0; j < 10; ++j) acc[j] = 0.f;
  const float* xbase = xc + (size_t)p0g * DIn;
  for (int kc = 0; kc < 192; kc += 32){
    #pragma unroll
    for (int it = 0; it < 2; ++it){
      int e = it * 256 + tid; int dd = e & 31; int m = e >> 5;
      Xs[dd][m] = xbase[(size_t)m * DIn + kc + dd];
    }
    #pragma unroll
    for (int it = 0; it < 20; ++it){
      int e = it * 256 + tid; int dd = e / 160; int n = e - dd * 160;
      Wsh[dd][n] = (n < 152) ? xpwT[(size_t)(kc + dd) * 152 + n] : 0.f;
    }
    __syncthreads();
    #pragma unroll
    for (int dd = 0; dd < 32; ++dd){
      float xv = Xs[dd][ty];
      #pragma unroll
      for (int j = 0; j < 10; ++j)
        acc[j] = fmaf(xv, Wsh[dd][tx + 16 * j], acc[j]);
    }
    __syncthreads();
  }
  int p = p0 + ty;
  #pragma unroll
  for (int j = 0; j < 10; ++j){
    int n = tx + 16 * j;
    if (n >= 152) continue;
    int k = n / 38, jj = n - k * 38;
    int l = l_of(k, p);
    if (jj < 6) dtsG[((size_t)((b * 4 + k) * Ll + l)) * 6 + jj] = acc[j];
    else        bc [((size_t)((b * 4 + k) * Ll + l)) * 32 + (jj - 6)] = acc[j];
  }
}

// ---------------- pack: delta softplus + u-gather -> packed[unit][l][dt16|du16] ----------------
__global__ void k_pack(const float* __restrict__ dtsG, const float* __restrict__ dtwT,
                       const float* __restrict__ dtb, const float* __restrict__ xc,
                       float* __restrict__ packed){
  int t = blockIdx.x * 256 + threadIdx.x;
  if (t >= 36864 * DIn) return;
  int d = t % DIn; int row = t / DIn;
  int bk = row / Ll; int l = row - bk * Ll;
  int k = bk & 3; int b = bk >> 2;
  const float* ds = dtsG + (size_t)row * 6;
  float a = dtb[k * DIn + d];
  #pragma unroll
  for (int r = 0; r < 6; ++r)
    a = fmaf(dtwT[r * 768 + k * DIn + d], ds[r], a);
  float dt = fmaxf(a, 0.f) + __logf(1.0f + __expf(-fabsf(a)));
  int pix = pix_of(k, l);
  float u = xc[((size_t)(b * Ll) + pix) * DIn + d];
  int unit = bk * 12 + (d >> 4);
  size_t base = ((size_t)unit * Ll + l) * 32 + (d & 15);
  packed[base]      = dt;
  packed[base + 16] = dt * u;
}

// ======================= segmented selective scan =======================
// unit = bk*12+g : 192 units; Sseg=32 segments of SEGL=72 steps.
// lane = ch*4 + ns : ch local channel [0,16), ns handles 4 of 16 states.

// ---- pass A: local scan per segment (h0=0), emit h_end + sum(dt) ----
__global__ __launch_bounds__(64) void k_scanA(const float* __restrict__ packed, const float* __restrict__ bc,
                                              const float* __restrict__ Alog,
                                              float* __restrict__ hend, float* __restrict__ dtsum){
  int blk = blockIdx.x; int unit = blk >> 5; int seg = blk & 31;
  int g = unit % 12; int bk = unit / 12; int k = bk & 3;
  int lane = threadIdx.x; int ch = lane >> 2; int ns = lane & 3; int nb = ns * 4;
  int d = g * 16 + ch;
  const int arow = (k * DIn + d) * 16 + nb;
  float A0 = -__expf(Alog[arow + 0]);
  float A1 = -__expf(Alog[arow + 1]);
  float A2 = -__expf(Alog[arow + 2]);
  float A3 = -__expf(Alog[arow + 3]);
  float h0 = 0.f, h1 = 0.f, h2 = 0.f, h3 = 0.f, dacc = 0.f;

  const int l0 = seg * SEGL;
  const float* pbase = packed + ((size_t)unit * Ll + l0) * 32;
  const float* bbase = bc + ((size_t)(bk * Ll) + l0) * 32;

  __shared__ float pl[256];
  __shared__ float blA[128];

  // prologue: chunk 0
  float4 pn = *(const float4*)(pbase + lane * 4);
  float4 bn;
  if (lane < 32) bn = *(const float4*)(bbase + (size_t)(lane >> 2) * 32 + (lane & 3) * 4);
  *(float4*)&pl[lane * 4] = pn;
  if (lane < 32) *(float4*)&blA[lane * 4] = bn;
  __syncthreads();

  for (int cc = 0; cc < NCH; ++cc){
    bool more = (cc + 1 < NCH);
    if (more){
      pn = *(const float4*)(pbase + (cc + 1) * 256 + lane * 4);
      if (lane < 32) bn = *(const float4*)(bbase + (size_t)((cc + 1) * 8 + (lane >> 2)) * 32 + (lane & 3) * 4);
    }
    #pragma unroll
    for (int lp = 0; lp < 8; ++lp){
      float dt = pl[lp * 32 + ch];
      float du = pl[lp * 32 + 16 + ch];
      float4 Bv = *(const float4*)&blA[lp * 16 + nb];
      dacc += dt;
      h0 = fmaf(h0, __expf(dt * A0), du * Bv.x);
      h1 = fmaf(h1, __expf(dt * A1), du * Bv.y);
      h2 = fmaf(h2, __expf(dt * A2), du * Bv.z);
      h3 = fmaf(h3, __expf(dt * A3), du * Bv.w);
    }
    __syncthreads();
    if (more){
      *(float4*)&pl[lane * 4] = pn;
      if (lane < 32) *(float4*)&blA[lane * 4] = bn;
    }
    __syncthreads();
  }
  size_t sb = (size_t)unit * Sseg + seg;
  *(float4*)&hend[sb * 256 + lane * 4] = make_float4(h0, h1, h2, h3);
  if (ns == 0) dtsum[sb * 16 + ch] = dacc;
}

// ---- combine: sequential fold over segments -> h_init per segment ----
__global__ __launch_bounds__(64) void k_comb(const float* __restrict__ Alog, const float* __restrict__ hend,
                                             const float* __restrict__ dtsum,
                                             float* __restrict__ hlo, float* __restrict__ hhi){
  int unit = blockIdx.x; int g = unit % 12; int bk = unit / 12; int k = bk & 3;
  int lane = threadIdx.x; int ch = lane >> 2; int ns = lane & 3; int nb = ns * 4;
  int d = g * 16 + ch;
  const int arow = (k * DIn + d) * 16 + nb;
  float A0 = -__expf(Alog[arow + 0]);
  float A1 = -__expf(Alog[arow + 1]);
  float A2 = -__expf(Alog[arow + 2]);
  float A3 = -__expf(Alog[arow + 3]);
  float h0 = 0.f, h1 = 0.f, h2 = 0.f, h3 = 0.f;
  for (int s = 0; s < Sseg; ++s){
    size_t sb = (size_t)unit * Sseg + s;
    *hptr(hlo, hhi, sb * 256 + lane * 4) = make_float4(h0, h1, h2, h3);
    float dsv = dtsum[sb * 16 + ch];
    float4 he = *(const float4*)&hend[sb * 256 + lane * 4];
    h0 = fmaf(h0, __expf(A0 * dsv), he.x);
    h1 = fmaf(h1, __expf(A1 * dsv), he.y);
    h2 = fmaf(h2, __expf(A2 * dsv), he.z);
    h3 = fmaf(h3, __expf(A3 * dsv), he.w);
  }
}

// ---- pass B: rescan from h_init, atomically accumulate y into ysum[b][pix][d] ----
__global__ __launch_bounds__(64) void k_scanB(const float* __restrict__ packed, const float* __restrict__ bc,
                                              const float* __restrict__ Alog,
                                              float* __restrict__ hlo, float* __restrict__ hhi,
                                              float* __restrict__ ysum){
  int blk = blockIdx.x; int unit = blk >> 5; int seg = blk & 31;
  int g = unit % 12; int bk = unit / 12; int k = bk & 3; int b = bk >> 2;
  int lane = threadIdx.x; int ch = lane >> 2; int ns = lane & 3; int nb = ns * 4;
  int d = g * 16 + ch;
  const int arow = (k * DIn + d) * 16 + nb;
  float A0 = -__expf(Alog[arow + 0]);
  float A1 = -__expf(Alog[arow + 1]);
  float A2 = -__expf(Alog[arow + 2]);
  float A3 = -__expf(Alog[arow + 3]);
  size_t sb = (size_t)unit * Sseg + seg;
  float4 hi = *hptr(hlo, hhi, sb * 256 + lane * 4);
  float h0 = hi.x, h1 = hi.y, h2 = hi.z, h3 = hi.w;

  const int l0 = seg * SEGL;
  const float* pbase = packed + ((size_t)unit * Ll + l0) * 32;
  const float* bbase = bc + ((size_t)(bk * Ll) + l0) * 32;
  float* ybase = ysum + (size_t)(b * Ll) * DIn + d;

  __shared__ float pl[256];
  __shared__ float bl[256];

  float4 pn = *(const float4*)(pbase + lane * 4);
  float4 bn = *(const float4*)(bbase + lane * 4);
  *(float4*)&pl[lane * 4] = pn;
  *(float4*)&bl[lane * 4] = bn;
  __syncthreads();

  for (int cc = 0; cc < NCH; ++cc){
    bool more = (cc + 1 < NCH);
    if (more){
      pn = *(const float4*)(pbase + (cc + 1) * 256 + lane * 4);
      bn = *(const float4*)(bbase + (cc + 1) * 256 + lane * 4);
    }
    #pragma unroll
    for (int lp = 0; lp < 8; ++lp){
      float dt = pl[lp * 32 + ch];
      float du = pl[lp * 32 + 16 + ch];
      float4 Bv = *(const float4*)&bl[lp * 32 + nb];
      float4 Cv = *(const float4*)&bl[lp * 32 + 16 + nb];
      h0 = fmaf(h0, __expf(dt * A0), du * Bv.x);
      h1 = fmaf(h1, __expf(dt * A1), du * Bv.y);
      h2 = fmaf(h2, __expf(dt * A2), du * Bv.z);
      h3 = fmaf(h3, __expf(dt * A3), du * Bv.w);
      float yp = fmaf(h0, Cv.x, fmaf(h1, Cv.y, fmaf(h2, Cv.z, h3 * Cv.w)));
      yp += __shfl_xor(yp, 1);
      yp += __shfl_xor(yp, 2);
      if (ns == 0){
        int l = l0 + cc * 8 + lp;
        int pix = pix_of(k, l);
        atomicAdd(ybase + (size_t)pix * DIn, yp);
      }
    }
    __syncthreads();
    if (more){
      *(float4*)&pl[lane * 4] = pn;
      *(float4*)&bl[lane * 4] = bn;
    }
    __syncthreads();
  }
}

// ---------------- block reductions ----------------
__device__ inline float block_sum_192(float* red, int d, float v){
  red[d] = v; __syncthreads();
  if (d < 96) red[d] += red[d + 96]; __syncthreads();
  if (d < 48) red[d] += red[d + 48]; __syncthreads();
  if (d < 24) red[d] += red[d + 24]; __syncthreads();
  if (d < 12) red[d] += red[d + 12]; __syncthreads();
  if (d < 6)  red[d] += red[d + 6];  __syncthreads();
  float tot = red[0] + red[1] + red[2] + red[3] + red[4] + red[5];
  __syncthreads();
  return tot;
}
__device__ inline float block_sum_96(float* red, int d, float v){
  if (d < 96) red[d] = v; __syncthreads();
  if (d < 48) red[d] += red[d + 48]; __syncthreads();
  if (d < 24) red[d] += red[d + 24]; __syncthreads();
  if (d < 12) red[d] += red[d + 12]; __syncthreads();
  if (d < 6)  red[d] += red[d + 6];  __syncthreads();
  float tot = red[0] + red[1] + red[2] + red[3] + red[4] + red[5];
  __syncthreads();
  return tot;
}

// ---- combine: ysum + D·u + LN(192) + z-gate + out-proj + add + LN(96) + squeeze ----
__global__ void k_combine(const float* __restrict__ ysum, const float* __restrict__ xc,
                          const float* __restrict__ z, const float* __restrict__ Dp,
                          const float* __restrict__ ong, const float* __restrict__ onb,
                          const float* __restrict__ owT, const float* __restrict__ x2g,
                          const float* __restrict__ lng, const float* __restrict__ lnb,
                          const float* __restrict__ sq1T, const float* __restrict__ sq2T,
                          float* __restrict__ ul){
  int p = blockIdx.x;
  int d = threadIdx.x;
  __shared__ float red[192];
  __shared__ float ygv[192];
  __shared__ float crs[96];
  float yv = ysum[(size_t)p * DIn + d];
  float u = xc[(size_t)p * DIn + d];
  float Ds = Dp[d] + Dp[192 + d] + Dp[384 + d] + Dp[576 + d];
  yv = fmaf(u, Ds, yv);
  float mu = block_sum_192(red, d, yv) * (1.f / 192.f);
  float dv = yv - mu;
  float var = block_sum_192(red, d, dv * dv) * (1.f / 192.f);
  float yn = dv * rsqrtf(var + 1e-5f) * ong[d] + onb[d];
  float zv = z[(size_t)p * DIn + d];
  ygv[d] = yn * (zv * sigmf(zv));
  __syncthreads();
  float sval = 0.f;
  if (d < 96){
    float acc = 0.f;
    for (int dd = 0; dd < 192; ++dd) acc = fmaf(owT[dd * 96 + d], ygv[dd], acc);
    sval = acc + x2g[(size_t)p * CHn + d];
  }
  float mu2 = block_sum_96(red, d, sval) * (1.f / 96.f);
  float dv2 = sval - mu2;
  float var2 = block_sum_96(red, d, (d < 96) ? dv2 * dv2 : 0.f) * (1.f / 96.f);
  if (d < 96) crs[d] = dv2 * rsqrtf(var2 + 1e-5f) * lng[d] + lnb[d];
  __syncthreads();
  if (d < 48){
    float a = 0.f;
    if (d < 24){
      for (int i = 0; i < 48; ++i) a = fmaf(sq1T[i * 24 + d], crs[i], a);
    } else {
      int o = d - 24;
      for (int i = 0; i < 48; ++i) a = fmaf(sq2T[i * 24 + o], crs[48 + i], a);
    }
    ul[(size_t)p * 48 + d] = a;
  }
}

// ---------------- CRM main ----------------
__global__ void k_y(const float* __restrict__ ul, const float* __restrict__ gwcT,
                    const float* __restrict__ gwcb, const float* __restrict__ pwc1T,
                    const float* __restrict__ pwc2T, float* __restrict__ Ybig){
  int p = blockIdx.x; int b = p / Ll; int pp = p - b * Ll;
  int r = pp / Ww; int cx = pp - r * Ww;
  int oc = threadIdx.x;
  __shared__ float ulv[48];
  if (oc < 48) ulv[oc] = ul[(size_t)p * 48 + oc];
  __syncthreads();
  float acc;
  if (oc < 96){
    acc = gwcb[oc];
    int grp = oc / 48;
    for (int dy = -1; dy <= 1; ++dy){
      int ny = r + dy; if ((unsigned)ny >= Hh) continue;
      for (int dx = -1; dx <= 1; ++dx){
        int nx = cx + dx; if ((unsigned)nx >= Ww) continue;
        const float* un = ul + (size_t)((b * Ll) + ny * Ww + nx) * 48 + grp * 12;
        int k9 = (dy + 1) * 3 + (dx + 1);
        #pragma unroll
        for (int i = 0; i < 12; ++i) acc = fmaf(gwcT[(i * 9 + k9) * 96 + oc], un[i], acc);
      }
    }
    for (int i = 0; i < 24; ++i) acc = fmaf(pwc1T[i * 96 + oc], ulv[i], acc);
  } else if (oc < 168){
    int o2 = oc - 96; acc = 0.f;
    for (int i = 0; i < 24; ++i) acc = fmaf(pwc2T[i * 72 + o2], ulv[24 + i], acc);
  } else {
    acc = ulv[24 + oc - 168];
  }
  Ybig[(size_t)p * 192 + oc] = acc;
}

// ---------------- coalesced partial spatial sums ----------------
__global__ void k_csum(const float* __restrict__ Ybig, float* __restrict__ csum_p){
  int b = blockIdx.x / 36; int ch = blockIdx.x - b * 36;
  int t = threadIdx.x;
  if (t >= 192) return;
  float acc = 0.f;
  const float* base = Ybig + (size_t)(b * Ll + ch * 64) * 192 + t;
  #pragma unroll 4
  for (int i = 0; i < 64; ++i) acc += base[(size_t)i * 192];
  csum_p[(size_t)blockIdx.x * 192 + t] = acc;
}

// ---------------- softmax over 192 channel means ----------------
__global__ void k_softmax(const float* __restrict__ csum_p, float* __restrict__ wsm){
  int b = blockIdx.x; int t = threadIdx.x;
  __shared__ float red[192];
  float m = 0.f;
  for (int cc = 0; cc < 36; ++cc) m += csum_p[(size_t)(b * 36 + cc) * 192 + t];
  m *= (1.f / 2304.f);
  red[t] = m; __syncthreads();
  if (t < 96) red[t] = fmaxf(red[t], red[t + 96]); __syncthreads();
  if (t < 48) red[t] = fmaxf(red[t], red[t + 48]); __syncthreads();
  if (t < 24) red[t] = fmaxf(red[t], red[t + 24]); __syncthreads();
  if (t < 12) red[t] = fmaxf(red[t], red[t + 12]); __syncthreads();
  if (t < 6)  red[t] = fmaxf(red[t], red[t + 6]);  __syncthreads();
  float mx = fmaxf(fmaxf(fmaxf(red[0], red[1]), fmaxf(red[2], red[3])), fmaxf(red[4], red[5]));
  __syncthreads();
  float e = __expf(m - mx);
  float s = block_sum_192(red, t, e);
  wsm[b * 192 + t] = e / s;
}

// ---------------- weighted halves + final linear -> [p][c] ----------------
__global__ void k_final(const float* __restrict__ Ybig, const float* __restrict__ wsm,
                        const float* __restrict__ finT, const float* __restrict__ finb,
                        float* __restrict__ outT){
  int p = blockIdx.x; int b = p / Ll;
  int c = threadIdx.x;
  __shared__ float ov[96];
  float o = wsm[b * 192 + c]      * Ybig[(size_t)p * 192 + c]
          + wsm[b * 192 + 96 + c] * Ybig[(size_t)p * 192 + 96 + c];
  ov[c] = o; __syncthreads();
  float acc = finb[c];
  for (int i = 0; i < 96; ++i) acc = fmaf(finT[i * 96 + c], ov[i], acc);
  outT[(size_t)p * CHn + c] = acc;
}

// ---------------- host launch ----------------
extern "C" void kernel_launch(void* const* d_in, const int* in_sizes, int n_in,
                              void* d_out, int out_size, void* d_ws, size_t ws_size,
                              hipStream_t stream) {
  const float* x     = (const float*)d_in[0];
  const float* w1    = (const float*)d_in[1];
  const float* b1    = (const float*)d_in[2];
  const float* bng   = (const float*)d_in[3];
  const float* bnb   = (const float*)d_in[4];
  const float* linw  = (const float*)d_in[5];
  const float* linb  = (const float*)d_in[6];
  const float* dw1w  = (const float*)d_in[7];
  const float* dw1b  = (const float*)d_in[8];
  const float* dw2w  = (const float*)d_in[9];
  const float* dw2b  = (const float*)d_in[10];
  const float* ag1w  = (const float*)d_in[11];
  const float* ag1b  = (const float*)d_in[12];
  const float* ag2w  = (const float*)d_in[13];
  const float* ag2b  = (const float*)d_in[14];
  const float* lng   = (const float*)d_in[15];
  const float* lnb   = (const float*)d_in[16];
  const float* sq1w  = (const float*)d_in[17];
  const float* sq2w  = (const float*)d_in[18];
  const float* gwcw  = (const float*)d_in[19];
  const float* gwcb  = (const float*)d_in[20];
  const float* pwc1w = (const float*)d_in[21];
  const float* pwc2w = (const float*)d_in[22];
  const float* finw  = (const float*)d_in[23];
  const float* finb  = (const float*)d_in[24];
  const float* inw   = (const float*)d_in[25];
  const float* scw   = (const float*)d_in[26];
  const float* scb   = (const float*)d_in[27];
  const float* xpw   = (const float*)d_in[28];
  const float* dtw   = (const float*)d_in[29];
  const float* dtb   = (const float*)d_in[30];
  const float* Alog  = (const float*)d_in[31];
  const float* Dp    = (const float*)d_in[32];
  const float* ong   = (const float*)d_in[33];
  const float* onb   = (const float*)d_in[34];
  const float* oww   = (const float*)d_in[35];

  float* ws = (float*)d_ws;
  // layout (floats):
  float* hlin   = ws + 0;         // 884736: hlin(k_pre->k_dw); ulb(k_combine->k_y); dtsum @+442368
  float* dtsum  = ws + 442368;    // 98304  (scanA->comb)
  float* x1pre  = ws + 884736;    // 884736: x1pre(k_dw->k_ssin); hinit_lo(comb->scanB); csum_p later
  float* x2     = ws + 1769472;   // 884736: x2(k_dw->k_gate); dtsG(k_xproj->k_pack); hinit_hi
  float* x2g    = ws + 2654208;   // 884736: (k_gate->k_combine)
  float* xibuf  = ws + 3538944;   // 1769472: xi(k_ssin->k_ssdw); hend(scanA->comb); Ybig(k_y->k_final)
  float* zbuf   = ws + 5308416;   // 1769472: (k_ssin->k_combine)
  float* xcbuf  = ws + 7077888;   // 1769472: (k_ssdw->k_xproj,k_pack,k_combine)
  float* packed = ws + 8847360;   // 14155776: (k_pack->scans); xT/outT alias at ends of pipeline
  float* bcbuf  = ws + 23003136;  // 1179648: (k_xproj->scans)
  float* ysum   = ws + 24182784;  // 1769472: (scanB atomics ->k_combine)
  float* wT     = ws + 25952256;  // 142656 weights -> total 26094912 floats (104.4 MB)

  float* dtsG    = x2;
  float* hend    = xibuf;
  float* hinitlo = x1pre;
  float* hinithi = x2;
  float* ulb     = hlin;
  float* Ybig    = xibuf;
  float* csum_p  = x1pre;
  float* wsmb    = x1pre + 27648;
  float* xT      = packed;
  float* outT    = packed;

  float* w1T   = wT + 0;
  float* linT  = wT + 9216;
  float* ag1T  = wT + 18432;
  float* ag2T  = wT + 23040;
  float* inT   = wT + 27648;
  float* owT   = wT + 64512;
  float* pwc1T = wT + 82944;
  float* pwc2T = wT + 85248;
  float* finT  = wT + 86976;
  float* sq1T  = wT + 96192;
  float* sq2T  = wT + 97344;
  float* gwcT  = wT + 98496;
  float* dtwT  = wT + 108864;
  float* xpwT  = wT + 113472;

  TArgs ta;
  const float* srcs[14] = {w1, linw, ag1w, ag2w, inw, oww, pwc1w, pwc2w, finw, sq1w, sq2w, gwcw, dtw, xpw};
  float* dsts[14]       = {w1T, linT, ag1T, ag2T, inT, owT, pwc1T, pwc2T, finT, sq1T, sq2T, gwcT, dtwT, xpwT};
  int rows[14] = {96, 96, 48, 96, 384, 96, 96, 72, 96, 24, 24, 96, 768, 152};
  int cols[14] = {96, 96, 96, 48, 96, 192, 24, 24, 96, 48, 48, 108, 6, 192};
  for (int i = 0; i < 14; ++i){ ta.s[i] = srcs[i]; ta.d[i] = dsts[i]; ta.rows[i] = rows[i]; ta.cols[i] = cols[i]; }

  k_tr<<<dim3(144, 14), 256, 0, stream>>>(ta);
  k_trx<<<dim3(72, 3, 4), 256, 0, stream>>>(x, xT);
  k_pre<<<Pp, CHn, 0, stream>>>(xT, w1T, b1, bng, bnb, linT, linb, hlin);
  k_dw<<<(Pp * CHn) / 256, 256, 0, stream>>>(hlin, dw1w, dw1b, dw2w, dw2b, x1pre, x2);
  k_gate<<<Pp, CHn, 0, stream>>>(x2, ag1T, ag1b, ag2T, ag2b, x2g);
  k_ssin<<<288 * 3, 256, 0, stream>>>(x1pre, inT, xibuf, zbuf);
  k_ssdw<<<(Pp * DIn) / 256, 256, 0, stream>>>(xibuf, scw, scb, xcbuf);
  k_xproj<<<576, 256, 0, stream>>>(xcbuf, xpwT, bcbuf, dtsG);
  k_pack<<<(36864 * DIn) / 256, 256, 0, stream>>>(dtsG, dtwT, dtb, xcbuf, packed);
  hipMemsetAsync(ysum, 0, (size_t)1769472 * 4, stream);
  k_scanA<<<192 * Sseg, 64, 0, stream>>>(packed, bcbuf, Alog, hend, dtsum);
  k_comb<<<192, 64, 0, stream>>>(Alog, hend, dtsum, hinitlo, hinithi);
  k_scanB<<<192 * Sseg, 64, 0, stream>>>(packed, bcbuf, Alog, hinitlo, hinithi, ysum);
  k_combine<<<Pp, DIn, 0, stream>>>(ysum, xcbuf, zbuf, Dp, ong, onb, owT, x2g, lng, lnb, sq1T, sq2T, ulb);
  k_y<<<Pp, 192, 0, stream>>>(ulb, gwcT, gwcb, pwc1T, pwc2T, Ybig);
  k_csum<<<144, 256, 0, stream>>>(Ybig, csum_p);
  k_softmax<<<4, 192, 0, stream>>>(csum_p, wsmb);
  k_final<<<Pp, CHn, 0, stream>>>(Ybig, wsmb, finT, finb, outT);
  k_tro<<<dim3(72, 3, 4), 256, 0, stream>>>(outT, (float*)d_out);
}

// Round 6
// 356.537 us; speedup vs baseline: 2.2926x; 1.0680x over previous
//
#include <hip/hip_runtime.h>
#include <hip/hip_bf16.h>

// Problem constants
#define Bn   4
#define CHn  96
#define Hh   48
#define Ww   48
#define Ll   2304      // H*W
#define Pp   9216      // B*L
#define DIn  192
#define Nn   16
#define Rr   6
#define Sseg   32      // scan segments per sequence
#define SEGL   72      // 2304 / 32
#define NCH     9      // 72 / 8 chunks
#define HSPLIT 884736  // hinit split boundary (floats)

__device__ inline float siluf(float x){ return x / (1.0f + __expf(-x)); }
__device__ inline float sigmf(float x){ return 1.0f / (1.0f + __expf(-x)); }

__device__ inline int pix_of(int k, int l){
  if (k == 0) return l;
  if (k == 1) return (l % 48) * 48 + l / 48;
  if (k == 2) return Ll - 1 - l;
  int lr = Ll - 1 - l; return (lr % 48) * 48 + lr / 48;
}
// row index l for direction k such that pix_of(k,l) == p
__device__ inline int l_of(int k, int p){
  if (k == 0) return p;
  if (k == 1) return (p % 48) * 48 + p / 48;
  if (k == 2) return Ll - 1 - p;
  return Ll - 1 - ((p % 48) * 48 + p / 48);
}

// split-region hinit accessor (boundary is a multiple of 256 -> float4 never straddles)
__device__ inline float4* hptr(float* lo, float* hi, size_t idx){
  return (float4*)(idx < HSPLIT ? lo + idx : hi + (idx - HSPLIT));
}

// ---------------- transpose-all-weights kernel (one launch) ----------------
struct TArgs {
  const float* s[14];
  float* d[14];
  int rows[14];
  int cols[14];
};
__global__ void k_tr(TArgs a){
  int id = blockIdx.y;
  int n = a.rows[id] * a.cols[id];
  int t = blockIdx.x * blockDim.x + threadIdx.x;
  if (t < n){
    int r = t / a.cols[id];
    int c = t - r * a.cols[id];
    a.d[id][c * a.rows[id] + r] = a.s[id][t];
  }
}

// ---------------- NCHW -> NHWC transpose of input x ----------------
__global__ void k_trx(const float* __restrict__ src, float* __restrict__ dst){
  __shared__ float tile[32][33];
  int pt = blockIdx.x, ct = blockIdx.y, b = blockIdx.z;
  int tx = threadIdx.x & 31, ty = threadIdx.x >> 5;
  #pragma unroll
  for (int i = 0; i < 4; ++i){
    int r = ty + i * 8;
    tile[r][tx] = src[((size_t)(b * CHn + ct * 32 + r)) * Ll + pt * 32 + tx];
  }
  __syncthreads();
  #pragma unroll
  for (int i = 0; i < 4; ++i){
    int r = ty + i * 8;
    dst[((size_t)(b * Ll + pt * 32 + r)) * CHn + ct * 32 + tx] = tile[tx][r];
  }
}

// ---------------- [p][c] -> NCHW transpose of output ----------------
__global__ void k_tro(const float* __restrict__ src, float* __restrict__ dst){
  __shared__ float tile[32][33];
  int pt = blockIdx.x, ct = blockIdx.y, b = blockIdx.z;
  int tx = threadIdx.x & 31, ty = threadIdx.x >> 5;
  #pragma unroll
  for (int i = 0; i < 4; ++i){
    int r = ty + i * 8;
    tile[r][tx] = src[((size_t)(b * Ll + pt * 32 + r)) * CHn + ct * 32 + tx];
  }
  __syncthreads();
  #pragma unroll
  for (int i = 0; i < 4; ++i){
    int r = ty + i * 8;
    dst[((size_t)(b * CHn + ct * 32 + r)) * Ll + pt * 32 + tx] = tile[tx][r];
  }
}

// ---------------- conv1x1 + BN + ReLU + channel linear ----------------
__global__ void k_pre(const float* __restrict__ xT, const float* __restrict__ w1T, const float* __restrict__ b1,
                      const float* __restrict__ bng, const float* __restrict__ bnb,
                      const float* __restrict__ linT, const float* __restrict__ lb,
                      float* __restrict__ hlin){
  int p = blockIdx.x;
  int c = threadIdx.x;
  __shared__ float xv[CHn];
  __shared__ float hv[CHn];
  xv[c] = xT[(size_t)p * CHn + c];
  __syncthreads();
  float acc = 0.f;
  for (int i = 0; i < CHn; ++i) acc = fmaf(w1T[i * CHn + c], xv[i], acc);
  float s = bng[c] * rsqrtf(1.0f + 1e-5f);
  float h = fmaxf((acc + b1[c]) * s + bnb[c], 0.f);
  hv[c] = h;
  __syncthreads();
  float a2 = lb[c];
  for (int i = 0; i < CHn; ++i) a2 = fmaf(linT[i * CHn + c], hv[i], a2);
  hlin[(size_t)p * CHn + c] = a2;
}

// ---------------- two depthwise 3x3 convs + SiLU ----------------
__global__ void k_dw(const float* __restrict__ hlin,
                     const float* __restrict__ dw1w, const float* __restrict__ dw1b,
                     const float* __restrict__ dw2w, const float* __restrict__ dw2b,
                     float* __restrict__ x1pre, float* __restrict__ x2){
  int t = blockIdx.x * 256 + threadIdx.x;
  if (t >= Pp * CHn) return;
  int c = t % CHn; int p = t / CHn; int b = p / Ll; int pp = p - b * Ll;
  int r = pp / Ww; int cx = pp - r * Ww;
  float a1 = dw1b[c], a2 = dw2b[c];
  for (int dy = -1; dy <= 1; ++dy){
    int ny = r + dy; if ((unsigned)ny >= Hh) continue;
    for (int dx = -1; dx <= 1; ++dx){
      int nx = cx + dx; if ((unsigned)nx >= Ww) continue;
      float v = hlin[(size_t)((b * Ll) + ny * Ww + nx) * CHn + c];
      int wi = c * 9 + (dy + 1) * 3 + (dx + 1);
      a1 = fmaf(dw1w[wi], v, a1);
      a2 = fmaf(dw2w[wi], v, a2);
    }
  }
  x1pre[t] = siluf(a1);
  x2[t]   = siluf(a2);
}

// ---------------- attention gate ----------------
__global__ void k_gate(const float* __restrict__ x2,
                       const float* __restrict__ ag1T, const float* __restrict__ ag1b,
                       const float* __restrict__ ag2T, const float* __restrict__ ag2b,
                       float* __restrict__ x2g){
  int p = blockIdx.x; int c = threadIdx.x;
  __shared__ float xv[CHn];
  __shared__ float rv[48];
  xv[c] = x2[(size_t)p * CHn + c];
  __syncthreads();
  if (c < 48){
    float a = ag1b[c];
    for (int i = 0; i < CHn; ++i) a = fmaf(ag1T[i * 48 + c], xv[i], a);
    rv[c] = fmaxf(a, 0.f);
  }
  __syncthreads();
  float a2 = ag2b[c];
  for (int tt = 0; tt < 48; ++tt) a2 = fmaf(ag2T[tt * CHn + c], rv[tt], a2);
  x2g[(size_t)p * CHn + c] = xv[c] * sigmf(a2);
}

// ---------------- SS2D input projection (GEMM-tiled, M-tile 16): 1728 blocks ----------------
__global__ __launch_bounds__(256) void k_ssin(const float* __restrict__ x1pre, const float* __restrict__ inT,
                                              float* __restrict__ xi, float* __restrict__ z){
  __shared__ float Xs[32][17];
  __shared__ float Wsh[32][128];
  int tid = threadIdx.x;
  int mt = blockIdx.x % 576; int nt = blockIdx.x / 576;
  int p0 = mt * 16, n0 = nt * 128;
  int tx = tid & 15, ty = tid >> 4;
  float acc[8];
  #pragma unroll
  for (int j = 0; j < 8; ++j) acc[j] = 0.f;
  for (int kc = 0; kc < 96; kc += 32){
    #pragma unroll
    for (int it = 0; it < 2; ++it){
      int e = it * 256 + tid; int dd = e & 31; int m = e >> 5;
      Xs[dd][m] = x1pre[(size_t)(p0 + m) * CHn + kc + dd];
    }
    #pragma unroll
    for (int it = 0; it < 16; ++it){
      int e = it * 256 + tid; int n = e & 127; int dd = e >> 7;
      Wsh[dd][n] = inT[(size_t)(kc + dd) * 384 + n0 + n];
    }
    __syncthreads();
    #pragma unroll
    for (int dd = 0; dd < 32; ++dd){
      float xv = Xs[dd][ty];
      #pragma unroll
      for (int j = 0; j < 8; ++j)
        acc[j] = fmaf(xv, Wsh[dd][tx + 16 * j], acc[j]);
    }
    __syncthreads();
  }
  int p = p0 + ty;
  #pragma unroll
  for (int j = 0; j < 8; ++j){
    int n = n0 + tx + 16 * j;
    float v = acc[j];
    if (n < 192) xi[(size_t)p * DIn + n] = v;
    else         z [(size_t)p * DIn + (n - 192)] = v;
  }
}

// ---------------- SS2D depthwise 3x3 + SiLU ----------------
__global__ void k_ssdw(const float* __restrict__ xi, const float* __restrict__ scw,
                       const float* __restrict__ scb, float* __restrict__ xc){
  int t = blockIdx.x * 256 + threadIdx.x;
  if (t >= Pp * DIn) return;
  int d = t % DIn; int p = t / DIn; int b = p / Ll; int pp = p - b * Ll;
  int r = pp / Ww; int cx = pp - r * Ww;
  float a = scb[d];
  for (int dy = -1; dy <= 1; ++dy){
    int ny = r + dy; if ((unsigned)ny >= Hh) continue;
    for (int dx = -1; dx <= 1; ++dx){
      int nx = cx + dx; if ((unsigned)nx >= Ww) continue;
      float v = xi[(size_t)((b * Ll) + ny * Ww + nx) * DIn + d];
      a = fmaf(scw[d * 9 + (dy + 1) * 3 + (dx + 1)], v, a);
    }
  }
  xc[t] = siluf(a);
}

// ---------------- xproj GEMM split-K: 576 M-tiles x 6 K-chunks -> partials ----------------
// part layout: [(mt*6+kc)][m(16)][152]
__global__ __launch_bounds__(256) void k_xproj(const float* __restrict__ xc,
    const float* __restrict__ xpwT, float* __restrict__ part){
  __shared__ float Xs[32][17];
  __shared__ float Wsh[32][160];
  int tid = threadIdx.x;
  int mt = blockIdx.x / 6; int kc = (blockIdx.x - mt * 6) * 32;
  int p0g = mt * 16;
  int tx = tid & 15, ty = tid >> 4;
  const float* xbase = xc + (size_t)p0g * DIn + kc;
  #pragma unroll
  for (int it = 0; it < 2; ++it){
    int e = it * 256 + tid; int dd = e & 31; int m = e >> 5;
    Xs[dd][m] = xbase[(size_t)m * DIn + dd];
  }
  #pragma unroll
  for (int it = 0; it < 20; ++it){
    int e = it * 256 + tid; int dd = e / 160; int n = e - dd * 160;
    Wsh[dd][n] = (n < 152) ? xpwT[(size_t)(kc + dd) * 152 + n] : 0.f;
  }
  __syncthreads();
  float acc[10];
  #pragma unroll
  for (int j = 0; j < 10; ++j) acc[j] = 0.f;
  #pragma unroll
  for (int dd = 0; dd < 32; ++dd){
    float xv = Xs[dd][ty];
    #pragma unroll
    for (int j = 0; j < 10; ++j)
      acc[j] = fmaf(xv, Wsh[dd][tx + 16 * j], acc[j]);
  }
  float* pb = part + ((size_t)blockIdx.x * 16 + ty) * 152;
  #pragma unroll
  for (int j = 0; j < 10; ++j){
    int n = tx + 16 * j;
    if (n < 152) pb[n] = acc[j];
  }
}

// ---------------- xred: sum 6 partials + scatter B/C + dt-rank ----------------
__global__ void k_xred(const float* __restrict__ part, float* __restrict__ bc,
                       float* __restrict__ dtsG){
  int t = blockIdx.x * 256 + threadIdx.x;
  if (t >= Pp * 152) return;
  int p = t / 152, n = t - p * 152;
  int mt = p >> 4, m = p & 15;
  const float* pb = part + ((size_t)(mt * 6) * 16 + m) * 152 + n;
  float s = 0.f;
  #pragma unroll
  for (int kc = 0; kc < 6; ++kc) s += pb[(size_t)kc * 16 * 152];
  int b = p / Ll; int pp = p - b * Ll;
  int k = n / 38, jj = n - k * 38;
  int l = l_of(k, pp);
  if (jj < 6) dtsG[((size_t)((b * 4 + k) * Ll + l)) * 6 + jj] = s;
  else        bc [((size_t)((b * 4 + k) * Ll + l)) * 32 + (jj - 6)] = s;
}

// ---------------- pack: delta softplus + u-gather -> packed[unit][l][dt16|du16] ----------------
__global__ void k_pack(const float* __restrict__ dtsG, const float* __restrict__ dtwT,
                       const float* __restrict__ dtb, const float* __restrict__ xc,
                       float* __restrict__ packed){
  int t = blockIdx.x * 256 + threadIdx.x;
  if (t >= 36864 * DIn) return;
  int d = t % DIn; int row = t / DIn;
  int bk = row / Ll; int l = row - bk * Ll;
  int k = bk & 3; int b = bk >> 2;
  const float* ds = dtsG + (size_t)row * 6;
  float a = dtb[k * DIn + d];
  #pragma unroll
  for (int r = 0; r < 6; ++r)
    a = fmaf(dtwT[r * 768 + k * DIn + d], ds[r], a);
  float dt = fmaxf(a, 0.f) + __logf(1.0f + __expf(-fabsf(a)));
  int pix = pix_of(k, l);
  float u = xc[((size_t)(b * Ll) + pix) * DIn + d];
  int unit = bk * 12 + (d >> 4);
  size_t base = ((size_t)unit * Ll + l) * 32 + (d & 15);
  packed[base]      = dt;
  packed[base + 16] = dt * u;
}

// ======================= segmented selective scan =======================
// unit = bk*12+g : 192 units; Sseg=32 segments of SEGL=72 steps.
// lane = ch*4 + ns : ch local channel [0,16), ns handles 4 of 16 states.

// ---- pass A: local scan per segment (h0=0), emit h_end + sum(dt) ----
__global__ __launch_bounds__(64) void k_scanA(const float* __restrict__ packed, const float* __restrict__ bc,
                                              const float* __restrict__ Alog,
                                              float* __restrict__ hend, float* __restrict__ dtsum){
  int blk = blockIdx.x; int unit = blk >> 5; int seg = blk & 31;
  int g = unit % 12; int bk = unit / 12; int k = bk & 3;
  int lane = threadIdx.x; int ch = lane >> 2; int ns = lane & 3; int nb = ns * 4;
  int d = g * 16 + ch;
  const int arow = (k * DIn + d) * 16 + nb;
  float A0 = -__expf(Alog[arow + 0]);
  float A1 = -__expf(Alog[arow + 1]);
  float A2 = -__expf(Alog[arow + 2]);
  float A3 = -__expf(Alog[arow + 3]);
  float h0 = 0.f, h1 = 0.f, h2 = 0.f, h3 = 0.f, dacc = 0.f;

  const int l0 = seg * SEGL;
  const float* pbase = packed + ((size_t)unit * Ll + l0) * 32;
  const float* bbase = bc + ((size_t)(bk * Ll) + l0) * 32;

  __shared__ float pl[256];
  __shared__ float blA[128];

  float4 pn = *(const float4*)(pbase + lane * 4);
  float4 bn;
  if (lane < 32) bn = *(const float4*)(bbase + (size_t)(lane >> 2) * 32 + (lane & 3) * 4);
  *(float4*)&pl[lane * 4] = pn;
  if (lane < 32) *(float4*)&blA[lane * 4] = bn;
  __syncthreads();

  for (int cc = 0; cc < NCH; ++cc){
    bool more = (cc + 1 < NCH);
    if (more){
      pn = *(const float4*)(pbase + (cc + 1) * 256 + lane * 4);
      if (lane < 32) bn = *(const float4*)(bbase + (size_t)((cc + 1) * 8 + (lane >> 2)) * 32 + (lane & 3) * 4);
    }
    #pragma unroll
    for (int lp = 0; lp < 8; ++lp){
      float dt = pl[lp * 32 + ch];
      float du = pl[lp * 32 + 16 + ch];
      float4 Bv = *(const float4*)&blA[lp * 16 + nb];
      dacc += dt;
      h0 = fmaf(h0, __expf(dt * A0), du * Bv.x);
      h1 = fmaf(h1, __expf(dt * A1), du * Bv.y);
      h2 = fmaf(h2, __expf(dt * A2), du * Bv.z);
      h3 = fmaf(h3, __expf(dt * A3), du * Bv.w);
    }
    __syncthreads();
    if (more){
      *(float4*)&pl[lane * 4] = pn;
      if (lane < 32) *(float4*)&blA[lane * 4] = bn;
    }
    __syncthreads();
  }
  size_t sb = (size_t)unit * Sseg + seg;
  *(float4*)&hend[sb * 256 + lane * 4] = make_float4(h0, h1, h2, h3);
  if (ns == 0) dtsum[sb * 16 + ch] = dacc;
}

// ---- combine: sequential fold over segments -> h_init per segment ----
__global__ __launch_bounds__(64) void k_comb(const float* __restrict__ Alog, const float* __restrict__ hend,
                                             const float* __restrict__ dtsum,
                                             float* __restrict__ hlo, float* __restrict__ hhi){
  int unit = blockIdx.x; int g = unit % 12; int bk = unit / 12; int k = bk & 3;
  int lane = threadIdx.x; int ch = lane >> 2; int ns = lane & 3; int nb = ns * 4;
  int d = g * 16 + ch;
  const int arow = (k * DIn + d) * 16 + nb;
  float A0 = -__expf(Alog[arow + 0]);
  float A1 = -__expf(Alog[arow + 1]);
  float A2 = -__expf(Alog[arow + 2]);
  float A3 = -__expf(Alog[arow + 3]);
  float h0 = 0.f, h1 = 0.f, h2 = 0.f, h3 = 0.f;
  for (int s = 0; s < Sseg; ++s){
    size_t sb = (size_t)unit * Sseg + s;
    *hptr(hlo, hhi, sb * 256 + lane * 4) = make_float4(h0, h1, h2, h3);
    float dsv = dtsum[sb * 16 + ch];
    float4 he = *(const float4*)&hend[sb * 256 + lane * 4];
    h0 = fmaf(h0, __expf(A0 * dsv), he.x);
    h1 = fmaf(h1, __expf(A1 * dsv), he.y);
    h2 = fmaf(h2, __expf(A2 * dsv), he.z);
    h3 = fmaf(h3, __expf(A3 * dsv), he.w);
  }
}

// ---- pass B: rescan from h_init, atomically accumulate y into ysum[b][pix][d] ----
__global__ __launch_bounds__(64) void k_scanB(const float* __restrict__ packed, const float* __restrict__ bc,
                                              const float* __restrict__ Alog,
                                              float* __restrict__ hlo, float* __restrict__ hhi,
                                              float* __restrict__ ysum){
  int blk = blockIdx.x; int unit = blk >> 5; int seg = blk & 31;
  int g = unit % 12; int bk = unit / 12; int k = bk & 3; int b = bk >> 2;
  int lane = threadIdx.x; int ch = lane >> 2; int ns = lane & 3; int nb = ns * 4;
  int d = g * 16 + ch;
  const int arow = (k * DIn + d) * 16 + nb;
  float A0 = -__expf(Alog[arow + 0]);
  float A1 = -__expf(Alog[arow + 1]);
  float A2 = -__expf(Alog[arow + 2]);
  float A3 = -__expf(Alog[arow + 3]);
  size_t sb = (size_t)unit * Sseg + seg;
  float4 hi = *hptr(hlo, hhi, sb * 256 + lane * 4);
  float h0 = hi.x, h1 = hi.y, h2 = hi.z, h3 = hi.w;

  const int l0 = seg * SEGL;
  const float* pbase = packed + ((size_t)unit * Ll + l0) * 32;
  const float* bbase = bc + ((size_t)(bk * Ll) + l0) * 32;
  float* ybase = ysum + (size_t)(b * Ll) * DIn + d;

  __shared__ float pl[256];
  __shared__ float bl[256];

  float4 pn = *(const float4*)(pbase + lane * 4);
  float4 bn = *(const float4*)(bbase + lane * 4);
  *(float4*)&pl[lane * 4] = pn;
  *(float4*)&bl[lane * 4] = bn;
  __syncthreads();

  for (int cc = 0; cc < NCH; ++cc){
    bool more = (cc + 1 < NCH);
    if (more){
      pn = *(const float4*)(pbase + (cc + 1) * 256 + lane * 4);
      bn = *(const float4*)(bbase + (cc + 1) * 256 + lane * 4);
    }
    #pragma unroll
    for (int lp = 0; lp < 8; ++lp){
      float dt = pl[lp * 32 + ch];
      float du = pl[lp * 32 + 16 + ch];
      float4 Bv = *(const float4*)&bl[lp * 32 + nb];
      float4 Cv = *(const float4*)&bl[lp * 32 + 16 + nb];
      h0 = fmaf(h0, __expf(dt * A0), du * Bv.x);
      h1 = fmaf(h1, __expf(dt * A1), du * Bv.y);
      h2 = fmaf(h2, __expf(dt * A2), du * Bv.z);
      h3 = fmaf(h3, __expf(dt * A3), du * Bv.w);
      float yp = fmaf(h0, Cv.x, fmaf(h1, Cv.y, fmaf(h2, Cv.z, h3 * Cv.w)));
      yp += __shfl_xor(yp, 1);
      yp += __shfl_xor(yp, 2);
      if (ns == 0){
        int l = l0 + cc * 8 + lp;
        int pix = pix_of(k, l);
        atomicAdd(ybase + (size_t)pix * DIn, yp);
      }
    }
    __syncthreads();
    if (more){
      *(float4*)&pl[lane * 4] = pn;
      *(float4*)&bl[lane * 4] = bn;
    }
    __syncthreads();
  }
}

// ---------------- block reductions ----------------
__device__ inline float block_sum_192(float* red, int d, float v){
  red[d] = v; __syncthreads();
  if (d < 96) red[d] += red[d + 96]; __syncthreads();
  if (d < 48) red[d] += red[d + 48]; __syncthreads();
  if (d < 24) red[d] += red[d + 24]; __syncthreads();
  if (d < 12) red[d] += red[d + 12]; __syncthreads();
  if (d < 6)  red[d] += red[d + 6];  __syncthreads();
  float tot = red[0] + red[1] + red[2] + red[3] + red[4] + red[5];
  __syncthreads();
  return tot;
}
__device__ inline float block_sum_96(float* red, int d, float v){
  if (d < 96) red[d] = v; __syncthreads();
  if (d < 48) red[d] += red[d + 48]; __syncthreads();
  if (d < 24) red[d] += red[d + 24]; __syncthreads();
  if (d < 12) red[d] += red[d + 12]; __syncthreads();
  if (d < 6)  red[d] += red[d + 6];  __syncthreads();
  float tot = red[0] + red[1] + red[2] + red[3] + red[4] + red[5];
  __syncthreads();
  return tot;
}

// ---- combine: ysum + D·u + LN(192) + z-gate + out-proj + add + LN(96) + squeeze ----
__global__ void k_combine(const float* __restrict__ ysum, const float* __restrict__ xc,
                          const float* __restrict__ z, const float* __restrict__ Dp,
                          const float* __restrict__ ong, const float* __restrict__ onb,
                          const float* __restrict__ owT, const float* __restrict__ x2g,
                          const float* __restrict__ lng, const float* __restrict__ lnb,
                          const float* __restrict__ sq1T, const float* __restrict__ sq2T,
                          float* __restrict__ ul){
  int p = blockIdx.x;
  int d = threadIdx.x;
  __shared__ float red[192];
  __shared__ float ygv[192];
  __shared__ float crs[96];
  float yv = ysum[(size_t)p * DIn + d];
  float u = xc[(size_t)p * DIn + d];
  float Ds = Dp[d] + Dp[192 + d] + Dp[384 + d] + Dp[576 + d];
  yv = fmaf(u, Ds, yv);
  float mu = block_sum_192(red, d, yv) * (1.f / 192.f);
  float dv = yv - mu;
  float var = block_sum_192(red, d, dv * dv) * (1.f / 192.f);
  float yn = dv * rsqrtf(var + 1e-5f) * ong[d] + onb[d];
  float zv = z[(size_t)p * DIn + d];
  ygv[d] = yn * (zv * sigmf(zv));
  __syncthreads();
  float sval = 0.f;
  if (d < 96){
    float acc = 0.f;
    for (int dd = 0; dd < 192; ++dd) acc = fmaf(owT[dd * 96 + d], ygv[dd], acc);
    sval = acc + x2g[(size_t)p * CHn + d];
  }
  float mu2 = block_sum_96(red, d, sval) * (1.f / 96.f);
  float dv2 = sval - mu2;
  float var2 = block_sum_96(red, d, (d < 96) ? dv2 * dv2 : 0.f) * (1.f / 96.f);
  if (d < 96) crs[d] = dv2 * rsqrtf(var2 + 1e-5f) * lng[d] + lnb[d];
  __syncthreads();
  if (d < 48){
    float a = 0.f;
    if (d < 24){
      for (int i = 0; i < 48; ++i) a = fmaf(sq1T[i * 24 + d], crs[i], a);
    } else {
      int o = d - 24;
      for (int i = 0; i < 48; ++i) a = fmaf(sq2T[i * 24 + o], crs[48 + i], a);
    }
    ul[(size_t)p * 48 + d] = a;
  }
}

// ---------------- CRM main ----------------
__global__ void k_y(const float* __restrict__ ul, const float* __restrict__ gwcT,
                    const float* __restrict__ gwcb, const float* __restrict__ pwc1T,
                    const float* __restrict__ pwc2T, float* __restrict__ Ybig){
  int p = blockIdx.x; int b = p / Ll; int pp = p - b * Ll;
  int r = pp / Ww; int cx = pp - r * Ww;
  int oc = threadIdx.x;
  __shared__ float ulv[48];
  if (oc < 48) ulv[oc] = ul[(size_t)p * 48 + oc];
  __syncthreads();
  float acc;
  if (oc < 96){
    acc = gwcb[oc];
    int grp = oc / 48;
    for (int dy = -1; dy <= 1; ++dy){
      int ny = r + dy; if ((unsigned)ny >= Hh) continue;
      for (int dx = -1; dx <= 1; ++dx){
        int nx = cx + dx; if ((unsigned)nx >= Ww) continue;
        const float* un = ul + (size_t)((b * Ll) + ny * Ww + nx) * 48 + grp * 12;
        int k9 = (dy + 1) * 3 + (dx + 1);
        #pragma unroll
        for (int i = 0; i < 12; ++i) acc = fmaf(gwcT[(i * 9 + k9) * 96 + oc], un[i], acc);
      }
    }
    for (int i = 0; i < 24; ++i) acc = fmaf(pwc1T[i * 96 + oc], ulv[i], acc);
  } else if (oc < 168){
    int o2 = oc - 96; acc = 0.f;
    for (int i = 0; i < 24; ++i) acc = fmaf(pwc2T[i * 72 + o2], ulv[24 + i], acc);
  } else {
    acc = ulv[24 + oc - 168];
  }
  Ybig[(size_t)p * 192 + oc] = acc;
}

// ---------------- coalesced partial spatial sums ----------------
__global__ void k_csum(const float* __restrict__ Ybig, float* __restrict__ csum_p){
  int b = blockIdx.x / 36; int ch = blockIdx.x - b * 36;
  int t = threadIdx.x;
  if (t >= 192) return;
  float acc = 0.f;
  const float* base = Ybig + (size_t)(b * Ll + ch * 64) * 192 + t;
  #pragma unroll 4
  for (int i = 0; i < 64; ++i) acc += base[(size_t)i * 192];
  csum_p[(size_t)blockIdx.x * 192 + t] = acc;
}

// ---------------- softmax over 192 channel means ----------------
__global__ void k_softmax(const float* __restrict__ csum_p, float* __restrict__ wsm){
  int b = blockIdx.x; int t = threadIdx.x;
  __shared__ float red[192];
  float m = 0.f;
  for (int cc = 0; cc < 36; ++cc) m += csum_p[(size_t)(b * 36 + cc) * 192 + t];
  m *= (1.f / 2304.f);
  red[t] = m; __syncthreads();
  if (t < 96) red[t] = fmaxf(red[t], red[t + 96]); __syncthreads();
  if (t < 48) red[t] = fmaxf(red[t], red[t + 48]); __syncthreads();
  if (t < 24) red[t] = fmaxf(red[t], red[t + 24]); __syncthreads();
  if (t < 12) red[t] = fmaxf(red[t], red[t + 12]); __syncthreads();
  if (t < 6)  red[t] = fmaxf(red[t], red[t + 6]);  __syncthreads();
  float mx = fmaxf(fmaxf(fmaxf(red[0], red[1]), fmaxf(red[2], red[3])), fmaxf(red[4], red[5]));
  __syncthreads();
  float e = __expf(m - mx);
  float s = block_sum_192(red, t, e);
  wsm[b * 192 + t] = e / s;
}

// ---------------- weighted halves + final linear -> [p][c] ----------------
__global__ void k_final(const float* __restrict__ Ybig, const float* __restrict__ wsm,
                        const float* __restrict__ finT, const float* __restrict__ finb,
                        float* __restrict__ outT){
  int p = blockIdx.x; int b = p / Ll;
  int c = threadIdx.x;
  __shared__ float ov[96];
  float o = wsm[b * 192 + c]      * Ybig[(size_t)p * 192 + c]
          + wsm[b * 192 + 96 + c] * Ybig[(size_t)p * 192 + 96 + c];
  ov[c] = o; __syncthreads();
  float acc = finb[c];
  for (int i = 0; i < 96; ++i) acc = fmaf(finT[i * 96 + c], ov[i], acc);
  outT[(size_t)p * CHn + c] = acc;
}

// ---------------- host launch ----------------
extern "C" void kernel_launch(void* const* d_in, const int* in_sizes, int n_in,
                              void* d_out, int out_size, void* d_ws, size_t ws_size,
                              hipStream_t stream) {
  const float* x     = (const float*)d_in[0];
  const float* w1    = (const float*)d_in[1];
  const float* b1    = (const float*)d_in[2];
  const float* bng   = (const float*)d_in[3];
  const float* bnb   = (const float*)d_in[4];
  const float* linw  = (const float*)d_in[5];
  const float* linb  = (const float*)d_in[6];
  const float* dw1w  = (const float*)d_in[7];
  const float* dw1b  = (const float*)d_in[8];
  const float* dw2w  = (const float*)d_in[9];
  const float* dw2b  = (const float*)d_in[10];
  const float* ag1w  = (const float*)d_in[11];
  const float* ag1b  = (const float*)d_in[12];
  const float* ag2w  = (const float*)d_in[13];
  const float* ag2b  = (const float*)d_in[14];
  const float* lng   = (const float*)d_in[15];
  const float* lnb   = (const float*)d_in[16];
  const float* sq1w  = (const float*)d_in[17];
  const float* sq2w  = (const float*)d_in[18];
  const float* gwcw  = (const float*)d_in[19];
  const float* gwcb  = (const float*)d_in[20];
  const float* pwc1w = (const float*)d_in[21];
  const float* pwc2w = (const float*)d_in[22];
  const float* finw  = (const float*)d_in[23];
  const float* finb  = (const float*)d_in[24];
  const float* inw   = (const float*)d_in[25];
  const float* scw   = (const float*)d_in[26];
  const float* scb   = (const float*)d_in[27];
  const float* xpw   = (const float*)d_in[28];
  const float* dtw   = (const float*)d_in[29];
  const float* dtb   = (const float*)d_in[30];
  const float* Alog  = (const float*)d_in[31];
  const float* Dp    = (const float*)d_in[32];
  const float* ong   = (const float*)d_in[33];
  const float* onb   = (const float*)d_in[34];
  const float* oww   = (const float*)d_in[35];

  float* ws = (float*)d_ws;
  // layout (floats):
  float* hlin   = ws + 0;         // 884736: hlin(k_pre->k_dw); ulb(k_combine->k_y); dtsum @+442368
  float* dtsum  = ws + 442368;    // 98304  (scanA->comb)
  float* x1pre  = ws + 884736;    // 884736: x1pre(k_dw->k_ssin); hinit_lo(comb->scanB); csum_p later
  float* x2     = ws + 1769472;   // 884736: x2(k_dw->k_gate); dtsG(k_xred->k_pack); hinit_hi
  float* x2g    = ws + 2654208;   // 884736: (k_gate->k_combine)
  float* xibuf  = ws + 3538944;   // 1769472: xi(k_ssin->k_ssdw); hend(scanA->comb); Ybig(k_y->k_final)
  float* zbuf   = ws + 5308416;   // 1769472: (k_ssin->k_combine)
  float* xcbuf  = ws + 7077888;   // 1769472: (k_ssdw->k_xproj,k_pack,k_combine)
  float* packed = ws + 8847360;   // 14155776: part(k_xproj->k_xred) then packed(k_pack->scans); xT/outT alias
  float* bcbuf  = ws + 23003136;  // 1179648: (k_xred->scans)
  float* ysum   = ws + 24182784;  // 1769472: (scanB atomics ->k_combine)
  float* wT     = ws + 25952256;  // 142656 weights -> total 26094912 floats (104.4 MB)

  float* dtsG    = x2;
  float* hend    = xibuf;
  float* hinitlo = x1pre;
  float* hinithi = x2;
  float* ulb     = hlin;
  float* Ybig    = xibuf;
  float* csum_p  = x1pre;
  float* wsmb    = x1pre + 27648;
  float* xT      = packed;
  float* part    = packed;        // 8404992 floats used (k_xproj->k_xred)
  float* outT    = packed;

  float* w1T   = wT + 0;
  float* linT  = wT + 9216;
  float* ag1T  = wT + 18432;
  float* ag2T  = wT + 23040;
  float* inT   = wT + 27648;
  float* owT   = wT + 64512;
  float* pwc1T = wT + 82944;
  float* pwc2T = wT + 85248;
  float* finT  = wT + 86976;
  float* sq1T  = wT + 96192;
  float* sq2T  = wT + 97344;
  float* gwcT  = wT + 98496;
  float* dtwT  = wT + 108864;
  float* xpwT  = wT + 113472;

  TArgs ta;
  const float* srcs[14] = {w1, linw, ag1w, ag2w, inw, oww, pwc1w, pwc2w, finw, sq1w, sq2w, gwcw, dtw, xpw};
  float* dsts[14]       = {w1T, linT, ag1T, ag2T, inT, owT, pwc1T, pwc2T, finT, sq1T, sq2T, gwcT, dtwT, xpwT};
  int rows[14] = {96, 96, 48, 96, 384, 96, 96, 72, 96, 24, 24, 96, 768, 152};
  int cols[14] = {96, 96, 96, 48, 96, 192, 24, 24, 96, 48, 48, 108, 6, 192};
  for (int i = 0; i < 14; ++i){ ta.s[i] = srcs[i]; ta.d[i] = dsts[i]; ta.rows[i] = rows[i]; ta.cols[i] = cols[i]; }

  k_tr<<<dim3(144, 14), 256, 0, stream>>>(ta);
  k_trx<<<dim3(72, 3, 4), 256, 0, stream>>>(x, xT);
  k_pre<<<Pp, CHn, 0, stream>>>(xT, w1T, b1, bng, bnb, linT, linb, hlin);
  k_dw<<<(Pp * CHn) / 256, 256, 0, stream>>>(hlin, dw1w, dw1b, dw2w, dw2b, x1pre, x2);
  k_gate<<<Pp, CHn, 0, stream>>>(x2, ag1T, ag1b, ag2T, ag2b, x2g);
  k_ssin<<<576 * 3, 256, 0, stream>>>(x1pre, inT, xibuf, zbuf);
  k_ssdw<<<(Pp * DIn) / 256, 256, 0, stream>>>(xibuf, scw, scb, xcbuf);
  k_xproj<<<576 * 6, 256, 0, stream>>>(xcbuf, xpwT, part);
  k_xred<<<(Pp * 152 + 255) / 256, 256, 0, stream>>>(part, bcbuf, dtsG);
  k_pack<<<(36864 * DIn) / 256, 256, 0, stream>>>(dtsG, dtwT, dtb, xcbuf, packed);
  hipMemsetAsync(ysum, 0, (size_t)1769472 * 4, stream);
  k_scanA<<<192 * Sseg, 64, 0, stream>>>(packed, bcbuf, Alog, hend, dtsum);
  k_comb<<<192, 64, 0, stream>>>(Alog, hend, dtsum, hinitlo, hinithi);
  k_scanB<<<192 * Sseg, 64, 0, stream>>>(packed, bcbuf, Alog, hinitlo, hinithi, ysum);
  k_combine<<<Pp, DIn, 0, stream>>>(ysum, xcbuf, zbuf, Dp, ong, onb, owT, x2g, lng, lnb, sq1T, sq2T, ulb);
  k_y<<<Pp, 192, 0, stream>>>(ulb, gwcT, gwcb, pwc1T, pwc2T, Ybig);
  k_csum<<<144, 256, 0, stream>>>(Ybig, csum_p);
  k_softmax<<<4, 192, 0, stream>>>(csum_p, wsmb);
  k_final<<<Pp, CHn, 0, stream>>>(Ybig, wsmb, finT, finb, outT);
  k_tro<<<dim3(72, 3, 4), 256, 0, stream>>>(outT, (float*)d_out);
}

// Round 7
// 349.922 us; speedup vs baseline: 2.3360x; 1.0189x over previous
//
#include <hip/hip_runtime.h>
#include <hip/hip_bf16.h>

// Problem constants
#define Bn   4
#define CHn  96
#define Hh   48
#define Ww   48
#define Ll   2304      // H*W
#define Pp   9216      // B*L
#define DIn  192
#define Nn   16
#define Rr   6
#define Sseg   32      // scan segments per sequence
#define SEGL   72      // 2304 / 32
#define NCH     9      // 72 / 8 chunks
#define HSPLIT 884736  // hinit split boundary (floats)

__device__ inline float siluf(float x){ return x / (1.0f + __expf(-x)); }
__device__ inline float sigmf(float x){ return 1.0f / (1.0f + __expf(-x)); }

__device__ inline int pix_of(int k, int l){
  if (k == 0) return l;
  if (k == 1) return (l % 48) * 48 + l / 48;
  if (k == 2) return Ll - 1 - l;
  int lr = Ll - 1 - l; return (lr % 48) * 48 + lr / 48;
}
// row index l for direction k such that pix_of(k,l) == p
__device__ inline int l_of(int k, int p){
  if (k == 0) return p;
  if (k == 1) return (p % 48) * 48 + p / 48;
  if (k == 2) return Ll - 1 - p;
  return Ll - 1 - ((p % 48) * 48 + p / 48);
}

// split-region hinit accessor (boundary is a multiple of 256 -> float4 never straddles)
__device__ inline float4* hptr(float* lo, float* hi, size_t idx){
  return (float4*)(idx < HSPLIT ? lo + idx : hi + (idx - HSPLIT));
}

// ---------------- transpose-all-weights kernel (one launch) ----------------
struct TArgs {
  const float* s[14];
  float* d[14];
  int rows[14];
  int cols[14];
};
__global__ void k_tr(TArgs a){
  int id = blockIdx.y;
  int n = a.rows[id] * a.cols[id];
  int t = blockIdx.x * blockDim.x + threadIdx.x;
  if (t < n){
    int r = t / a.cols[id];
    int c = t - r * a.cols[id];
    a.d[id][c * a.rows[id] + r] = a.s[id][t];
  }
}

// ---------------- NCHW -> NHWC transpose of input x ----------------
__global__ void k_trx(const float* __restrict__ src, float* __restrict__ dst){
  __shared__ float tile[32][33];
  int pt = blockIdx.x, ct = blockIdx.y, b = blockIdx.z;
  int tx = threadIdx.x & 31, ty = threadIdx.x >> 5;
  #pragma unroll
  for (int i = 0; i < 4; ++i){
    int r = ty + i * 8;
    tile[r][tx] = src[((size_t)(b * CHn + ct * 32 + r)) * Ll + pt * 32 + tx];
  }
  __syncthreads();
  #pragma unroll
  for (int i = 0; i < 4; ++i){
    int r = ty + i * 8;
    dst[((size_t)(b * Ll + pt * 32 + r)) * CHn + ct * 32 + tx] = tile[tx][r];
  }
}

// ---------------- [p][c] -> NCHW transpose of output ----------------
__global__ void k_tro(const float* __restrict__ src, float* __restrict__ dst){
  __shared__ float tile[32][33];
  int pt = blockIdx.x, ct = blockIdx.y, b = blockIdx.z;
  int tx = threadIdx.x & 31, ty = threadIdx.x >> 5;
  #pragma unroll
  for (int i = 0; i < 4; ++i){
    int r = ty + i * 8;
    tile[r][tx] = src[((size_t)(b * Ll + pt * 32 + r)) * CHn + ct * 32 + tx];
  }
  __syncthreads();
  #pragma unroll
  for (int i = 0; i < 4; ++i){
    int r = ty + i * 8;
    dst[((size_t)(b * CHn + ct * 32 + r)) * Ll + pt * 32 + tx] = tile[tx][r];
  }
}

// ---------------- conv1x1 + BN + ReLU + channel linear ----------------
__global__ void k_pre(const float* __restrict__ xT, const float* __restrict__ w1T, const float* __restrict__ b1,
                      const float* __restrict__ bng, const float* __restrict__ bnb,
                      const float* __restrict__ linT, const float* __restrict__ lb,
                      float* __restrict__ hlin){
  int p = blockIdx.x;
  int c = threadIdx.x;
  __shared__ float xv[CHn];
  __shared__ float hv[CHn];
  xv[c] = xT[(size_t)p * CHn + c];
  __syncthreads();
  float acc = 0.f;
  for (int i = 0; i < CHn; ++i) acc = fmaf(w1T[i * CHn + c], xv[i], acc);
  float s = bng[c] * rsqrtf(1.0f + 1e-5f);
  float h = fmaxf((acc + b1[c]) * s + bnb[c], 0.f);
  hv[c] = h;
  __syncthreads();
  float a2 = lb[c];
  for (int i = 0; i < CHn; ++i) a2 = fmaf(linT[i * CHn + c], hv[i], a2);
  hlin[(size_t)p * CHn + c] = a2;
}

// ---------------- two depthwise 3x3 convs + SiLU ----------------
__global__ void k_dw(const float* __restrict__ hlin,
                     const float* __restrict__ dw1w, const float* __restrict__ dw1b,
                     const float* __restrict__ dw2w, const float* __restrict__ dw2b,
                     float* __restrict__ x1pre, float* __restrict__ x2){
  int t = blockIdx.x * 256 + threadIdx.x;
  if (t >= Pp * CHn) return;
  int c = t % CHn; int p = t / CHn; int b = p / Ll; int pp = p - b * Ll;
  int r = pp / Ww; int cx = pp - r * Ww;
  float a1 = dw1b[c], a2 = dw2b[c];
  for (int dy = -1; dy <= 1; ++dy){
    int ny = r + dy; if ((unsigned)ny >= Hh) continue;
    for (int dx = -1; dx <= 1; ++dx){
      int nx = cx + dx; if ((unsigned)nx >= Ww) continue;
      float v = hlin[(size_t)((b * Ll) + ny * Ww + nx) * CHn + c];
      int wi = c * 9 + (dy + 1) * 3 + (dx + 1);
      a1 = fmaf(dw1w[wi], v, a1);
      a2 = fmaf(dw2w[wi], v, a2);
    }
  }
  x1pre[t] = siluf(a1);
  x2[t]   = siluf(a2);
}

// ---------------- attention gate ----------------
__global__ void k_gate(const float* __restrict__ x2,
                       const float* __restrict__ ag1T, const float* __restrict__ ag1b,
                       const float* __restrict__ ag2T, const float* __restrict__ ag2b,
                       float* __restrict__ x2g){
  int p = blockIdx.x; int c = threadIdx.x;
  __shared__ float xv[CHn];
  __shared__ float rv[48];
  xv[c] = x2[(size_t)p * CHn + c];
  __syncthreads();
  if (c < 48){
    float a = ag1b[c];
    for (int i = 0; i < CHn; ++i) a = fmaf(ag1T[i * 48 + c], xv[i], a);
    rv[c] = fmaxf(a, 0.f);
  }
  __syncthreads();
  float a2 = ag2b[c];
  for (int tt = 0; tt < 48; ++tt) a2 = fmaf(ag2T[tt * CHn + c], rv[tt], a2);
  x2g[(size_t)p * CHn + c] = xv[c] * sigmf(a2);
}

// ---------------- SS2D input projection (GEMM-tiled, M-tile 16): 1728 blocks ----------------
__global__ __launch_bounds__(256) void k_ssin(const float* __restrict__ x1pre, const float* __restrict__ inT,
                                              float* __restrict__ xi, float* __restrict__ z){
  __shared__ float Xs[32][17];
  __shared__ float Wsh[32][128];
  int tid = threadIdx.x;
  int mt = blockIdx.x % 576; int nt = blockIdx.x / 576;
  int p0 = mt * 16, n0 = nt * 128;
  int tx = tid & 15, ty = tid >> 4;
  float acc[8];
  #pragma unroll
  for (int j = 0; j < 8; ++j) acc[j] = 0.f;
  for (int kc = 0; kc < 96; kc += 32){
    #pragma unroll
    for (int it = 0; it < 2; ++it){
      int e = it * 256 + tid; int dd = e & 31; int m = e >> 5;
      Xs[dd][m] = x1pre[(size_t)(p0 + m) * CHn + kc + dd];
    }
    #pragma unroll
    for (int it = 0; it < 16; ++it){
      int e = it * 256 + tid; int n = e & 127; int dd = e >> 7;
      Wsh[dd][n] = inT[(size_t)(kc + dd) * 384 + n0 + n];
    }
    __syncthreads();
    #pragma unroll
    for (int dd = 0; dd < 32; ++dd){
      float xv = Xs[dd][ty];
      #pragma unroll
      for (int j = 0; j < 8; ++j)
        acc[j] = fmaf(xv, Wsh[dd][tx + 16 * j], acc[j]);
    }
    __syncthreads();
  }
  int p = p0 + ty;
  #pragma unroll
  for (int j = 0; j < 8; ++j){
    int n = n0 + tx + 16 * j;
    float v = acc[j];
    if (n < 192) xi[(size_t)p * DIn + n] = v;
    else         z [(size_t)p * DIn + (n - 192)] = v;
  }
}

// ---------------- SS2D depthwise 3x3 + SiLU ----------------
__global__ void k_ssdw(const float* __restrict__ xi, const float* __restrict__ scw,
                       const float* __restrict__ scb, float* __restrict__ xc){
  int t = blockIdx.x * 256 + threadIdx.x;
  if (t >= Pp * DIn) return;
  int d = t % DIn; int p = t / DIn; int b = p / Ll; int pp = p - b * Ll;
  int r = pp / Ww; int cx = pp - r * Ww;
  float a = scb[d];
  for (int dy = -1; dy <= 1; ++dy){
    int ny = r + dy; if ((unsigned)ny >= Hh) continue;
    for (int dx = -1; dx <= 1; ++dx){
      int nx = cx + dx; if ((unsigned)nx >= Ww) continue;
      float v = xi[(size_t)((b * Ll) + ny * Ww + nx) * DIn + d];
      a = fmaf(scw[d * 9 + (dy + 1) * 3 + (dx + 1)], v, a);
    }
  }
  xc[t] = siluf(a);
}

// ---------------- xproj GEMM split-K: 576 M-tiles x 6 K-chunks -> partials ----------------
// part layout: [(mt*6+kc)][m(16)][152]
__global__ __launch_bounds__(256) void k_xproj(const float* __restrict__ xc,
    const float* __restrict__ xpwT, float* __restrict__ part){
  __shared__ float Xs[32][17];
  __shared__ float Wsh[32][160];
  int tid = threadIdx.x;
  int mt = blockIdx.x / 6; int kc = (blockIdx.x - mt * 6) * 32;
  int p0g = mt * 16;
  int tx = tid & 15, ty = tid >> 4;
  const float* xbase = xc + (size_t)p0g * DIn + kc;
  #pragma unroll
  for (int it = 0; it < 2; ++it){
    int e = it * 256 + tid; int dd = e & 31; int m = e >> 5;
    Xs[dd][m] = xbase[(size_t)m * DIn + dd];
  }
  #pragma unroll
  for (int it = 0; it < 20; ++it){
    int e = it * 256 + tid; int dd = e / 160; int n = e - dd * 160;
    Wsh[dd][n] = (n < 152) ? xpwT[(size_t)(kc + dd) * 152 + n] : 0.f;
  }
  __syncthreads();
  float acc[10];
  #pragma unroll
  for (int j = 0; j < 10; ++j) acc[j] = 0.f;
  #pragma unroll
  for (int dd = 0; dd < 32; ++dd){
    float xv = Xs[dd][ty];
    #pragma unroll
    for (int j = 0; j < 10; ++j)
      acc[j] = fmaf(xv, Wsh[dd][tx + 16 * j], acc[j]);
  }
  float* pb = part + ((size_t)blockIdx.x * 16 + ty) * 152;
  #pragma unroll
  for (int j = 0; j < 10; ++j){
    int n = tx + 16 * j;
    if (n < 152) pb[n] = acc[j];
  }
}

// ---------------- xred: sum 6 partials + scatter B/C + dt-rank ----------------
__global__ void k_xred(const float* __restrict__ part, float* __restrict__ bc,
                       float* __restrict__ dtsG){
  int t = blockIdx.x * 256 + threadIdx.x;
  if (t >= Pp * 152) return;
  int p = t / 152, n = t - p * 152;
  int mt = p >> 4, m = p & 15;
  const float* pb = part + ((size_t)(mt * 6) * 16 + m) * 152 + n;
  float s = 0.f;
  #pragma unroll
  for (int kc = 0; kc < 6; ++kc) s += pb[(size_t)kc * 16 * 152];
  int b = p / Ll; int pp = p - b * Ll;
  int k = n / 38, jj = n - k * 38;
  int l = l_of(k, pp);
  if (jj < 6) dtsG[((size_t)((b * 4 + k) * Ll + l)) * 6 + jj] = s;
  else        bc [((size_t)((b * 4 + k) * Ll + l)) * 32 + (jj - 6)] = s;
}

// ---------------- pack: delta softplus + u-gather -> packed[unit][l][dt16|du16] ----------------
__global__ void k_pack(const float* __restrict__ dtsG, const float* __restrict__ dtwT,
                       const float* __restrict__ dtb, const float* __restrict__ xc,
                       float* __restrict__ packed){
  int t = blockIdx.x * 256 + threadIdx.x;
  if (t >= 36864 * DIn) return;
  int d = t % DIn; int row = t / DIn;
  int bk = row / Ll; int l = row - bk * Ll;
  int k = bk & 3; int b = bk >> 2;
  const float* ds = dtsG + (size_t)row * 6;
  float a = dtb[k * DIn + d];
  #pragma unroll
  for (int r = 0; r < 6; ++r)
    a = fmaf(dtwT[r * 768 + k * DIn + d], ds[r], a);
  float dt = fmaxf(a, 0.f) + __logf(1.0f + __expf(-fabsf(a)));
  int pix = pix_of(k, l);
  float u = xc[((size_t)(b * Ll) + pix) * DIn + d];
  int unit = bk * 12 + (d >> 4);
  size_t base = ((size_t)unit * Ll + l) * 32 + (d & 15);
  packed[base]      = dt;
  packed[base + 16] = dt * u;
}

// ======================= segmented selective scan =======================
// unit = bk*12+g : 192 units; Sseg=32 segments of SEGL=72 steps.
// lane = ch*4 + ns : ch local channel [0,16), ns handles 4 of 16 states.

// ---- pass A: local scan per segment (h0=0), emit h_end + sum(dt) ----
__global__ __launch_bounds__(64) void k_scanA(const float* __restrict__ packed, const float* __restrict__ bc,
                                              const float* __restrict__ Alog,
                                              float* __restrict__ hend, float* __restrict__ dtsum){
  int blk = blockIdx.x; int unit = blk >> 5; int seg = blk & 31;
  int g = unit % 12; int bk = unit / 12; int k = bk & 3;
  int lane = threadIdx.x; int ch = lane >> 2; int ns = lane & 3; int nb = ns * 4;
  int d = g * 16 + ch;
  const int arow = (k * DIn + d) * 16 + nb;
  float A0 = -__expf(Alog[arow + 0]);
  float A1 = -__expf(Alog[arow + 1]);
  float A2 = -__expf(Alog[arow + 2]);
  float A3 = -__expf(Alog[arow + 3]);
  float h0 = 0.f, h1 = 0.f, h2 = 0.f, h3 = 0.f, dacc = 0.f;

  const int l0 = seg * SEGL;
  const float* pbase = packed + ((size_t)unit * Ll + l0) * 32;
  const float* bbase = bc + ((size_t)(bk * Ll) + l0) * 32;

  __shared__ float pl[256];
  __shared__ float blA[128];

  float4 pn = *(const float4*)(pbase + lane * 4);
  float4 bn;
  if (lane < 32) bn = *(const float4*)(bbase + (size_t)(lane >> 2) * 32 + (lane & 3) * 4);
  *(float4*)&pl[lane * 4] = pn;
  if (lane < 32) *(float4*)&blA[lane * 4] = bn;
  __syncthreads();

  for (int cc = 0; cc < NCH; ++cc){
    bool more = (cc + 1 < NCH);
    if (more){
      pn = *(const float4*)(pbase + (cc + 1) * 256 + lane * 4);
      if (lane < 32) bn = *(const float4*)(bbase + (size_t)((cc + 1) * 8 + (lane >> 2)) * 32 + (lane & 3) * 4);
    }
    #pragma unroll
    for (int lp = 0; lp < 8; ++lp){
      float dt = pl[lp * 32 + ch];
      float du = pl[lp * 32 + 16 + ch];
      float4 Bv = *(const float4*)&blA[lp * 16 + nb];
      dacc += dt;
      h0 = fmaf(h0, __expf(dt * A0), du * Bv.x);
      h1 = fmaf(h1, __expf(dt * A1), du * Bv.y);
      h2 = fmaf(h2, __expf(dt * A2), du * Bv.z);
      h3 = fmaf(h3, __expf(dt * A3), du * Bv.w);
    }
    __syncthreads();
    if (more){
      *(float4*)&pl[lane * 4] = pn;
      if (lane < 32) *(float4*)&blA[lane * 4] = bn;
    }
    __syncthreads();
  }
  size_t sb = (size_t)unit * Sseg + seg;
  *(float4*)&hend[sb * 256 + lane * 4] = make_float4(h0, h1, h2, h3);
  if (ns == 0) dtsum[sb * 16 + ch] = dacc;
}

// ---- combine: sequential fold over segments -> h_init per segment ----
__global__ __launch_bounds__(64) void k_comb(const float* __restrict__ Alog, const float* __restrict__ hend,
                                             const float* __restrict__ dtsum,
                                             float* __restrict__ hlo, float* __restrict__ hhi){
  int unit = blockIdx.x; int g = unit % 12; int bk = unit / 12; int k = bk & 3;
  int lane = threadIdx.x; int ch = lane >> 2; int ns = lane & 3; int nb = ns * 4;
  int d = g * 16 + ch;
  const int arow = (k * DIn + d) * 16 + nb;
  float A0 = -__expf(Alog[arow + 0]);
  float A1 = -__expf(Alog[arow + 1]);
  float A2 = -__expf(Alog[arow + 2]);
  float A3 = -__expf(Alog[arow + 3]);
  float h0 = 0.f, h1 = 0.f, h2 = 0.f, h3 = 0.f;
  for (int s = 0; s < Sseg; ++s){
    size_t sb = (size_t)unit * Sseg + s;
    *hptr(hlo, hhi, sb * 256 + lane * 4) = make_float4(h0, h1, h2, h3);
    float dsv = dtsum[sb * 16 + ch];
    float4 he = *(const float4*)&hend[sb * 256 + lane * 4];
    h0 = fmaf(h0, __expf(A0 * dsv), he.x);
    h1 = fmaf(h1, __expf(A1 * dsv), he.y);
    h2 = fmaf(h2, __expf(A2 * dsv), he.z);
    h3 = fmaf(h3, __expf(A3 * dsv), he.w);
  }
}

// ---- pass B: rescan from h_init, atomically accumulate y into ysum[b][pix][d] ----
__global__ __launch_bounds__(64) void k_scanB(const float* __restrict__ packed, const float* __restrict__ bc,
                                              const float* __restrict__ Alog,
                                              float* __restrict__ hlo, float* __restrict__ hhi,
                                              float* __restrict__ ysum){
  int blk = blockIdx.x; int unit = blk >> 5; int seg = blk & 31;
  int g = unit % 12; int bk = unit / 12; int k = bk & 3; int b = bk >> 2;
  int lane = threadIdx.x; int ch = lane >> 2; int ns = lane & 3; int nb = ns * 4;
  int d = g * 16 + ch;
  const int arow = (k * DIn + d) * 16 + nb;
  float A0 = -__expf(Alog[arow + 0]);
  float A1 = -__expf(Alog[arow + 1]);
  float A2 = -__expf(Alog[arow + 2]);
  float A3 = -__expf(Alog[arow + 3]);
  size_t sb = (size_t)unit * Sseg + seg;
  float4 hi = *hptr(hlo, hhi, sb * 256 + lane * 4);
  float h0 = hi.x, h1 = hi.y, h2 = hi.z, h3 = hi.w;

  const int l0 = seg * SEGL;
  const float* pbase = packed + ((size_t)unit * Ll + l0) * 32;
  const float* bbase = bc + ((size_t)(bk * Ll) + l0) * 32;
  float* ybase = ysum + (size_t)(b * Ll) * DIn + d;

  __shared__ float pl[256];
  __shared__ float bl[256];

  float4 pn = *(const float4*)(pbase + lane * 4);
  float4 bn = *(const float4*)(bbase + lane * 4);
  *(float4*)&pl[lane * 4] = pn;
  *(float4*)&bl[lane * 4] = bn;
  __syncthreads();

  for (int cc = 0; cc < NCH; ++cc){
    bool more = (cc + 1 < NCH);
    if (more){
      pn = *(const float4*)(pbase + (cc + 1) * 256 + lane * 4);
      bn = *(const float4*)(bbase + (cc + 1) * 256 + lane * 4);
    }
    #pragma unroll
    for (int lp = 0; lp < 8; ++lp){
      float dt = pl[lp * 32 + ch];
      float du = pl[lp * 32 + 16 + ch];
      float4 Bv = *(const float4*)&bl[lp * 32 + nb];
      float4 Cv = *(const float4*)&bl[lp * 32 + 16 + nb];
      h0 = fmaf(h0, __expf(dt * A0), du * Bv.x);
      h1 = fmaf(h1, __expf(dt * A1), du * Bv.y);
      h2 = fmaf(h2, __expf(dt * A2), du * Bv.z);
      h3 = fmaf(h3, __expf(dt * A3), du * Bv.w);
      float yp = fmaf(h0, Cv.x, fmaf(h1, Cv.y, fmaf(h2, Cv.z, h3 * Cv.w)));
      yp += __shfl_xor(yp, 1);
      yp += __shfl_xor(yp, 2);
      if (ns == 0){
        int l = l0 + cc * 8 + lp;
        int pix = pix_of(k, l);
        atomicAdd(ybase + (size_t)pix * DIn, yp);
      }
    }
    __syncthreads();
    if (more){
      *(float4*)&pl[lane * 4] = pn;
      *(float4*)&bl[lane * 4] = bn;
    }
    __syncthreads();
  }
}

// ---------------- block reduction (k_softmax helper) ----------------
__device__ inline float block_sum_192(float* red, int d, float v){
  red[d] = v; __syncthreads();
  if (d < 96) red[d] += red[d + 96]; __syncthreads();
  if (d < 48) red[d] += red[d + 48]; __syncthreads();
  if (d < 24) red[d] += red[d + 24]; __syncthreads();
  if (d < 12) red[d] += red[d + 12]; __syncthreads();
  if (d < 6)  red[d] += red[d + 6];  __syncthreads();
  float tot = red[0] + red[1] + red[2] + red[3] + red[4] + red[5];
  __syncthreads();
  return tot;
}

// ---- combine v2: 16-pixel tiles, shfl-reduce LNs, owT reused across tile ----
// thread = (m = tid>>4 : pixel, t = tid&15); 576 blocks x 256 threads
__global__ __launch_bounds__(256) void k_combine(const float* __restrict__ ysum, const float* __restrict__ xc,
                          const float* __restrict__ z, const float* __restrict__ Dp,
                          const float* __restrict__ ong, const float* __restrict__ onb,
                          const float* __restrict__ owT, const float* __restrict__ x2g,
                          const float* __restrict__ lng, const float* __restrict__ lnb,
                          const float* __restrict__ sq1T, const float* __restrict__ sq2T,
                          float* __restrict__ ul){
  __shared__ float ygs[16 * 200];
  __shared__ float crs_s[16 * 104];
  int tid = threadIdx.x;
  int m = tid >> 4, t = tid & 15;
  int p = blockIdx.x * 16 + m;
  const float* yrow = ysum + (size_t)p * DIn;
  const float* urow = xc   + (size_t)p * DIn;
  const float* zrow = z    + (size_t)p * DIn;

  // LN(192) over channels d = t + 16j
  float yv[12];
  float s1 = 0.f;
  #pragma unroll
  for (int j = 0; j < 12; ++j){
    int d = t + 16 * j;
    float Ds = Dp[d] + Dp[192 + d] + Dp[384 + d] + Dp[576 + d];
    float v = fmaf(urow[d], Ds, yrow[d]);
    yv[j] = v; s1 += v;
  }
  #pragma unroll
  for (int mk = 1; mk < 16; mk <<= 1) s1 += __shfl_xor(s1, mk, 16);
  float mu = s1 * (1.f / 192.f);
  float s2 = 0.f;
  #pragma unroll
  for (int j = 0; j < 12; ++j){ float dv = yv[j] - mu; s2 += dv * dv; }
  #pragma unroll
  for (int mk = 1; mk < 16; mk <<= 1) s2 += __shfl_xor(s2, mk, 16);
  float rstd = rsqrtf(s2 * (1.f / 192.f) + 1e-5f);
  #pragma unroll
  for (int j = 0; j < 12; ++j){
    int d = t + 16 * j;
    float yn = (yv[j] - mu) * rstd * ong[d] + onb[d];
    float zv = zrow[d];
    ygs[m * 200 + d] = yn * (zv * sigmf(zv));
  }
  __syncthreads();

  // out-proj 192->96 (owT reused by all 16 pixels), c = t + 16jj
  float acc[6];
  #pragma unroll
  for (int jj = 0; jj < 6; ++jj) acc[jj] = 0.f;
  const float* yg = &ygs[m * 200];
  for (int dd = 0; dd < 192; ++dd){
    float xv = yg[dd];
    const float* wrow = owT + dd * 96 + t;
    #pragma unroll
    for (int jj = 0; jj < 6; ++jj)
      acc[jj] = fmaf(xv, wrow[16 * jj], acc[jj]);
  }
  // + gated branch, LN(96)
  float sv[6]; float s3 = 0.f;
  #pragma unroll
  for (int jj = 0; jj < 6; ++jj){
    int c = t + 16 * jj;
    sv[jj] = acc[jj] + x2g[(size_t)p * CHn + c];
    s3 += sv[jj];
  }
  #pragma unroll
  for (int mk = 1; mk < 16; mk <<= 1) s3 += __shfl_xor(s3, mk, 16);
  float mu2 = s3 * (1.f / 96.f);
  float s4 = 0.f;
  #pragma unroll
  for (int jj = 0; jj < 6; ++jj){ float dv = sv[jj] - mu2; s4 += dv * dv; }
  #pragma unroll
  for (int mk = 1; mk < 16; mk <<= 1) s4 += __shfl_xor(s4, mk, 16);
  float rstd2 = rsqrtf(s4 * (1.f / 96.f) + 1e-5f);
  #pragma unroll
  for (int jj = 0; jj < 6; ++jj){
    int c = t + 16 * jj;
    crs_s[m * 104 + c] = (sv[jj] - mu2) * rstd2 * lng[c] + lnb[c];
  }
  __syncthreads();

  // squeeze convs: 48 outputs per pixel, o = t + 16jj2
  const float* cr = &crs_s[m * 104];
  #pragma unroll
  for (int jj = 0; jj < 3; ++jj){
    int o = t + 16 * jj;
    float a = 0.f;
    if (o < 24){
      for (int i = 0; i < 48; ++i) a = fmaf(sq1T[i * 24 + o], cr[i], a);
    } else {
      int oo = o - 24;
      for (int i = 0; i < 48; ++i) a = fmaf(sq2T[i * 24 + oo], cr[48 + i], a);
    }
    ul[(size_t)p * 48 + o] = a;
  }
}

// ---------------- CRM main ----------------
__global__ void k_y(const float* __restrict__ ul, const float* __restrict__ gwcT,
                    const float* __restrict__ gwcb, const float* __restrict__ pwc1T,
                    const float* __restrict__ pwc2T, float* __restrict__ Ybig){
  int p = blockIdx.x; int b = p / Ll; int pp = p - b * Ll;
  int r = pp / Ww; int cx = pp - r * Ww;
  int oc = threadIdx.x;
  __shared__ float ulv[48];
  if (oc < 48) ulv[oc] = ul[(size_t)p * 48 + oc];
  __syncthreads();
  float acc;
  if (oc < 96){
    acc = gwcb[oc];
    int grp = oc / 48;
    for (int dy = -1; dy <= 1; ++dy){
      int ny = r + dy; if ((unsigned)ny >= Hh) continue;
      for (int dx = -1; dx <= 1; ++dx){
        int nx = cx + dx; if ((unsigned)nx >= Ww) continue;
        const float* un = ul + (size_t)((b * Ll) + ny * Ww + nx) * 48 + grp * 12;
        int k9 = (dy + 1) * 3 + (dx + 1);
        #pragma unroll
        for (int i = 0; i < 12; ++i) acc = fmaf(gwcT[(i * 9 + k9) * 96 + oc], un[i], acc);
      }
    }
    for (int i = 0; i < 24; ++i) acc = fmaf(pwc1T[i * 96 + oc], ulv[i], acc);
  } else if (oc < 168){
    int o2 = oc - 96; acc = 0.f;
    for (int i = 0; i < 24; ++i) acc = fmaf(pwc2T[i * 72 + o2], ulv[24 + i], acc);
  } else {
    acc = ulv[24 + oc - 168];
  }
  Ybig[(size_t)p * 192 + oc] = acc;
}

// ---------------- coalesced partial spatial sums ----------------
__global__ void k_csum(const float* __restrict__ Ybig, float* __restrict__ csum_p){
  int b = blockIdx.x / 36; int ch = blockIdx.x - b * 36;
  int t = threadIdx.x;
  if (t >= 192) return;
  float acc = 0.f;
  const float* base = Ybig + (size_t)(b * Ll + ch * 64) * 192 + t;
  #pragma unroll 4
  for (int i = 0; i < 64; ++i) acc += base[(size_t)i * 192];
  csum_p[(size_t)blockIdx.x * 192 + t] = acc;
}

// ---------------- softmax over 192 channel means ----------------
__global__ void k_softmax(const float* __restrict__ csum_p, float* __restrict__ wsm){
  int b = blockIdx.x; int t = threadIdx.x;
  __shared__ float red[192];
  float m = 0.f;
  for (int cc = 0; cc < 36; ++cc) m += csum_p[(size_t)(b * 36 + cc) * 192 + t];
  m *= (1.f / 2304.f);
  red[t] = m; __syncthreads();
  if (t < 96) red[t] = fmaxf(red[t], red[t + 96]); __syncthreads();
  if (t < 48) red[t] = fmaxf(red[t], red[t + 48]); __syncthreads();
  if (t < 24) red[t] = fmaxf(red[t], red[t + 24]); __syncthreads();
  if (t < 12) red[t] = fmaxf(red[t], red[t + 12]); __syncthreads();
  if (t < 6)  red[t] = fmaxf(red[t], red[t + 6]);  __syncthreads();
  float mx = fmaxf(fmaxf(fmaxf(red[0], red[1]), fmaxf(red[2], red[3])), fmaxf(red[4], red[5]));
  __syncthreads();
  float e = __expf(m - mx);
  float s = block_sum_192(red, t, e);
  wsm[b * 192 + t] = e / s;
}

// ---------------- weighted halves + final linear -> [p][c] ----------------
__global__ void k_final(const float* __restrict__ Ybig, const float* __restrict__ wsm,
                        const float* __restrict__ finT, const float* __restrict__ finb,
                        float* __restrict__ outT){
  int p = blockIdx.x; int b = p / Ll;
  int c = threadIdx.x;
  __shared__ float ov[96];
  float o = wsm[b * 192 + c]      * Ybig[(size_t)p * 192 + c]
          + wsm[b * 192 + 96 + c] * Ybig[(size_t)p * 192 + 96 + c];
  ov[c] = o; __syncthreads();
  float acc = finb[c];
  for (int i = 0; i < 96; ++i) acc = fmaf(finT[i * 96 + c], ov[i], acc);
  outT[(size_t)p * CHn + c] = acc;
}

// ---------------- host launch ----------------
extern "C" void kernel_launch(void* const* d_in, const int* in_sizes, int n_in,
                              void* d_out, int out_size, void* d_ws, size_t ws_size,
                              hipStream_t stream) {
  const float* x     = (const float*)d_in[0];
  const float* w1    = (const float*)d_in[1];
  const float* b1    = (const float*)d_in[2];
  const float* bng   = (const float*)d_in[3];
  const float* bnb   = (const float*)d_in[4];
  const float* linw  = (const float*)d_in[5];
  const float* linb  = (const float*)d_in[6];
  const float* dw1w  = (const float*)d_in[7];
  const float* dw1b  = (const float*)d_in[8];
  const float* dw2w  = (const float*)d_in[9];
  const float* dw2b  = (const float*)d_in[10];
  const float* ag1w  = (const float*)d_in[11];
  const float* ag1b  = (const float*)d_in[12];
  const float* ag2w  = (const float*)d_in[13];
  const float* ag2b  = (const float*)d_in[14];
  const float* lng   = (const float*)d_in[15];
  const float* lnb   = (const float*)d_in[16];
  const float* sq1w  = (const float*)d_in[17];
  const float* sq2w  = (const float*)d_in[18];
  const float* gwcw  = (const float*)d_in[19];
  const float* gwcb  = (const float*)d_in[20];
  const float* pwc1w = (const float*)d_in[21];
  const float* pwc2w = (const float*)d_in[22];
  const float* finw  = (const float*)d_in[23];
  const float* finb  = (const float*)d_in[24];
  const float* inw   = (const float*)d_in[25];
  const float* scw   = (const float*)d_in[26];
  const float* scb   = (const float*)d_in[27];
  const float* xpw   = (const float*)d_in[28];
  const float* dtw   = (const float*)d_in[29];
  const float* dtb   = (const float*)d_in[30];
  const float* Alog  = (const float*)d_in[31];
  const float* Dp    = (const float*)d_in[32];
  const float* ong   = (const float*)d_in[33];
  const float* onb   = (const float*)d_in[34];
  const float* oww   = (const float*)d_in[35];

  float* ws = (float*)d_ws;
  // layout (floats):
  float* hlin   = ws + 0;         // 884736: hlin(k_pre->k_dw); ulb(k_combine->k_y); dtsum @+442368
  float* dtsum  = ws + 442368;    // 98304  (scanA->comb)
  float* x1pre  = ws + 884736;    // 884736: x1pre(k_dw->k_ssin); hinit_lo(comb->scanB); csum_p later
  float* x2     = ws + 1769472;   // 884736: x2(k_dw->k_gate); dtsG(k_xred->k_pack); hinit_hi
  float* x2g    = ws + 2654208;   // 884736: (k_gate->k_combine)
  float* xibuf  = ws + 3538944;   // 1769472: xi(k_ssin->k_ssdw); hend(scanA->comb); Ybig(k_y->k_final)
  float* zbuf   = ws + 5308416;   // 1769472: (k_ssin->k_combine)
  float* xcbuf  = ws + 7077888;   // 1769472: (k_ssdw->k_xproj,k_pack,k_combine)
  float* packed = ws + 8847360;   // 14155776: part(k_xproj->k_xred) then packed(k_pack->scans); xT/outT alias
  float* bcbuf  = ws + 23003136;  // 1179648: (k_xred->scans)
  float* ysum   = ws + 24182784;  // 1769472: (scanB atomics ->k_combine)
  float* wT     = ws + 25952256;  // 142656 weights -> total 26094912 floats (104.4 MB)

  float* dtsG    = x2;
  float* hend    = xibuf;
  float* hinitlo = x1pre;
  float* hinithi = x2;
  float* ulb     = hlin;
  float* Ybig    = xibuf;
  float* csum_p  = x1pre;
  float* wsmb    = x1pre + 27648;
  float* xT      = packed;
  float* part    = packed;        // 8404992 floats used (k_xproj->k_xred)
  float* outT    = packed;

  float* w1T   = wT + 0;
  float* linT  = wT + 9216;
  float* ag1T  = wT + 18432;
  float* ag2T  = wT + 23040;
  float* inT   = wT + 27648;
  float* owT   = wT + 64512;
  float* pwc1T = wT + 82944;
  float* pwc2T = wT + 85248;
  float* finT  = wT + 86976;
  float* sq1T  = wT + 96192;
  float* sq2T  = wT + 97344;
  float* gwcT  = wT + 98496;
  float* dtwT  = wT + 108864;
  float* xpwT  = wT + 113472;

  TArgs ta;
  const float* srcs[14] = {w1, linw, ag1w, ag2w, inw, oww, pwc1w, pwc2w, finw, sq1w, sq2w, gwcw, dtw, xpw};
  float* dsts[14]       = {w1T, linT, ag1T, ag2T, inT, owT, pwc1T, pwc2T, finT, sq1T, sq2T, gwcT, dtwT, xpwT};
  int rows[14] = {96, 96, 48, 96, 384, 96, 96, 72, 96, 24, 24, 96, 768, 152};
  int cols[14] = {96, 96, 96, 48, 96, 192, 24, 24, 96, 48, 48, 108, 6, 192};
  for (int i = 0; i < 14; ++i){ ta.s[i] = srcs[i]; ta.d[i] = dsts[i]; ta.rows[i] = rows[i]; ta.cols[i] = cols[i]; }

  k_tr<<<dim3(144, 14), 256, 0, stream>>>(ta);
  k_trx<<<dim3(72, 3, 4), 256, 0, stream>>>(x, xT);
  k_pre<<<Pp, CHn, 0, stream>>>(xT, w1T, b1, bng, bnb, linT, linb, hlin);
  k_dw<<<(Pp * CHn) / 256, 256, 0, stream>>>(hlin, dw1w, dw1b, dw2w, dw2b, x1pre, x2);
  k_gate<<<Pp, CHn, 0, stream>>>(x2, ag1T, ag1b, ag2T, ag2b, x2g);
  k_ssin<<<576 * 3, 256, 0, stream>>>(x1pre, inT, xibuf, zbuf);
  k_ssdw<<<(Pp * DIn) / 256, 256, 0, stream>>>(xibuf, scw, scb, xcbuf);
  k_xproj<<<576 * 6, 256, 0, stream>>>(xcbuf, xpwT, part);
  k_xred<<<(Pp * 152 + 255) / 256, 256, 0, stream>>>(part, bcbuf, dtsG);
  k_pack<<<(36864 * DIn) / 256, 256, 0, stream>>>(dtsG, dtwT, dtb, xcbuf, packed);
  hipMemsetAsync(ysum, 0, (size_t)1769472 * 4, stream);
  k_scanA<<<192 * Sseg, 64, 0, stream>>>(packed, bcbuf, Alog, hend, dtsum);
  k_comb<<<192, 64, 0, stream>>>(Alog, hend, dtsum, hinitlo, hinithi);
  k_scanB<<<192 * Sseg, 64, 0, stream>>>(packed, bcbuf, Alog, hinitlo, hinithi, ysum);
  k_combine<<<576, 256, 0, stream>>>(ysum, xcbuf, zbuf, Dp, ong, onb, owT, x2g, lng, lnb, sq1T, sq2T, ulb);
  k_y<<<Pp, 192, 0, stream>>>(ulb, gwcT, gwcb, pwc1T, pwc2T, Ybig);
  k_csum<<<144, 256, 0, stream>>>(Ybig, csum_p);
  k_softmax<<<4, 192, 0, stream>>>(csum_p, wsmb);
  k_final<<<Pp, CHn, 0, stream>>>(Ybig, wsmb, finT, finb, outT);
  k_tro<<<dim3(72, 3, 4), 256, 0, stream>>>(outT, (float*)d_out);
}